// Round 9
// baseline (689.602 us; speedup 1.0000x reference)
//
#include <hip/hip_runtime.h>
#include <hip/hip_bf16.h>

#define ND 8192
#define NZ 4096
#define IN_DIM 256
#define HID 128
#define MIDW 192
#define NP 4
#define NCH 5
#define DEG 32
#define E_D (ND*DEG)
#define E_Z (NZ*DEG)

typedef __hip_bfloat16 bf16;
typedef __attribute__((ext_vector_type(8))) short s8v;
typedef __attribute__((ext_vector_type(4))) float f4v;

static __device__ __forceinline__ unsigned short f2bf(float x){
  bf16 b = __float2bfloat16(x);
  return *reinterpret_cast<unsigned short*>(&b);
}
static __device__ __forceinline__ uint packbf2(float a, float b){
  return (uint)f2bf(a) | ((uint)f2bf(b) << 16);
}
static __device__ __forceinline__ float bfl(uint w){ return __uint_as_float(w<<16); }
static __device__ __forceinline__ float bfh(uint w){ return __uint_as_float(w & 0xffff0000u); }
static __device__ __forceinline__ void gload16(const void* g, void* l){
  __builtin_amdgcn_global_load_lds(
      (const __attribute__((address_space(1))) unsigned int*)g,
      (__attribute__((address_space(3))) unsigned int*)l, 16, 0, 0);
}

// ---------------- CSR build: one block per metapath, LDS-only atomics ----------------
__global__ __launch_bounds__(1024) void k_csr(
    const int* __restrict__ src_d, const int* __restrict__ dst_d,
    int* __restrict__ off_d, ushort* __restrict__ csr_d,
    const int* __restrict__ src_z, const int* __restrict__ dst_z,
    int* __restrict__ off_z, ushort* __restrict__ csr_z)
{
  int b = blockIdx.x, t = threadIdx.x;
  const int *src, *dst; int* off; ushort* csr; int n, E;
  if (b < NP){
    src = src_d + (long)b*E_D; dst = dst_d + (long)b*E_D;
    off = off_d + (long)b*(ND+1); csr = csr_d + (long)b*E_D; n = ND; E = E_D;
  } else {
    int m = b - NP;
    src = src_z + (long)m*E_Z; dst = dst_z + (long)m*E_Z;
    off = off_z + (long)m*(NZ+1); csr = csr_z + (long)m*E_Z; n = NZ; E = E_Z;
  }
  __shared__ int hist[ND];      // 32 KB; disease uses first 4096 (rest zero)
  __shared__ int wpart[16];
  #pragma unroll
  for (int j=0;j<8;j++) hist[t + j*1024] = 0;
  __syncthreads();
  // pass 1: count (LDS atomics only)
  for (int e=t; e<E; e+=1024) atomicAdd(&hist[src[e]], 1);
  __syncthreads();
  // in-block exclusive scan over 8192 entries (thread owns 8)
  int base = t*8;
  int loc[8]; int sum = 0;
  #pragma unroll
  for (int j=0;j<8;j++){ loc[j] = sum; sum += hist[base+j]; }
  int lane = t&63, wv = t>>6;
  int x = sum;
  #pragma unroll
  for (int s2=1; s2<64; s2<<=1){
    int u = __shfl_up(x, s2, 64);
    if (lane >= s2) x += u;
  }
  if (lane==63) wpart[wv] = x;
  __syncthreads();
  int wo = 0;
  for (int w=0; w<wv; w++) wo += wpart[w];
  int tbase = wo + x - sum;
  __syncthreads();
  #pragma unroll
  for (int j=0;j<8;j++){
    int v = tbase + loc[j];
    if (base+j < n) off[base+j] = v;
    hist[base+j] = v;             // seed cursor
  }
  if (t==0) off[n] = E;
  __syncthreads();
  // pass 2: scatter (LDS cursor, plain global stores; single block -> L2-local)
  for (int e=t; e<E; e+=1024){
    int s = src[e];
    int pos = atomicAdd(&hist[s], 1);
    csr[pos] = (ushort)dst[e];
  }
}

// ---------------- mega prep: cvts + transposes + G + v2 (no atomics) ----------------
static __device__ __forceinline__ void tpz(const float* __restrict__ in, bf16* __restrict__ out,
                                           int rows, int cols, long idx){
  int per = rows*cols;
  int b = (int)(idx / per);
  int rem = (int)(idx - (long)b*per);
  int r = rem / cols, c = rem - r*cols;
  out[(long)b*per + (long)c*rows + r] = __float2bfloat16(in[idx]);
}

#define B_CVD 2048
#define B_CVZ (B_CVD+1024)     // 3072
#define B_W1D (B_CVZ+960)      // 4032
#define B_W1Z (B_W1D+960)      // 4992
#define B_W2D (B_W1Z+720)      // 5712
#define B_W2Z (B_W2D+720)      // 6432
#define B_W3D (B_W2Z+480)      // 6912
#define B_W3Z (B_W3D+480)      // 7392
#define B_WDEC (B_W3Z+320)     // 7712
#define B_G (B_WDEC+128)       // 7840
#define B_END (B_G+1)          // 7841

__global__ __launch_bounds__(256) void k_prep(
    const float* feat_d, const float* feat_z, bf16* featb_d, bf16* featb_z,
    const float* dW1, const float* dW2, const float* dW3,
    const float* zW1, const float* zW2, const float* zW3,
    bf16* w1t_d, bf16* w2t_d, bf16* w3t_d, bf16* w1t_z, bf16* w2t_z, bf16* w3t_z,
    const float* Wdec, bf16* wdect,
    const float* Wq_d, const float* Wk_d, const float* Wq_z, const float* Wk_z,
    bf16* Gtb,
    const float* bq_d, const float* bq_z, float* v2v,
    const float* wattn, float* wsm)
{
  int b = blockIdx.x, t = threadIdx.x;
  if (b < B_CVD){
    long i4 = (long)b*256 + t;
    float4 v = ((const float4*)feat_d)[i4];
    ushort4 o; o.x=f2bf(v.x); o.y=f2bf(v.y); o.z=f2bf(v.z); o.w=f2bf(v.w);
    ((ushort4*)featb_d)[i4] = o;
  } else if (b < B_CVZ){
    long i4 = (long)(b - B_CVD)*256 + t;
    float4 v = ((const float4*)feat_z)[i4];
    ushort4 o; o.x=f2bf(v.x); o.y=f2bf(v.y); o.z=f2bf(v.z); o.w=f2bf(v.w);
    ((ushort4*)featb_z)[i4] = o;
  } else if (b < B_W1D){ tpz(dW1, w1t_d, IN_DIM, MIDW, (long)(b-B_CVZ)*256 + t); }
  else if (b < B_W1Z){ tpz(zW1, w1t_z, IN_DIM, MIDW, (long)(b-B_W1D)*256 + t); }
  else if (b < B_W2D){ tpz(dW2, w2t_d, MIDW, MIDW, (long)(b-B_W1Z)*256 + t); }
  else if (b < B_W2Z){ tpz(zW2, w2t_z, MIDW, MIDW, (long)(b-B_W2D)*256 + t); }
  else if (b < B_W3D){ tpz(dW3, w3t_d, MIDW, HID, (long)(b-B_W2Z)*256 + t); }
  else if (b < B_W3Z){ tpz(zW3, w3t_z, MIDW, HID, (long)(b-B_W3D)*256 + t); }
  else if (b < B_WDEC){ tpz(Wdec, wdect, HID, HID, (long)(b-B_W3Z)*256 + t); }
  else if (b < B_G){
    // Gt[c,h'] = sum_j Wq[h',j]*Wk[c,j]
    int cc = (b - B_WDEC)*2 + (t>>7);
    int hp = t & 127;
    const float* Wq = cc < 128 ? Wq_d : Wq_z;
    const float* Wk = cc < 128 ? Wk_d : Wk_z;
    int c = cc & 127;
    float s = 0.f;
    for (int j=0;j<HID;j++) s += Wq[hp*HID+j]*Wk[c*HID+j];
    Gtb[(cc < 128 ? 0 : HID*HID) + c*HID + hp] = __float2bfloat16(s);
  } else {
    if (t < 128){
      float s = 0.f;
      for (int j=0;j<HID;j++) s += Wk_d[t*HID+j]*bq_d[j];
      v2v[t] = s;
    } else {
      int tt = t-128;
      float s = 0.f;
      for (int j=0;j<HID;j++) s += Wk_z[tt*HID+j]*bq_z[j];
      v2v[128+tt] = s;
    }
    if (t == 0){
      float mx = wattn[0];
      for (int i=1;i<NCH;i++) mx = fmaxf(mx, wattn[i]);
      float e[NCH], s=0.f;
      for (int i=0;i<NCH;i++){ e[i]=expf(wattn[i]-mx); s+=e[i]; }
      for (int i=0;i<NCH;i++) wsm[i]=e[i]/s;
    }
  }
}

// ---------------- stage 1: (A1 | A2) GEMM, z = type*5 + channel ----------------
__global__ __launch_bounds__(256) void k_stage1(
    const bf16* __restrict__ featb_d, const bf16* __restrict__ featb_z,
    const bf16* __restrict__ w1t_d, const bf16* __restrict__ w1t_z,
    const float* __restrict__ db1, const float* __restrict__ zb1,
    const float* __restrict__ att_d, const float* __restrict__ att_z,
    bf16* __restrict__ h1_d, bf16* __restrict__ h1_z,
    bf16* __restrict__ Y_d, bf16* __restrict__ Y_z)
{
  int z = blockIdx.z, typ = z/5, c = z - 5*(z/5);
  int n = typ ? NZ : ND;
  long row0 = (long)blockIdx.x*128;
  if (row0 >= n) return;
  int col0 = blockIdx.y*64;
  __shared__ short As[128*40];
  __shared__ short Bs[64*40];
  int t = threadIdx.x, lane = t&63, wv = t>>6;
  int l15 = lane&15, kof = (lane>>4)*8;
  const short* Ag = (const short*)(typ ? featb_z : featb_d);
  const short* Bg = (const short*)(typ ? w1t_z : w1t_d) + (long)c*MIDW*IN_DIM;
  f4v acc[2][4] = {};
  for (int kk=0; kk<IN_DIM; kk+=32){
    __syncthreads();
    #pragma unroll
    for (int j=0;j<2;j++){
      int c2 = t + j*256;
      int row = c2>>2, sub = c2&3;
      *(s8v*)(&As[row*40 + sub*8]) = *(const s8v*)(Ag + (row0+row)*IN_DIM + kk + sub*8);
    }
    { int row = t>>2, sub = t&3;
      *(s8v*)(&Bs[row*40 + sub*8]) = *(const s8v*)(Bg + (long)(col0+row)*IN_DIM + kk + sub*8); }
    __syncthreads();
    s8v af[2], bfr[4];
    #pragma unroll
    for (int i2=0;i2<2;i2++) af[i2] = *(const s8v*)(&As[(wv*32 + i2*16 + l15)*40 + kof]);
    #pragma unroll
    for (int j2=0;j2<4;j2++) bfr[j2] = *(const s8v*)(&Bs[(j2*16 + l15)*40 + kof]);
    #pragma unroll
    for (int i2=0;i2<2;i2++)
      #pragma unroll
      for (int j2=0;j2<4;j2++)
        acc[i2][j2] = __builtin_amdgcn_mfma_f32_16x16x32_bf16(af[i2], bfr[j2], acc[i2][j2],0,0,0);
  }
  if (c == 0){
    const float* bb = typ ? zb1 : db1;
    bf16* outp = typ ? h1_z : h1_d;
    #pragma unroll
    for (int i2=0;i2<2;i2++)
      #pragma unroll
      for (int j2=0;j2<4;j2++){
        int col = col0 + j2*16 + l15;
        float bv = bb[col];
        #pragma unroll
        for (int r=0;r<4;r++){
          long row = row0 + wv*32 + i2*16 + (lane>>4)*4 + r;
          outp[row*MIDW + col] = __float2bfloat16(fmaxf(acc[i2][j2][r] + bv, 0.f));
        }
      }
  } else {
    const float* rs = (typ ? att_z : att_d) + (long)(c-1)*n;
    bf16* outp = (typ ? Y_z : Y_d) + (long)(c-1)*n*MIDW;
    #pragma unroll
    for (int i2=0;i2<2;i2++)
      #pragma unroll
      for (int j2=0;j2<4;j2++){
        int col = col0 + j2*16 + l15;
        #pragma unroll
        for (int r=0;r<4;r++){
          long row = row0 + wv*32 + i2*16 + (lane>>4)*4 + r;
          outp[row*MIDW + col] = __float2bfloat16(acc[i2][j2][r] * rs[row]);
        }
      }
  }
}

// ---------------- aggregation (compact ushort CSR) ----------------
__global__ __launch_bounds__(256) void k_agg2(
    const ushort* __restrict__ csr_d, const int* __restrict__ off_d, const float* __restrict__ bias_d,
    const bf16* __restrict__ Y_d, bf16* __restrict__ h1_d,
    const ushort* __restrict__ csr_z, const int* __restrict__ off_z, const float* __restrict__ bias_z,
    const bf16* __restrict__ Y_z, bf16* __restrict__ h1_z)
{
  int wid = (blockIdx.x*256 + threadIdx.x) >> 6;
  int lane = threadIdx.x & 63;
  const ushort* csr; const int* off; const float* bias; const uint* Yb; bf16* h1; int n, m; long ebase;
  if (wid < NP*ND){
    m = wid >> 13; int s0 = wid & (ND-1);
    csr = csr_d; off = off_d + (long)m*(ND+1); bias = bias_d; h1 = h1_d; n = ND;
    Yb = (const uint*)Y_d + (long)m*ND*96;
    ebase = (long)m*E_D;
    wid = s0;
  } else {
    int w2 = wid - NP*ND;
    m = w2 >> 12; int s0 = w2 & (NZ-1);
    csr = csr_z; off = off_z + (long)m*(NZ+1); bias = bias_z; h1 = h1_z; n = NZ;
    Yb = (const uint*)Y_z + (long)m*NZ*96;
    ebase = (long)m*E_Z;
    wid = s0;
  }
  int s = wid;
  int o0 = off[s], o1 = off[s+1];
  int cnt = o1 - o0;
  const ushort* lp = csr + ebase + o0;
  bool hi2 = lane < 32;
  float a0=0.f,a1=0.f,a2=0.f,a3=0.f;
  for (int base=0; base<cnt; base+=64){
    int rem = cnt - base;
    int idx = (lane < rem) ? lane : (rem-1);
    int e = lp[base + idx];
    int lim = rem < 64 ? rem : 64;
    int j = 0;
    for (; j+1<lim; j+=2){
      int d0 = __shfl(e, j), d1 = __shfl(e, j+1);
      const uint* r0 = Yb + (long)d0*96;
      const uint* r1 = Yb + (long)d1*96;
      uint w0 = r0[lane], w1 = r1[lane];
      uint v0 = hi2 ? r0[64+lane] : 0u;
      uint v1 = hi2 ? r1[64+lane] : 0u;
      a0 += bfl(w0)+bfl(w1); a1 += bfh(w0)+bfh(w1);
      a2 += bfl(v0)+bfl(v1); a3 += bfh(v0)+bfh(v1);
    }
    if (j < lim){
      int d0 = __shfl(e, j);
      const uint* r0 = Yb + (long)d0*96;
      uint w0 = r0[lane];
      uint v0 = hi2 ? r0[64+lane] : 0u;
      a0 += bfl(w0); a1 += bfh(w0);
      a2 += bfl(v0); a3 += bfh(v0);
    }
  }
  float inv = 1.0f / fmaxf((float)cnt, 1.0f);
  const float* bb = bias + (m+1)*MIDW;
  float2 b0 = *(const float2*)(bb + 2*lane);
  uint* hrow = (uint*)((short*)h1 + ((long)(m+1)*n + s)*MIDW);
  hrow[lane] = packbf2(fmaxf(a0*inv + b0.x, 0.f), fmaxf(a1*inv + b0.y, 0.f));
  if (hi2){
    float2 b1v = *(const float2*)(bb + 128 + 2*lane);
    hrow[64+lane] = packbf2(fmaxf(a2*inv + b1v.x, 0.f), fmaxf(a3*inv + b1v.y, 0.f));
  }
}

// ---------------- generic batched GEMM (decoder) ----------------
struct GemmP {
  const bf16* A; const bf16* BT; const float* bias; bf16* out;
  const float* scale; const float* rowsc;
  long rs_moff, a_moff, out_rstride, out_moff;
  int K, N, nrows, relu;
};

__global__ __launch_bounds__(256) void k_gemm(GemmP P0, GemmP P1, int zsplit)
{
  const GemmP& p = ((int)blockIdx.z < zsplit) ? P0 : P1;
  int m = ((int)blockIdx.z < zsplit) ? blockIdx.z : blockIdx.z - zsplit;
  long row0 = (long)blockIdx.x*128;
  if (row0 >= p.nrows) return;
  int col0 = blockIdx.y*64;
  if (col0 >= p.N) return;
  __shared__ short As[128*40];
  __shared__ short Bs[64*40];
  int t = threadIdx.x;
  const short* Ag = (const short*)p.A + m*p.a_moff;
  const short* Bg = (const short*)p.BT + (long)m*p.N*p.K;
  int lane = t&63, wv = t>>6;
  int l15 = lane&15, kof = (lane>>4)*8;
  int K = p.K;
  f4v acc[2][4] = {};
  for (int kk=0; kk<K; kk+=32){
    __syncthreads();
    #pragma unroll
    for (int j=0;j<2;j++){
      int c = t + j*256;
      int row = c>>2, sub = c&3;
      *(s8v*)(&As[row*40 + sub*8]) = *(const s8v*)(Ag + (row0+row)*K + kk + sub*8);
    }
    { int row = t>>2, sub = t&3;
      *(s8v*)(&Bs[row*40 + sub*8]) = *(const s8v*)(Bg + (long)(col0+row)*K + kk + sub*8); }
    __syncthreads();
    s8v af[2], bfr[4];
    #pragma unroll
    for (int i2=0;i2<2;i2++) af[i2] = *(const s8v*)(&As[(wv*32 + i2*16 + l15)*40 + kof]);
    #pragma unroll
    for (int j2=0;j2<4;j2++) bfr[j2] = *(const s8v*)(&Bs[(j2*16 + l15)*40 + kof]);
    #pragma unroll
    for (int i2=0;i2<2;i2++)
      #pragma unroll
      for (int j2=0;j2<4;j2++)
        acc[i2][j2] = __builtin_amdgcn_mfma_f32_16x16x32_bf16(af[i2], bfr[j2], acc[i2][j2],0,0,0);
  }
  float sc = p.scale ? p.scale[m] : 1.0f;
  #pragma unroll
  for (int i2=0;i2<2;i2++){
    #pragma unroll
    for (int j2=0;j2<4;j2++){
      int col = col0 + j2*16 + l15;
      float bv = p.bias ? p.bias[m*p.N + col] : 0.f;
      #pragma unroll
      for (int r=0;r<4;r++){
        long row = row0 + wv*32 + i2*16 + (lane>>4)*4 + r;
        float v = acc[i2][j2][r] + bv;
        if (p.relu) v = fmaxf(v, 0.f);
        v *= sc;
        if (p.rowsc) v *= p.rowsc[m*p.rs_moff + row];
        p.out[m*p.out_moff + row*p.out_rstride + col] = __float2bfloat16(v);
      }
    }
  }
}

// ---------------- fused MLP 2+3 + pg ----------------
struct MlpP { const bf16* h1; const bf16* w2t; const float* b2;
              const bf16* w3t; const float* b3; bf16* pout; bf16* pgout;
              const bf16* gt; int n; };

__global__ __launch_bounds__(256) void k_mlp23(MlpP P0, MlpP P1, int zsplit)
{
  const MlpP& p = ((int)blockIdx.z < zsplit) ? P0 : P1;
  int m = ((int)blockIdx.z < zsplit) ? blockIdx.z : blockIdx.z - zsplit;
  int row0 = blockIdx.x*128;
  if (row0 >= p.n) return;
  __shared__ short h2s[128*200];
  __shared__ short As[128*40];
  __shared__ short Bs[192*40];
  int t = threadIdx.x, lane = t&63, wv = t>>6;
  int l15 = lane&15, hi = lane>>4, kof = hi*8;
  const short* Ag = (const short*)p.h1 + ((long)m*p.n + row0)*MIDW;
  const short* Bg = (const short*)p.w2t + (long)m*MIDW*MIDW;
  f4v accA[2][12] = {};
  for (int kk=0; kk<MIDW; kk+=32){
    __syncthreads();
    #pragma unroll
    for (int j=0;j<2;j++){
      int c = t + j*256;
      int row = c>>2, sub = c&3;
      *(s8v*)(&As[row*40 + sub*8]) = *(const s8v*)(Ag + (long)row*MIDW + kk + sub*8);
    }
    #pragma unroll
    for (int j=0;j<3;j++){
      int c = t + j*256;
      int row = c>>2, sub = c&3;
      *(s8v*)(&Bs[row*40 + sub*8]) = *(const s8v*)(Bg + (long)row*MIDW + kk + sub*8);
    }
    __syncthreads();
    s8v af[2], bfr[12];
    #pragma unroll
    for (int i2=0;i2<2;i2++) af[i2] = *(const s8v*)(&As[(wv*32 + i2*16 + l15)*40 + kof]);
    #pragma unroll
    for (int j2=0;j2<12;j2++) bfr[j2] = *(const s8v*)(&Bs[(j2*16 + l15)*40 + kof]);
    #pragma unroll
    for (int i2=0;i2<2;i2++)
      #pragma unroll
      for (int j2=0;j2<12;j2++)
        accA[i2][j2] = __builtin_amdgcn_mfma_f32_16x16x32_bf16(af[i2], bfr[j2], accA[i2][j2],0,0,0);
  }
  float b2l[12];
  #pragma unroll
  for (int j2=0;j2<12;j2++) b2l[j2] = p.b2[m*MIDW + j2*16 + l15];
  #pragma unroll
  for (int i2=0;i2<2;i2++)
    #pragma unroll
    for (int j2=0;j2<12;j2++)
      #pragma unroll
      for (int r=0;r<4;r++){
        int rl = wv*32 + i2*16 + hi*4 + r;
        h2s[rl*200 + j2*16 + l15] = (short)f2bf(fmaxf(accA[i2][j2][r] + b2l[j2], 0.f));
      }
  const short* Cg = (const short*)p.w3t + (long)m*HID*MIDW;
  f4v accB[2][8] = {};
  for (int kk=0; kk<MIDW; kk+=32){
    __syncthreads();
    #pragma unroll
    for (int j=0;j<2;j++){
      int c = t + j*256;
      int row = c>>2, sub = c&3;
      *(s8v*)(&Bs[row*40 + sub*8]) = *(const s8v*)(Cg + (long)row*MIDW + kk + sub*8);
    }
    __syncthreads();
    s8v af[2], bfr[8];
    #pragma unroll
    for (int i2=0;i2<2;i2++) af[i2] = *(const s8v*)(&h2s[(wv*32 + i2*16 + l15)*200 + kk + kof]);
    #pragma unroll
    for (int j2=0;j2<8;j2++) bfr[j2] = *(const s8v*)(&Bs[(j2*16 + l15)*40 + kof]);
    #pragma unroll
    for (int i2=0;i2<2;i2++)
      #pragma unroll
      for (int j2=0;j2<8;j2++)
        accB[i2][j2] = __builtin_amdgcn_mfma_f32_16x16x32_bf16(af[i2], bfr[j2], accB[i2][j2],0,0,0);
  }
  __syncthreads();
  #pragma unroll
  for (int j2=0;j2<8;j2++){
    float b3v = p.b3[m*HID + j2*16 + l15];
    #pragma unroll
    for (int i2=0;i2<2;i2++)
      #pragma unroll
      for (int r=0;r<4;r++){
        int rl = wv*32 + i2*16 + hi*4 + r;
        unsigned short hv = f2bf(accB[i2][j2][r] + b3v);
        p.pout[((long)(row0+rl))*(NCH*HID) + m*HID + j2*16 + l15] = *(bf16*)&hv;
        h2s[rl*200 + j2*16 + l15] = (short)hv;
      }
  }
  const short* Gg = (const short*)p.gt;
  f4v accC[2][8] = {};
  for (int kk=0; kk<HID; kk+=32){
    __syncthreads();
    #pragma unroll
    for (int j=0;j<2;j++){
      int c = t + j*256;
      int row = c>>2, sub = c&3;
      *(s8v*)(&Bs[row*40 + sub*8]) = *(const s8v*)(Gg + (long)row*HID + kk + sub*8);
    }
    __syncthreads();
    s8v af[2], bfr[8];
    #pragma unroll
    for (int i2=0;i2<2;i2++) af[i2] = *(const s8v*)(&h2s[(wv*32 + i2*16 + l15)*200 + kk + kof]);
    #pragma unroll
    for (int j2=0;j2<8;j2++) bfr[j2] = *(const s8v*)(&Bs[(j2*16 + l15)*40 + kof]);
    #pragma unroll
    for (int i2=0;i2<2;i2++)
      #pragma unroll
      for (int j2=0;j2<8;j2++)
        accC[i2][j2] = __builtin_amdgcn_mfma_f32_16x16x32_bf16(af[i2], bfr[j2], accC[i2][j2],0,0,0);
  }
  #pragma unroll
  for (int j2=0;j2<8;j2++)
    #pragma unroll
    for (int i2=0;i2<2;i2++)
      #pragma unroll
      for (int r=0;r<4;r++){
        long row = row0 + wv*32 + i2*16 + hi*4 + r;
        p.pgout[row*(NCH*HID) + m*HID + j2*16 + l15] = __float2bfloat16(accC[i2][j2][r]);
      }
}

// ---------------- per-node metapath attention (bilinear) ----------------
__global__ __launch_bounds__(64) void k_attn(
    const bf16* __restrict__ p_d, const bf16* __restrict__ pg_d, const float* __restrict__ v2v,
    const float* __restrict__ beta_d, bf16* __restrict__ o_d,
    const bf16* __restrict__ p_z, const bf16* __restrict__ pg_z,
    const float* __restrict__ beta_z, bf16* __restrict__ o_z)
{
  int node = blockIdx.x; int t = threadIdx.x;
  const bf16 *pp, *gg; bf16* outp; const float *betap, *v2p;
  if (node < ND){
    pp = p_d + (long)node*640; gg = pg_d + (long)node*640;
    outp = o_d + (long)node*640; betap = beta_d; v2p = v2v;
  } else {
    int nz = node - ND;
    pp = p_z + (long)nz*640; gg = pg_z + (long)nz*640;
    outp = o_z + (long)nz*640; betap = beta_z; v2p = v2v + 128;
  }
  __shared__ float pl[640], gl[640], v2l[128];
  __shared__ float lg[25], at[25], bv[5];
  const uint* pu = (const uint*)pp;
  const uint* gu = (const uint*)gg;
  for (int i=t; i<320; i+=64){
    uint w = pu[i];
    pl[2*i] = bfl(w); pl[2*i+1] = bfh(w);
    uint g = gu[i];
    gl[2*i] = bfl(g); gl[2*i+1] = bfh(g);
  }
  v2l[t] = v2p[t]; v2l[64+t] = v2p[64+t];
  __syncthreads();
  if (t < 60){
    int pr = t>>1, sub = t&1, h0 = sub*64;
    float s = 0.f;
    if (pr < 25){
      int mi = pr/5, ki = pr - 5*(pr/5);
      for (int h=h0; h<h0+64; h++) s += gl[mi*HID+h]*pl[ki*HID+h];
      s += __shfl_xor(s, 1);
      if (!sub) lg[pr] = s;
    } else {
      int k = pr - 25;
      for (int h=h0; h<h0+64; h++) s += pl[k*HID+h]*v2l[h];
      s += __shfl_xor(s, 1);
      if (!sub) bv[k] = s;
    }
  }
  __syncthreads();
  if (t < 5){
    float l0[5];
    for (int j=0;j<5;j++) l0[j] = lg[t*5+j] + bv[j];
    float mx = l0[0];
    for (int j=1;j<5;j++) mx = fmaxf(mx, l0[j]);
    float e[5], su=0.f;
    for (int j=0;j<5;j++){ e[j] = expf(l0[j]-mx); su += e[j]; }
    for (int j=0;j<5;j++) at[t*5+j] = e[j]/su;
  }
  __syncthreads();
  float bt = betap[0];
  for (int i=t; i<320; i+=64){
    int mm = i>>6, h = (i&63)*2;
    float s0=0.f, s1=0.f;
    #pragma unroll
    for (int k2=0;k2<5;k2++){
      s0 += at[mm*5+k2]*pl[k2*HID+h];
      s1 += at[mm*5+k2]*pl[k2*HID+h+1];
    }
    ((uint*)outp)[i] = packbf2(pl[2*i] + bt*s0, pl[2*i+1] + bt*s1);
  }
}

// ---------------- final GEMM ----------------
__global__ __launch_bounds__(256) void k_gemm_final(
    const bf16* __restrict__ Aout, const bf16* __restrict__ Bb, float* __restrict__ out)
{
  __shared__ short As[128*64];
  __shared__ short Bs[128*64];
  int t = threadIdx.x;
  int lane = t&63, wv=t>>6, wr=wv>>1, wc=wv&1;
  int row0 = blockIdx.x*128, col0 = blockIdx.y*128;
  const short* Ag = (const short*)Aout;
  const short* Bg = (const short*)Bb;
  int l15 = lane&15, hi = lane>>4;
  int srow = t>>3;
  int sseg = (t&7) ^ (srow&7);
  f4v acc[4][4] = {};
  for (int kk=0; kk<NCH*HID; kk+=64){
    int mch = kk>>7, h0 = kk&127;
    __syncthreads();
    #pragma unroll
    for (int j=0;j<4;j++){
      int row = j*32 + srow;
      gload16(Ag + ((long)mch*ND + row0+row)*HID + h0 + sseg*8,
              (char*)As + ((j*256 + t)<<4));
      gload16(Bg + (long)(col0+row)*(NCH*HID) + kk + sseg*8,
              (char*)Bs + ((j*256 + t)<<4));
    }
    asm volatile("s_waitcnt vmcnt(0)" ::: "memory");
    __syncthreads();
    #pragma unroll
    for (int sl=0; sl<2; sl++){
      s8v af[4], bg[4];
      #pragma unroll
      for (int i=0;i<4;i++){
        int ra = wr*64 + i*16 + l15;
        af[i] = *(const s8v*)(&As[ra*64 + (((sl*4+hi) ^ (ra&7))*8)]);
        int rb = wc*64 + i*16 + l15;
        bg[i] = *(const s8v*)(&Bs[rb*64 + (((sl*4+hi) ^ (rb&7))*8)]);
      }
      #pragma unroll
      for (int mi=0;mi<4;mi++)
        #pragma unroll
        for (int ni=0;ni<4;ni++)
          acc[mi][ni] = __builtin_amdgcn_mfma_f32_16x16x32_bf16(af[mi], bg[ni], acc[mi][ni],0,0,0);
    }
  }
  #pragma unroll
  for (int mi=0;mi<4;mi++){
    #pragma unroll
    for (int ni=0;ni<4;ni++){
      int col = col0 + wc*64 + ni*16 + l15;
      #pragma unroll
      for (int r=0;r<4;r++){
        int row = row0 + wr*64 + mi*16 + hi*4 + r;
        out[(long)row*NZ + col] = acc[mi][ni][r];
      }
    }
  }
}

extern "C" void kernel_launch(void* const* d_in, const int* in_sizes, int n_in,
                              void* d_out, int out_size, void* d_ws, size_t ws_size,
                              hipStream_t stream)
{
  (void)in_sizes; (void)n_in; (void)out_size;
  const float* feat_d = (const float*)d_in[0];
  const float* feat_z = (const float*)d_in[1];
  const float* att_d  = (const float*)d_in[2];
  const float* att_z  = (const float*)d_in[3];
  const int* src_d = (const int*)d_in[4];
  const int* dst_d = (const int*)d_in[5];
  const int* src_z = (const int*)d_in[6];
  const int* dst_z = (const int*)d_in[7];
  const float* dW1=(const float*)d_in[8];  const float* db1=(const float*)d_in[9];
  const float* dW2=(const float*)d_in[10]; const float* db2=(const float*)d_in[11];
  const float* dW3=(const float*)d_in[12]; const float* db3=(const float*)d_in[13];
  const float* Wq_d=(const float*)d_in[14]; const float* bq_d=(const float*)d_in[15];
  const float* Wk_d=(const float*)d_in[16]; const float* bk_d=(const float*)d_in[17];
  const float* beta_d=(const float*)d_in[18];
  const float* zW1=(const float*)d_in[19]; const float* zb1=(const float*)d_in[20];
  const float* zW2=(const float*)d_in[21]; const float* zb2=(const float*)d_in[22];
  const float* zW3=(const float*)d_in[23]; const float* zb3=(const float*)d_in[24];
  const float* Wq_z=(const float*)d_in[25]; const float* bq_z=(const float*)d_in[26];
  const float* Wk_z=(const float*)d_in[27]; const float* bk_z=(const float*)d_in[28];
  const float* beta_z=(const float*)d_in[29];
  const float* wattn=(const float*)d_in[30];
  const float* Wdec=(const float*)d_in[31]; const float* bdec=(const float*)d_in[32];
  (void)bk_d; (void)bk_z;

  char* ws = (char*)d_ws;
  size_t o = 0;
  auto alloc = [&](size_t bytes)->char*{
    size_t r = (o + 255) & ~(size_t)255;
    o = r + bytes;
    return ws + r;
  };
  // contiguity matters for aliasing below
  bf16* featb_d = (bf16*)alloc((size_t)ND*IN_DIM*2);      // 4.19 MB ┐
  bf16* featb_z = (bf16*)alloc((size_t)NZ*IN_DIM*2);      // 2.10 MB ├ pg_d (10.49) after agg2
  bf16* Y_d = (bf16*)alloc((size_t)NP*ND*MIDW*2);         // 6.29 MB ┘
  bf16* Y_z = (bf16*)alloc((size_t)NP*NZ*MIDW*2);         // 3.15 MB
  bf16* h1_d = (bf16*)alloc((size_t)NCH*ND*MIDW*2);       // out_d later
  bf16* h1_z = (bf16*)alloc((size_t)NCH*NZ*MIDW*2);       // out_z later
  bf16* pbuf_d = (bf16*)alloc((size_t)ND*NCH*HID*2);
  bf16* pbuf_z = (bf16*)alloc((size_t)NZ*NCH*HID*2);      // Bbig later
  bf16* pg_z = (bf16*)alloc((size_t)NZ*NCH*HID*2);
  ushort* csr_d = (ushort*)alloc((size_t)NP*E_D*2);       // 2.10 MB compact
  ushort* csr_z = (ushort*)alloc((size_t)NP*E_Z*2);       // 1.05 MB
  int* off_d = (int*)alloc((size_t)NP*(ND+1)*4);
  int* off_z = (int*)alloc((size_t)NP*(NZ+1)*4);
  bf16* w1t_d = (bf16*)alloc((size_t)NCH*MIDW*IN_DIM*2);
  bf16* w2t_d = (bf16*)alloc((size_t)NCH*MIDW*MIDW*2);
  bf16* w3t_d = (bf16*)alloc((size_t)NCH*HID*MIDW*2);
  bf16* w1t_z = (bf16*)alloc((size_t)NCH*MIDW*IN_DIM*2);
  bf16* w2t_z = (bf16*)alloc((size_t)NCH*MIDW*MIDW*2);
  bf16* w3t_z = (bf16*)alloc((size_t)NCH*HID*MIDW*2);
  bf16* Gtb = (bf16*)alloc((size_t)2*HID*HID*2);
  bf16* wdect = (bf16*)alloc((size_t)NCH*HID*HID*2);
  float* v2v = (float*)alloc((size_t)256*4);
  float* wsm = (float*)alloc((size_t)NCH*4);
  bf16* out_d = h1_d;
  bf16* out_z = h1_z;
  bf16* pg_d = featb_d;           // featb+Y_d region (12.58 MB >= 10.49), dead after agg2
  bf16* Bbig = pbuf_z;            // pbuf_z dead after attn
  if (ws_size < o) return;

  // CSR build: no global atomics anywhere (one block per metapath, LDS histogram+scan+cursor)
  k_csr<<<2*NP, 1024, 0, stream>>>(src_d, dst_d, off_d, csr_d,
                                   src_z, dst_z, off_z, csr_z);
  // prep: converts + transposes + G + v2
  k_prep<<<B_END, 256, 0, stream>>>(feat_d, feat_z, featb_d, featb_z,
      dW1, dW2, dW3, zW1, zW2, zW3,
      w1t_d, w2t_d, w3t_d, w1t_z, w2t_z, w3t_z,
      Wdec, wdect, Wq_d, Wk_d, Wq_z, Wk_z, Gtb,
      bq_d, bq_z, v2v, wattn, wsm);
  // stage 1: A1 + A2 GEMM
  k_stage1<<<dim3(64, 3, 10), 256, 0, stream>>>(featb_d, featb_z, w1t_d, w1t_z,
      db1, zb1, att_d, att_z, h1_d, h1_z, Y_d, Y_z);
  // aggregation -> h1 channels 1..4
  k_agg2<<<(NP*ND + NP*NZ)/4, 256, 0, stream>>>(csr_d, off_d, db1, Y_d, h1_d,
                                                csr_z, off_z, zb1, Y_z, h1_z);
  // fused MLP 2+3 + pg
  {
    MlpP pd = {h1_d, w2t_d, db2, w3t_d, db3, pbuf_d, pg_d, Gtb, ND};
    MlpP pz = {h1_z, w2t_z, zb2, w3t_z, zb3, pbuf_z, pg_z, Gtb + HID*HID, NZ};
    k_mlp23<<<dim3(64, 1, 10), 256, 0, stream>>>(pd, pz, 5);
  }
  // metapath attention
  k_attn<<<ND + NZ, 64, 0, stream>>>(pbuf_d, pg_d, v2v, beta_d, out_d,
                                     pbuf_z, pg_z, beta_z, out_z);
  // decoder
  {
    GemmP pz = {out_z, wdect, bdec, Bbig, wsm, nullptr, 0, (long)NZ*HID, (long)NCH*HID, HID, HID, HID, NZ, 0};
    k_gemm<<<dim3(32, 2, 5), 256, 0, stream>>>(pz, pz, 5);
  }
  // final
  k_gemm_final<<<dim3(64, 32), 256, 0, stream>>>(out_d, Bbig, (float*)d_out);
}

// Round 10
// 636.058 us; speedup vs baseline: 1.0842x; 1.0842x over previous
//
#include <hip/hip_runtime.h>
#include <hip/hip_bf16.h>

#define ND 8192
#define NZ 4096
#define IN_DIM 256
#define HID 128
#define MIDW 192
#define NP 4
#define NCH 5
#define DEG 32
#define E_D (ND*DEG)
#define E_Z (NZ*DEG)
#define CHUNK 8192
#define NB_D (E_D/CHUNK)   // 32
#define NB_Z (E_Z/CHUNK)   // 16
#define NCHK (NP*NB_D + NP*NB_Z)  // 192

typedef __hip_bfloat16 bf16;
typedef __attribute__((ext_vector_type(8))) short s8v;
typedef __attribute__((ext_vector_type(4))) float f4v;

static __device__ __forceinline__ unsigned short f2bf(float x){
  bf16 b = __float2bfloat16(x);
  return *reinterpret_cast<unsigned short*>(&b);
}
static __device__ __forceinline__ uint packbf2(float a, float b){
  return (uint)f2bf(a) | ((uint)f2bf(b) << 16);
}
static __device__ __forceinline__ float bfl(uint w){ return __uint_as_float(w<<16); }
static __device__ __forceinline__ float bfh(uint w){ return __uint_as_float(w & 0xffff0000u); }
static __device__ __forceinline__ void gload16(const void* g, void* l){
  __builtin_amdgcn_global_load_lds(
      (const __attribute__((address_space(1))) unsigned int*)g,
      (__attribute__((address_space(3))) unsigned int*)l, 16, 0, 0);
}

// ---------------- CSR phase 1: per-chunk LDS histogram -> bh ----------------
__global__ __launch_bounds__(256) void k_hist(
    const int* __restrict__ src_d, int* __restrict__ bh_d,
    const int* __restrict__ src_z, int* __restrict__ bh_z)
{
  __shared__ int hist[ND];
  int b = blockIdx.x, t = threadIdx.x;
  const int* src; int* bh; int n;
  if (b < NP*NB_D){
    int mp = b >> 5, ch = b & (NB_D-1);
    src = src_d + (long)mp*E_D + ch*CHUNK;
    bh = bh_d + ((long)mp*NB_D + ch)*ND;
    n = ND;
  } else {
    int b2 = b - NP*NB_D;
    int mp = b2 >> 4, ch = b2 & (NB_Z-1);
    src = src_z + (long)mp*E_Z + ch*CHUNK;
    bh = bh_z + ((long)mp*NB_Z + ch)*NZ;
    n = NZ;
  }
  for (int i=t; i<n; i+=256) hist[i] = 0;
  __syncthreads();
  for (int e=t; e<CHUNK; e+=256) atomicAdd(&hist[src[e]], 1);
  __syncthreads();
  for (int i=t; i<n; i+=256) bh[i] = hist[i];
}

// ---------------- CSR phase 2: cross-chunk + cross-node scan -> off + bases ----------------
__global__ __launch_bounds__(1024) void k_off(
    int* __restrict__ bh_d, int* __restrict__ off_d,
    int* __restrict__ bh_z, int* __restrict__ off_z)
{
  int b = blockIdx.x, t = threadIdx.x;
  int *bh, *off; int n, NB, E;
  if (b < NP){ bh = bh_d + (long)b*NB_D*ND; off = off_d + (long)b*(ND+1); n = ND; NB = NB_D; E = E_D; }
  else { int m = b-NP; bh = bh_z + (long)m*NB_Z*NZ; off = off_z + (long)m*(NZ+1); n = NZ; NB = NB_Z; E = E_Z; }
  int cnt = n >> 10;            // 8 (drug) or 4 (disease) nodes per thread
  int base = t*cnt;
  int tot[8], loc[8];
  for (int j=0;j<cnt;j++){
    int s = base+j;
    int running = 0;
    for (int bb=0; bb<NB; bb++){
      int v = bh[bb*n + s];
      bh[bb*n + s] = running;   // chunk-local exclusive base (pre node-offset)
      running += v;
    }
    tot[j] = running;
  }
  int sum = 0;
  for (int j=0;j<cnt;j++){ loc[j] = sum; sum += tot[j]; }
  int lane = t&63, wv = t>>6;
  __shared__ int wpart[16];
  int x = sum;
  #pragma unroll
  for (int s2=1; s2<64; s2<<=1){
    int u = __shfl_up(x, s2, 64);
    if (lane >= s2) x += u;
  }
  if (lane==63) wpart[wv] = x;
  __syncthreads();
  int wo = 0;
  for (int w=0; w<wv; w++) wo += wpart[w];
  int tbase = wo + x - sum;
  for (int j=0;j<cnt;j++){
    int s = base+j;
    int o0 = tbase + loc[j];
    off[s] = o0;
    for (int bb=0; bb<NB; bb++) bh[bb*n + s] += o0;
  }
  if (t==0) off[n] = E;
}

// ---------------- CSR phase 3: chunk scatter via LDS cursors, plain stores ----------------
__global__ __launch_bounds__(256) void k_scat2(
    const int* __restrict__ src_d, const int* __restrict__ dst_d,
    const int* __restrict__ bh_d, ushort* __restrict__ csr_d,
    const int* __restrict__ src_z, const int* __restrict__ dst_z,
    const int* __restrict__ bh_z, ushort* __restrict__ csr_z)
{
  __shared__ int cur[ND];
  int b = blockIdx.x, t = threadIdx.x;
  const int *src, *dst, *bh; ushort* csr; int n;
  if (b < NP*NB_D){
    int mp = b >> 5, ch = b & (NB_D-1);
    src = src_d + (long)mp*E_D + ch*CHUNK;
    dst = dst_d + (long)mp*E_D + ch*CHUNK;
    bh = bh_d + ((long)mp*NB_D + ch)*ND;
    csr = csr_d + (long)mp*E_D;
    n = ND;
  } else {
    int b2 = b - NP*NB_D;
    int mp = b2 >> 4, ch = b2 & (NB_Z-1);
    src = src_z + (long)mp*E_Z + ch*CHUNK;
    dst = dst_z + (long)mp*E_Z + ch*CHUNK;
    bh = bh_z + ((long)mp*NB_Z + ch)*NZ;
    csr = csr_z + (long)mp*E_Z;
    n = NZ;
  }
  for (int i=t; i<n; i+=256) cur[i] = bh[i];
  __syncthreads();
  for (int e=t; e<CHUNK; e+=256){
    int s = src[e];
    int pos = atomicAdd(&cur[s], 1);
    csr[pos] = (ushort)dst[e];
  }
}

// ---------------- mega prep: cvts + transposes + G + v2 ----------------
static __device__ __forceinline__ void tpz(const float* __restrict__ in, bf16* __restrict__ out,
                                           int rows, int cols, long idx){
  int per = rows*cols;
  int b = (int)(idx / per);
  int rem = (int)(idx - (long)b*per);
  int r = rem / cols, c = rem - r*cols;
  out[(long)b*per + (long)c*rows + r] = __float2bfloat16(in[idx]);
}

#define B_CVD 2048
#define B_CVZ (B_CVD+1024)     // 3072
#define B_W1D (B_CVZ+960)      // 4032
#define B_W1Z (B_W1D+960)      // 4992
#define B_W2D (B_W1Z+720)      // 5712
#define B_W2Z (B_W2D+720)      // 6432
#define B_W3D (B_W2Z+480)      // 6912
#define B_W3Z (B_W3D+480)      // 7392
#define B_WDEC (B_W3Z+320)     // 7712
#define B_G (B_WDEC+128)       // 7840
#define B_END (B_G+1)          // 7841

__global__ __launch_bounds__(256) void k_prep(
    const float* feat_d, const float* feat_z, bf16* featb_d, bf16* featb_z,
    const float* dW1, const float* dW2, const float* dW3,
    const float* zW1, const float* zW2, const float* zW3,
    bf16* w1t_d, bf16* w2t_d, bf16* w3t_d, bf16* w1t_z, bf16* w2t_z, bf16* w3t_z,
    const float* Wdec, bf16* wdect,
    const float* Wq_d, const float* Wk_d, const float* Wq_z, const float* Wk_z,
    bf16* Gtb,
    const float* bq_d, const float* bq_z, float* v2v,
    const float* wattn, float* wsm)
{
  int b = blockIdx.x, t = threadIdx.x;
  if (b < B_CVD){
    long i4 = (long)b*256 + t;
    float4 v = ((const float4*)feat_d)[i4];
    ushort4 o; o.x=f2bf(v.x); o.y=f2bf(v.y); o.z=f2bf(v.z); o.w=f2bf(v.w);
    ((ushort4*)featb_d)[i4] = o;
  } else if (b < B_CVZ){
    long i4 = (long)(b - B_CVD)*256 + t;
    float4 v = ((const float4*)feat_z)[i4];
    ushort4 o; o.x=f2bf(v.x); o.y=f2bf(v.y); o.z=f2bf(v.z); o.w=f2bf(v.w);
    ((ushort4*)featb_z)[i4] = o;
  } else if (b < B_W1D){ tpz(dW1, w1t_d, IN_DIM, MIDW, (long)(b-B_CVZ)*256 + t); }
  else if (b < B_W1Z){ tpz(zW1, w1t_z, IN_DIM, MIDW, (long)(b-B_W1D)*256 + t); }
  else if (b < B_W2D){ tpz(dW2, w2t_d, MIDW, MIDW, (long)(b-B_W1Z)*256 + t); }
  else if (b < B_W2Z){ tpz(zW2, w2t_z, MIDW, MIDW, (long)(b-B_W2D)*256 + t); }
  else if (b < B_W3D){ tpz(dW3, w3t_d, MIDW, HID, (long)(b-B_W2Z)*256 + t); }
  else if (b < B_W3Z){ tpz(zW3, w3t_z, MIDW, HID, (long)(b-B_W3D)*256 + t); }
  else if (b < B_WDEC){ tpz(Wdec, wdect, HID, HID, (long)(b-B_W3Z)*256 + t); }
  else if (b < B_G){
    // Gt[c,h'] = sum_j Wq[h',j]*Wk[c,j]
    int cc = (b - B_WDEC)*2 + (t>>7);
    int hp = t & 127;
    const float* Wq = cc < 128 ? Wq_d : Wq_z;
    const float* Wk = cc < 128 ? Wk_d : Wk_z;
    int c = cc & 127;
    float s = 0.f;
    for (int j=0;j<HID;j++) s += Wq[hp*HID+j]*Wk[c*HID+j];
    Gtb[(cc < 128 ? 0 : HID*HID) + c*HID + hp] = __float2bfloat16(s);
  } else {
    if (t < 128){
      float s = 0.f;
      for (int j=0;j<HID;j++) s += Wk_d[t*HID+j]*bq_d[j];
      v2v[t] = s;
    } else {
      int tt = t-128;
      float s = 0.f;
      for (int j=0;j<HID;j++) s += Wk_z[tt*HID+j]*bq_z[j];
      v2v[128+tt] = s;
    }
    if (t == 0){
      float mx = wattn[0];
      for (int i=1;i<NCH;i++) mx = fmaxf(mx, wattn[i]);
      float e[NCH], s=0.f;
      for (int i=0;i<NCH;i++){ e[i]=expf(wattn[i]-mx); s+=e[i]; }
      for (int i=0;i<NCH;i++) wsm[i]=e[i]/s;
    }
  }
}

// ---------------- stage 1: (A1 | A2) GEMM, z = type*5 + channel ----------------
__global__ __launch_bounds__(256) void k_stage1(
    const bf16* __restrict__ featb_d, const bf16* __restrict__ featb_z,
    const bf16* __restrict__ w1t_d, const bf16* __restrict__ w1t_z,
    const float* __restrict__ db1, const float* __restrict__ zb1,
    const float* __restrict__ att_d, const float* __restrict__ att_z,
    bf16* __restrict__ h1_d, bf16* __restrict__ h1_z,
    bf16* __restrict__ Y_d, bf16* __restrict__ Y_z)
{
  int z = blockIdx.z, typ = z/5, c = z - 5*(z/5);
  int n = typ ? NZ : ND;
  long row0 = (long)blockIdx.x*128;
  if (row0 >= n) return;
  int col0 = blockIdx.y*64;
  __shared__ short As[128*40];
  __shared__ short Bs[64*40];
  int t = threadIdx.x, lane = t&63, wv = t>>6;
  int l15 = lane&15, kof = (lane>>4)*8;
  const short* Ag = (const short*)(typ ? featb_z : featb_d);
  const short* Bg = (const short*)(typ ? w1t_z : w1t_d) + (long)c*MIDW*IN_DIM;
  f4v acc[2][4] = {};
  for (int kk=0; kk<IN_DIM; kk+=32){
    __syncthreads();
    #pragma unroll
    for (int j=0;j<2;j++){
      int c2 = t + j*256;
      int row = c2>>2, sub = c2&3;
      *(s8v*)(&As[row*40 + sub*8]) = *(const s8v*)(Ag + (row0+row)*IN_DIM + kk + sub*8);
    }
    { int row = t>>2, sub = t&3;
      *(s8v*)(&Bs[row*40 + sub*8]) = *(const s8v*)(Bg + (long)(col0+row)*IN_DIM + kk + sub*8); }
    __syncthreads();
    s8v af[2], bfr[4];
    #pragma unroll
    for (int i2=0;i2<2;i2++) af[i2] = *(const s8v*)(&As[(wv*32 + i2*16 + l15)*40 + kof]);
    #pragma unroll
    for (int j2=0;j2<4;j2++) bfr[j2] = *(const s8v*)(&Bs[(j2*16 + l15)*40 + kof]);
    #pragma unroll
    for (int i2=0;i2<2;i2++)
      #pragma unroll
      for (int j2=0;j2<4;j2++)
        acc[i2][j2] = __builtin_amdgcn_mfma_f32_16x16x32_bf16(af[i2], bfr[j2], acc[i2][j2],0,0,0);
  }
  if (c == 0){
    const float* bb = typ ? zb1 : db1;
    bf16* outp = typ ? h1_z : h1_d;
    #pragma unroll
    for (int i2=0;i2<2;i2++)
      #pragma unroll
      for (int j2=0;j2<4;j2++){
        int col = col0 + j2*16 + l15;
        float bv = bb[col];
        #pragma unroll
        for (int r=0;r<4;r++){
          long row = row0 + wv*32 + i2*16 + (lane>>4)*4 + r;
          outp[row*MIDW + col] = __float2bfloat16(fmaxf(acc[i2][j2][r] + bv, 0.f));
        }
      }
  } else {
    const float* rs = (typ ? att_z : att_d) + (long)(c-1)*n;
    bf16* outp = (typ ? Y_z : Y_d) + (long)(c-1)*n*MIDW;
    #pragma unroll
    for (int i2=0;i2<2;i2++)
      #pragma unroll
      for (int j2=0;j2<4;j2++){
        int col = col0 + j2*16 + l15;
        #pragma unroll
        for (int r=0;r<4;r++){
          long row = row0 + wv*32 + i2*16 + (lane>>4)*4 + r;
          outp[row*MIDW + col] = __float2bfloat16(acc[i2][j2][r] * rs[row]);
        }
      }
  }
}

// ---------------- aggregation (compact ushort CSR) ----------------
__global__ __launch_bounds__(256) void k_agg2(
    const ushort* __restrict__ csr_d, const int* __restrict__ off_d, const float* __restrict__ bias_d,
    const bf16* __restrict__ Y_d, bf16* __restrict__ h1_d,
    const ushort* __restrict__ csr_z, const int* __restrict__ off_z, const float* __restrict__ bias_z,
    const bf16* __restrict__ Y_z, bf16* __restrict__ h1_z)
{
  int wid = (blockIdx.x*256 + threadIdx.x) >> 6;
  int lane = threadIdx.x & 63;
  const ushort* csr; const int* off; const float* bias; const uint* Yb; bf16* h1; int n, m; long ebase;
  if (wid < NP*ND){
    m = wid >> 13; int s0 = wid & (ND-1);
    csr = csr_d; off = off_d + (long)m*(ND+1); bias = bias_d; h1 = h1_d; n = ND;
    Yb = (const uint*)Y_d + (long)m*ND*96;
    ebase = (long)m*E_D;
    wid = s0;
  } else {
    int w2 = wid - NP*ND;
    m = w2 >> 12; int s0 = w2 & (NZ-1);
    csr = csr_z; off = off_z + (long)m*(NZ+1); bias = bias_z; h1 = h1_z; n = NZ;
    Yb = (const uint*)Y_z + (long)m*NZ*96;
    ebase = (long)m*E_Z;
    wid = s0;
  }
  int s = wid;
  int o0 = off[s], o1 = off[s+1];
  int cnt = o1 - o0;
  const ushort* lp = csr + ebase + o0;
  bool hi2 = lane < 32;
  float a0=0.f,a1=0.f,a2=0.f,a3=0.f;
  for (int base=0; base<cnt; base+=64){
    int rem = cnt - base;
    int idx = (lane < rem) ? lane : (rem-1);
    int e = lp[base + idx];
    int lim = rem < 64 ? rem : 64;
    int j = 0;
    for (; j+1<lim; j+=2){
      int d0 = __shfl(e, j), d1 = __shfl(e, j+1);
      const uint* r0 = Yb + (long)d0*96;
      const uint* r1 = Yb + (long)d1*96;
      uint w0 = r0[lane], w1 = r1[lane];
      uint v0 = hi2 ? r0[64+lane] : 0u;
      uint v1 = hi2 ? r1[64+lane] : 0u;
      a0 += bfl(w0)+bfl(w1); a1 += bfh(w0)+bfh(w1);
      a2 += bfl(v0)+bfl(v1); a3 += bfh(v0)+bfh(v1);
    }
    if (j < lim){
      int d0 = __shfl(e, j);
      const uint* r0 = Yb + (long)d0*96;
      uint w0 = r0[lane];
      uint v0 = hi2 ? r0[64+lane] : 0u;
      a0 += bfl(w0); a1 += bfh(w0);
      a2 += bfl(v0); a3 += bfh(v0);
    }
  }
  float inv = 1.0f / fmaxf((float)cnt, 1.0f);
  const float* bb = bias + (m+1)*MIDW;
  float2 b0 = *(const float2*)(bb + 2*lane);
  uint* hrow = (uint*)((short*)h1 + ((long)(m+1)*n + s)*MIDW);
  hrow[lane] = packbf2(fmaxf(a0*inv + b0.x, 0.f), fmaxf(a1*inv + b0.y, 0.f));
  if (hi2){
    float2 b1v = *(const float2*)(bb + 128 + 2*lane);
    hrow[64+lane] = packbf2(fmaxf(a2*inv + b1v.x, 0.f), fmaxf(a3*inv + b1v.y, 0.f));
  }
}

// ---------------- generic batched GEMM (decoder) ----------------
struct GemmP {
  const bf16* A; const bf16* BT; const float* bias; bf16* out;
  const float* scale; const float* rowsc;
  long rs_moff, a_moff, out_rstride, out_moff;
  int K, N, nrows, relu;
};

__global__ __launch_bounds__(256) void k_gemm(GemmP P0, GemmP P1, int zsplit)
{
  const GemmP& p = ((int)blockIdx.z < zsplit) ? P0 : P1;
  int m = ((int)blockIdx.z < zsplit) ? blockIdx.z : blockIdx.z - zsplit;
  long row0 = (long)blockIdx.x*128;
  if (row0 >= p.nrows) return;
  int col0 = blockIdx.y*64;
  if (col0 >= p.N) return;
  __shared__ short As[128*40];
  __shared__ short Bs[64*40];
  int t = threadIdx.x;
  const short* Ag = (const short*)p.A + m*p.a_moff;
  const short* Bg = (const short*)p.BT + (long)m*p.N*p.K;
  int lane = t&63, wv = t>>6;
  int l15 = lane&15, kof = (lane>>4)*8;
  int K = p.K;
  f4v acc[2][4] = {};
  for (int kk=0; kk<K; kk+=32){
    __syncthreads();
    #pragma unroll
    for (int j=0;j<2;j++){
      int c = t + j*256;
      int row = c>>2, sub = c&3;
      *(s8v*)(&As[row*40 + sub*8]) = *(const s8v*)(Ag + (row0+row)*K + kk + sub*8);
    }
    { int row = t>>2, sub = t&3;
      *(s8v*)(&Bs[row*40 + sub*8]) = *(const s8v*)(Bg + (long)(col0+row)*K + kk + sub*8); }
    __syncthreads();
    s8v af[2], bfr[4];
    #pragma unroll
    for (int i2=0;i2<2;i2++) af[i2] = *(const s8v*)(&As[(wv*32 + i2*16 + l15)*40 + kof]);
    #pragma unroll
    for (int j2=0;j2<4;j2++) bfr[j2] = *(const s8v*)(&Bs[(j2*16 + l15)*40 + kof]);
    #pragma unroll
    for (int i2=0;i2<2;i2++)
      #pragma unroll
      for (int j2=0;j2<4;j2++)
        acc[i2][j2] = __builtin_amdgcn_mfma_f32_16x16x32_bf16(af[i2], bfr[j2], acc[i2][j2],0,0,0);
  }
  float sc = p.scale ? p.scale[m] : 1.0f;
  #pragma unroll
  for (int i2=0;i2<2;i2++){
    #pragma unroll
    for (int j2=0;j2<4;j2++){
      int col = col0 + j2*16 + l15;
      float bv = p.bias ? p.bias[m*p.N + col] : 0.f;
      #pragma unroll
      for (int r=0;r<4;r++){
        long row = row0 + wv*32 + i2*16 + (lane>>4)*4 + r;
        float v = acc[i2][j2][r] + bv;
        if (p.relu) v = fmaxf(v, 0.f);
        v *= sc;
        if (p.rowsc) v *= p.rowsc[m*p.rs_moff + row];
        p.out[m*p.out_moff + row*p.out_rstride + col] = __float2bfloat16(v);
      }
    }
  }
}

// ---------------- fused MLP 2+3 + pg ----------------
struct MlpP { const bf16* h1; const bf16* w2t; const float* b2;
              const bf16* w3t; const float* b3; bf16* pout; bf16* pgout;
              const bf16* gt; int n; };

__global__ __launch_bounds__(256) void k_mlp23(MlpP P0, MlpP P1, int zsplit)
{
  const MlpP& p = ((int)blockIdx.z < zsplit) ? P0 : P1;
  int m = ((int)blockIdx.z < zsplit) ? blockIdx.z : blockIdx.z - zsplit;
  int row0 = blockIdx.x*128;
  if (row0 >= p.n) return;
  __shared__ short h2s[128*200];
  __shared__ short As[128*40];
  __shared__ short Bs[192*40];
  int t = threadIdx.x, lane = t&63, wv = t>>6;
  int l15 = lane&15, hi = lane>>4, kof = hi*8;
  const short* Ag = (const short*)p.h1 + ((long)m*p.n + row0)*MIDW;
  const short* Bg = (const short*)p.w2t + (long)m*MIDW*MIDW;
  f4v accA[2][12] = {};
  for (int kk=0; kk<MIDW; kk+=32){
    __syncthreads();
    #pragma unroll
    for (int j=0;j<2;j++){
      int c = t + j*256;
      int row = c>>2, sub = c&3;
      *(s8v*)(&As[row*40 + sub*8]) = *(const s8v*)(Ag + (long)row*MIDW + kk + sub*8);
    }
    #pragma unroll
    for (int j=0;j<3;j++){
      int c = t + j*256;
      int row = c>>2, sub = c&3;
      *(s8v*)(&Bs[row*40 + sub*8]) = *(const s8v*)(Bg + (long)row*MIDW + kk + sub*8);
    }
    __syncthreads();
    s8v af[2], bfr[12];
    #pragma unroll
    for (int i2=0;i2<2;i2++) af[i2] = *(const s8v*)(&As[(wv*32 + i2*16 + l15)*40 + kof]);
    #pragma unroll
    for (int j2=0;j2<12;j2++) bfr[j2] = *(const s8v*)(&Bs[(j2*16 + l15)*40 + kof]);
    #pragma unroll
    for (int i2=0;i2<2;i2++)
      #pragma unroll
      for (int j2=0;j2<12;j2++)
        accA[i2][j2] = __builtin_amdgcn_mfma_f32_16x16x32_bf16(af[i2], bfr[j2], accA[i2][j2],0,0,0);
  }
  float b2l[12];
  #pragma unroll
  for (int j2=0;j2<12;j2++) b2l[j2] = p.b2[m*MIDW + j2*16 + l15];
  #pragma unroll
  for (int i2=0;i2<2;i2++)
    #pragma unroll
    for (int j2=0;j2<12;j2++)
      #pragma unroll
      for (int r=0;r<4;r++){
        int rl = wv*32 + i2*16 + hi*4 + r;
        h2s[rl*200 + j2*16 + l15] = (short)f2bf(fmaxf(accA[i2][j2][r] + b2l[j2], 0.f));
      }
  const short* Cg = (const short*)p.w3t + (long)m*HID*MIDW;
  f4v accB[2][8] = {};
  for (int kk=0; kk<MIDW; kk+=32){
    __syncthreads();
    #pragma unroll
    for (int j=0;j<2;j++){
      int c = t + j*256;
      int row = c>>2, sub = c&3;
      *(s8v*)(&Bs[row*40 + sub*8]) = *(const s8v*)(Cg + (long)row*MIDW + kk + sub*8);
    }
    __syncthreads();
    s8v af[2], bfr[8];
    #pragma unroll
    for (int i2=0;i2<2;i2++) af[i2] = *(const s8v*)(&h2s[(wv*32 + i2*16 + l15)*200 + kk + kof]);
    #pragma unroll
    for (int j2=0;j2<8;j2++) bfr[j2] = *(const s8v*)(&Bs[(j2*16 + l15)*40 + kof]);
    #pragma unroll
    for (int i2=0;i2<2;i2++)
      #pragma unroll
      for (int j2=0;j2<8;j2++)
        accB[i2][j2] = __builtin_amdgcn_mfma_f32_16x16x32_bf16(af[i2], bfr[j2], accB[i2][j2],0,0,0);
  }
  __syncthreads();
  #pragma unroll
  for (int j2=0;j2<8;j2++){
    float b3v = p.b3[m*HID + j2*16 + l15];
    #pragma unroll
    for (int i2=0;i2<2;i2++)
      #pragma unroll
      for (int r=0;r<4;r++){
        int rl = wv*32 + i2*16 + hi*4 + r;
        unsigned short hv = f2bf(accB[i2][j2][r] + b3v);
        p.pout[((long)(row0+rl))*(NCH*HID) + m*HID + j2*16 + l15] = *(bf16*)&hv;
        h2s[rl*200 + j2*16 + l15] = (short)hv;
      }
  }
  const short* Gg = (const short*)p.gt;
  f4v accC[2][8] = {};
  for (int kk=0; kk<HID; kk+=32){
    __syncthreads();
    #pragma unroll
    for (int j=0;j<2;j++){
      int c = t + j*256;
      int row = c>>2, sub = c&3;
      *(s8v*)(&Bs[row*40 + sub*8]) = *(const s8v*)(Gg + (long)row*HID + kk + sub*8);
    }
    __syncthreads();
    s8v af[2], bfr[8];
    #pragma unroll
    for (int i2=0;i2<2;i2++) af[i2] = *(const s8v*)(&h2s[(wv*32 + i2*16 + l15)*200 + kk + kof]);
    #pragma unroll
    for (int j2=0;j2<8;j2++) bfr[j2] = *(const s8v*)(&Bs[(j2*16 + l15)*40 + kof]);
    #pragma unroll
    for (int i2=0;i2<2;i2++)
      #pragma unroll
      for (int j2=0;j2<8;j2++)
        accC[i2][j2] = __builtin_amdgcn_mfma_f32_16x16x32_bf16(af[i2], bfr[j2], accC[i2][j2],0,0,0);
  }
  #pragma unroll
  for (int j2=0;j2<8;j2++)
    #pragma unroll
    for (int i2=0;i2<2;i2++)
      #pragma unroll
      for (int r=0;r<4;r++){
        long row = row0 + wv*32 + i2*16 + hi*4 + r;
        p.pgout[row*(NCH*HID) + m*HID + j2*16 + l15] = __float2bfloat16(accC[i2][j2][r]);
      }
}

// ---------------- per-node metapath attention (bilinear) ----------------
__global__ __launch_bounds__(64) void k_attn(
    const bf16* __restrict__ p_d, const bf16* __restrict__ pg_d, const float* __restrict__ v2v,
    const float* __restrict__ beta_d, bf16* __restrict__ o_d,
    const bf16* __restrict__ p_z, const bf16* __restrict__ pg_z,
    const float* __restrict__ beta_z, bf16* __restrict__ o_z)
{
  int node = blockIdx.x; int t = threadIdx.x;
  const bf16 *pp, *gg; bf16* outp; const float *betap, *v2p;
  if (node < ND){
    pp = p_d + (long)node*640; gg = pg_d + (long)node*640;
    outp = o_d + (long)node*640; betap = beta_d; v2p = v2v;
  } else {
    int nz = node - ND;
    pp = p_z + (long)nz*640; gg = pg_z + (long)nz*640;
    outp = o_z + (long)nz*640; betap = beta_z; v2p = v2v + 128;
  }
  __shared__ float pl[640], gl[640], v2l[128];
  __shared__ float lg[25], at[25], bv[5];
  const uint* pu = (const uint*)pp;
  const uint* gu = (const uint*)gg;
  for (int i=t; i<320; i+=64){
    uint w = pu[i];
    pl[2*i] = bfl(w); pl[2*i+1] = bfh(w);
    uint g = gu[i];
    gl[2*i] = bfl(g); gl[2*i+1] = bfh(g);
  }
  v2l[t] = v2p[t]; v2l[64+t] = v2p[64+t];
  __syncthreads();
  if (t < 60){
    int pr = t>>1, sub = t&1, h0 = sub*64;
    float s = 0.f;
    if (pr < 25){
      int mi = pr/5, ki = pr - 5*(pr/5);
      for (int h=h0; h<h0+64; h++) s += gl[mi*HID+h]*pl[ki*HID+h];
      s += __shfl_xor(s, 1);
      if (!sub) lg[pr] = s;
    } else {
      int k = pr - 25;
      for (int h=h0; h<h0+64; h++) s += pl[k*HID+h]*v2l[h];
      s += __shfl_xor(s, 1);
      if (!sub) bv[k] = s;
    }
  }
  __syncthreads();
  if (t < 5){
    float l0[5];
    for (int j=0;j<5;j++) l0[j] = lg[t*5+j] + bv[j];
    float mx = l0[0];
    for (int j=1;j<5;j++) mx = fmaxf(mx, l0[j]);
    float e[5], su=0.f;
    for (int j=0;j<5;j++){ e[j] = expf(l0[j]-mx); su += e[j]; }
    for (int j=0;j<5;j++) at[t*5+j] = e[j]/su;
  }
  __syncthreads();
  float bt = betap[0];
  for (int i=t; i<320; i+=64){
    int mm = i>>6, h = (i&63)*2;
    float s0=0.f, s1=0.f;
    #pragma unroll
    for (int k2=0;k2<5;k2++){
      s0 += at[mm*5+k2]*pl[k2*HID+h];
      s1 += at[mm*5+k2]*pl[k2*HID+h+1];
    }
    ((uint*)outp)[i] = packbf2(pl[2*i] + bt*s0, pl[2*i+1] + bt*s1);
  }
}

// ---------------- final GEMM ----------------
__global__ __launch_bounds__(256) void k_gemm_final(
    const bf16* __restrict__ Aout, const bf16* __restrict__ Bb, float* __restrict__ out)
{
  __shared__ short As[128*64];
  __shared__ short Bs[128*64];
  int t = threadIdx.x;
  int lane = t&63, wv=t>>6, wr=wv>>1, wc=wv&1;
  int row0 = blockIdx.x*128, col0 = blockIdx.y*128;
  const short* Ag = (const short*)Aout;
  const short* Bg = (const short*)Bb;
  int l15 = lane&15, hi = lane>>4;
  int srow = t>>3;
  int sseg = (t&7) ^ (srow&7);
  f4v acc[4][4] = {};
  for (int kk=0; kk<NCH*HID; kk+=64){
    int mch = kk>>7, h0 = kk&127;
    __syncthreads();
    #pragma unroll
    for (int j=0;j<4;j++){
      int row = j*32 + srow;
      gload16(Ag + ((long)mch*ND + row0+row)*HID + h0 + sseg*8,
              (char*)As + ((j*256 + t)<<4));
      gload16(Bg + (long)(col0+row)*(NCH*HID) + kk + sseg*8,
              (char*)Bs + ((j*256 + t)<<4));
    }
    asm volatile("s_waitcnt vmcnt(0)" ::: "memory");
    __syncthreads();
    #pragma unroll
    for (int sl=0; sl<2; sl++){
      s8v af[4], bg[4];
      #pragma unroll
      for (int i=0;i<4;i++){
        int ra = wr*64 + i*16 + l15;
        af[i] = *(const s8v*)(&As[ra*64 + (((sl*4+hi) ^ (ra&7))*8)]);
        int rb = wc*64 + i*16 + l15;
        bg[i] = *(const s8v*)(&Bs[rb*64 + (((sl*4+hi) ^ (rb&7))*8)]);
      }
      #pragma unroll
      for (int mi=0;mi<4;mi++)
        #pragma unroll
        for (int ni=0;ni<4;ni++)
          acc[mi][ni] = __builtin_amdgcn_mfma_f32_16x16x32_bf16(af[mi], bg[ni], acc[mi][ni],0,0,0);
    }
  }
  #pragma unroll
  for (int mi=0;mi<4;mi++){
    #pragma unroll
    for (int ni=0;ni<4;ni++){
      int col = col0 + wc*64 + ni*16 + l15;
      #pragma unroll
      for (int r=0;r<4;r++){
        int row = row0 + wr*64 + mi*16 + hi*4 + r;
        out[(long)row*NZ + col] = acc[mi][ni][r];
      }
    }
  }
}

extern "C" void kernel_launch(void* const* d_in, const int* in_sizes, int n_in,
                              void* d_out, int out_size, void* d_ws, size_t ws_size,
                              hipStream_t stream)
{
  (void)in_sizes; (void)n_in; (void)out_size;
  const float* feat_d = (const float*)d_in[0];
  const float* feat_z = (const float*)d_in[1];
  const float* att_d  = (const float*)d_in[2];
  const float* att_z  = (const float*)d_in[3];
  const int* src_d = (const int*)d_in[4];
  const int* dst_d = (const int*)d_in[5];
  const int* src_z = (const int*)d_in[6];
  const int* dst_z = (const int*)d_in[7];
  const float* dW1=(const float*)d_in[8];  const float* db1=(const float*)d_in[9];
  const float* dW2=(const float*)d_in[10]; const float* db2=(const float*)d_in[11];
  const float* dW3=(const float*)d_in[12]; const float* db3=(const float*)d_in[13];
  const float* Wq_d=(const float*)d_in[14]; const float* bq_d=(const float*)d_in[15];
  const float* Wk_d=(const float*)d_in[16]; const float* bk_d=(const float*)d_in[17];
  const float* beta_d=(const float*)d_in[18];
  const float* zW1=(const float*)d_in[19]; const float* zb1=(const float*)d_in[20];
  const float* zW2=(const float*)d_in[21]; const float* zb2=(const float*)d_in[22];
  const float* zW3=(const float*)d_in[23]; const float* zb3=(const float*)d_in[24];
  const float* Wq_z=(const float*)d_in[25]; const float* bq_z=(const float*)d_in[26];
  const float* Wk_z=(const float*)d_in[27]; const float* bk_z=(const float*)d_in[28];
  const float* beta_z=(const float*)d_in[29];
  const float* wattn=(const float*)d_in[30];
  const float* Wdec=(const float*)d_in[31]; const float* bdec=(const float*)d_in[32];
  (void)bk_d; (void)bk_z;

  char* ws = (char*)d_ws;
  size_t o = 0;
  auto alloc = [&](size_t bytes)->char*{
    size_t r = (o + 255) & ~(size_t)255;
    o = r + bytes;
    return ws + r;
  };
  // contiguity matters for aliasing below
  bf16* featb_d = (bf16*)alloc((size_t)ND*IN_DIM*2);      // 4.19 MB ┐
  bf16* featb_z = (bf16*)alloc((size_t)NZ*IN_DIM*2);      // 2.10 MB ├ pg_d (10.49) after agg2
  bf16* Y_d = (bf16*)alloc((size_t)NP*ND*MIDW*2);         // 6.29 MB ┘
  bf16* Y_z = (bf16*)alloc((size_t)NP*NZ*MIDW*2);         // 3.15 MB
  bf16* h1_d = (bf16*)alloc((size_t)NCH*ND*MIDW*2);       // out_d later
  bf16* h1_z = (bf16*)alloc((size_t)NCH*NZ*MIDW*2);       // out_z later
  bf16* pbuf_d = (bf16*)alloc((size_t)ND*NCH*HID*2);
  bf16* pbuf_z = (bf16*)alloc((size_t)NZ*NCH*HID*2);      // Bbig later
  bf16* pg_z = (bf16*)alloc((size_t)NZ*NCH*HID*2);
  ushort* csr_d = (ushort*)alloc((size_t)NP*E_D*2);       // 2.10 MB compact
  ushort* csr_z = (ushort*)alloc((size_t)NP*E_Z*2);       // 1.05 MB
  int* bh_d = (int*)alloc((size_t)NP*NB_D*ND*4);          // 4.19 MB per-chunk hist/bases
  int* bh_z = (int*)alloc((size_t)NP*NB_Z*NZ*4);          // 1.05 MB
  int* off_d = (int*)alloc((size_t)NP*(ND+1)*4);
  int* off_z = (int*)alloc((size_t)NP*(NZ+1)*4);
  bf16* w1t_d = (bf16*)alloc((size_t)NCH*MIDW*IN_DIM*2);
  bf16* w2t_d = (bf16*)alloc((size_t)NCH*MIDW*MIDW*2);
  bf16* w3t_d = (bf16*)alloc((size_t)NCH*HID*MIDW*2);
  bf16* w1t_z = (bf16*)alloc((size_t)NCH*MIDW*IN_DIM*2);
  bf16* w2t_z = (bf16*)alloc((size_t)NCH*MIDW*MIDW*2);
  bf16* w3t_z = (bf16*)alloc((size_t)NCH*HID*MIDW*2);
  bf16* Gtb = (bf16*)alloc((size_t)2*HID*HID*2);
  bf16* wdect = (bf16*)alloc((size_t)NCH*HID*HID*2);
  float* v2v = (float*)alloc((size_t)256*4);
  float* wsm = (float*)alloc((size_t)NCH*4);
  bf16* out_d = h1_d;
  bf16* out_z = h1_z;
  bf16* pg_d = featb_d;           // featb+Y_d region (12.58 MB >= 10.49), dead after agg2
  bf16* Bbig = pbuf_z;            // pbuf_z dead after attn
  if (ws_size < o) return;

  // CSR build: chunked counting sort, LDS atomics only, full-GPU parallelism
  k_hist<<<NCHK, 256, 0, stream>>>(src_d, bh_d, src_z, bh_z);
  k_off<<<2*NP, 1024, 0, stream>>>(bh_d, off_d, bh_z, off_z);
  k_scat2<<<NCHK, 256, 0, stream>>>(src_d, dst_d, bh_d, csr_d,
                                    src_z, dst_z, bh_z, csr_z);
  // prep: converts + transposes + G + v2
  k_prep<<<B_END, 256, 0, stream>>>(feat_d, feat_z, featb_d, featb_z,
      dW1, dW2, dW3, zW1, zW2, zW3,
      w1t_d, w2t_d, w3t_d, w1t_z, w2t_z, w3t_z,
      Wdec, wdect, Wq_d, Wk_d, Wq_z, Wk_z, Gtb,
      bq_d, bq_z, v2v, wattn, wsm);
  // stage 1: A1 + A2 GEMM
  k_stage1<<<dim3(64, 3, 10), 256, 0, stream>>>(featb_d, featb_z, w1t_d, w1t_z,
      db1, zb1, att_d, att_z, h1_d, h1_z, Y_d, Y_z);
  // aggregation -> h1 channels 1..4
  k_agg2<<<(NP*ND + NP*NZ)/4, 256, 0, stream>>>(csr_d, off_d, db1, Y_d, h1_d,
                                                csr_z, off_z, zb1, Y_z, h1_z);
  // fused MLP 2+3 + pg
  {
    MlpP pd = {h1_d, w2t_d, db2, w3t_d, db3, pbuf_d, pg_d, Gtb, ND};
    MlpP pz = {h1_z, w2t_z, zb2, w3t_z, zb3, pbuf_z, pg_z, Gtb + HID*HID, NZ};
    k_mlp23<<<dim3(64, 1, 10), 256, 0, stream>>>(pd, pz, 5);
  }
  // metapath attention
  k_attn<<<ND + NZ, 64, 0, stream>>>(pbuf_d, pg_d, v2v, beta_d, out_d,
                                     pbuf_z, pg_z, beta_z, out_z);
  // decoder
  {
    GemmP pz = {out_z, wdect, bdec, Bbig, wsm, nullptr, 0, (long)NZ*HID, (long)NCH*HID, HID, HID, HID, NZ, 0};
    k_gemm<<<dim3(32, 2, 5), 256, 0, stream>>>(pz, pz, 5);
  }
  // final
  k_gemm_final<<<dim3(64, 32), 256, 0, stream>>>(out_d, Bbig, (float*)d_out);
}

// Round 11
// 294.134 us; speedup vs baseline: 2.3445x; 2.1625x over previous
//
#include <hip/hip_runtime.h>
#include <hip/hip_bf16.h>

#define ND 8192
#define NZ 4096
#define IN_DIM 256
#define HID 128
#define MIDW 192
#define NP 4
#define NCH 5
#define DEG 32
#define E_D (ND*DEG)
#define E_Z (NZ*DEG)
#define CHUNK 8192
#define NB_D (E_D/CHUNK)   // 32
#define NB_Z (E_Z/CHUNK)   // 16
#define NCHK (NP*NB_D + NP*NB_Z)  // 192

typedef __hip_bfloat16 bf16;
typedef __attribute__((ext_vector_type(8))) short s8v;
typedef __attribute__((ext_vector_type(4))) float f4v;

static __device__ __forceinline__ unsigned short f2bf(float x){
  bf16 b = __float2bfloat16(x);
  return *reinterpret_cast<unsigned short*>(&b);
}
static __device__ __forceinline__ uint packbf2(float a, float b){
  return (uint)f2bf(a) | ((uint)f2bf(b) << 16);
}
static __device__ __forceinline__ float bfl(uint w){ return __uint_as_float(w<<16); }
static __device__ __forceinline__ float bfh(uint w){ return __uint_as_float(w & 0xffff0000u); }
static __device__ __forceinline__ void gload16(const void* g, void* l){
  __builtin_amdgcn_global_load_lds(
      (const __attribute__((address_space(1))) unsigned int*)g,
      (__attribute__((address_space(3))) unsigned int*)l, 16, 0, 0);
}

// ---------------- CSR phase 1: per-chunk LDS histogram -> bh ----------------
__global__ __launch_bounds__(256) void k_hist(
    const int* __restrict__ src_d, int* __restrict__ bh_d,
    const int* __restrict__ src_z, int* __restrict__ bh_z)
{
  __shared__ int hist[ND];
  int b = blockIdx.x, t = threadIdx.x;
  const int* src; int* bh; int n;
  if (b < NP*NB_D){
    int mp = b >> 5, ch = b & (NB_D-1);
    src = src_d + (long)mp*E_D + ch*CHUNK;
    bh = bh_d + ((long)mp*NB_D + ch)*ND;
    n = ND;
  } else {
    int b2 = b - NP*NB_D;
    int mp = b2 >> 4, ch = b2 & (NB_Z-1);
    src = src_z + (long)mp*E_Z + ch*CHUNK;
    bh = bh_z + ((long)mp*NB_Z + ch)*NZ;
    n = NZ;
  }
  for (int i=t; i<n; i+=256) hist[i] = 0;
  __syncthreads();
  for (int e=t; e<CHUNK; e+=256) atomicAdd(&hist[src[e]], 1);
  __syncthreads();
  for (int i=t; i<n; i+=256) bh[i] = hist[i];
}

// ---------------- CSR phase 2a: per-node cross-chunk scan (1 thread/node) ----------------
__global__ __launch_bounds__(256) void k_off_a(
    int* __restrict__ bh_d, int* __restrict__ tot_d,
    int* __restrict__ bh_z, int* __restrict__ tot_z)
{
  int i = blockIdx.x*256 + threadIdx.x;     // 0 .. NP*ND + NP*NZ - 1
  int* bh; int* tot; int n, NB, s;
  if (i < NP*ND){
    int m = i >> 13; s = i & (ND-1);
    bh = bh_d + (long)m*NB_D*ND; tot = tot_d + m*ND; n = ND; NB = NB_D;
  } else {
    int i2 = i - NP*ND;
    int m = i2 >> 12; s = i2 & (NZ-1);
    bh = bh_z + (long)m*NB_Z*NZ; tot = tot_z + m*NZ; n = NZ; NB = NB_Z;
  }
  int running = 0;
  for (int bb=0; bb<NB; bb++){
    int v = bh[bb*n + s];
    bh[bb*n + s] = running;     // chunk-local exclusive base (pre node-offset)
    running += v;
  }
  tot[s] = running;
}

// ---------------- CSR phase 2b: per-metapath exclusive scan tot -> off ----------------
__global__ __launch_bounds__(256) void k_scan(const int* __restrict__ tot_d, int* __restrict__ off_d,
                                              const int* __restrict__ tot_z, int* __restrict__ off_z){
  int b = blockIdx.x;
  const int* d; int* o; int n; int E;
  if (b < NP){ d = tot_d + (long)b*ND; o = off_d + (long)b*(ND+1); n = ND; E = E_D; }
  else { int m = b-NP; d = tot_z + (long)m*NZ; o = off_z + (long)m*(NZ+1); n = NZ; E = E_Z; }
  int t = threadIdx.x, lane = t&63, wv = t>>6;
  __shared__ int wsum[4];
  __shared__ int carry;
  if (t==0) carry = 0;
  __syncthreads();
  for (int base=0; base<n; base+=256){
    int v = d[base+t];
    int x = v;
    #pragma unroll
    for (int s=1; s<64; s<<=1){
      int u = __shfl_up(x, s, 64);
      if (lane >= s) x += u;
    }
    if (lane==63) wsum[wv] = x;
    __syncthreads();
    int wo = 0;
    for (int w=0; w<wv; w++) wo += wsum[w];
    int c = carry;
    o[base+t] = c + wo + x - v;
    __syncthreads();
    if (t==255) carry = c + wo + x;
    __syncthreads();
  }
  if (t==0) o[n] = E;
}

// ---------------- CSR phase 3: chunk scatter; XCD-clustered block remap ----------------
// block b -> (mp = b&7, ch = b>>3): all writers of one metapath's CSR region share
// blockIdx%8 (empirical XCD round-robin) -> same-L2 writes. Correct regardless of mapping.
__global__ __launch_bounds__(256) void k_scat2(
    const int* __restrict__ src_d, const int* __restrict__ dst_d,
    const int* __restrict__ bh_d, const int* __restrict__ off_d, ushort* __restrict__ csr_d,
    const int* __restrict__ src_z, const int* __restrict__ dst_z,
    const int* __restrict__ bh_z, const int* __restrict__ off_z, ushort* __restrict__ csr_z)
{
  __shared__ int cur[ND];
  int b = blockIdx.x, t = threadIdx.x;
  int mp8 = b & 7, ch = b >> 3;
  const int *src, *dst, *bh, *off; ushort* csr; int n;
  if (mp8 < NP){
    if (ch >= NB_D) return;
    int mp = mp8;
    src = src_d + (long)mp*E_D + ch*CHUNK;
    dst = dst_d + (long)mp*E_D + ch*CHUNK;
    bh = bh_d + ((long)mp*NB_D + ch)*ND;
    off = off_d + (long)mp*(ND+1);
    csr = csr_d + (long)mp*E_D;
    n = ND;
  } else {
    if (ch >= NB_Z) return;
    int mp = mp8 - NP;
    src = src_z + (long)mp*E_Z + ch*CHUNK;
    dst = dst_z + (long)mp*E_Z + ch*CHUNK;
    bh = bh_z + ((long)mp*NB_Z + ch)*NZ;
    off = off_z + (long)mp*(NZ+1);
    csr = csr_z + (long)mp*E_Z;
    n = NZ;
  }
  for (int i=t; i<n; i+=256) cur[i] = bh[i] + off[i];
  __syncthreads();
  for (int e=t; e<CHUNK; e+=256){
    int s = src[e];
    int pos = atomicAdd(&cur[s], 1);
    csr[pos] = (ushort)dst[e];
  }
}

// ---------------- mega prep: cvts + transposes + G + v2 ----------------
static __device__ __forceinline__ void tpz(const float* __restrict__ in, bf16* __restrict__ out,
                                           int rows, int cols, long idx){
  int per = rows*cols;
  int b = (int)(idx / per);
  int rem = (int)(idx - (long)b*per);
  int r = rem / cols, c = rem - r*cols;
  out[(long)b*per + (long)c*rows + r] = __float2bfloat16(in[idx]);
}

#define B_CVD 2048
#define B_CVZ (B_CVD+1024)     // 3072
#define B_W1D (B_CVZ+960)      // 4032
#define B_W1Z (B_W1D+960)      // 4992
#define B_W2D (B_W1Z+720)      // 5712
#define B_W2Z (B_W2D+720)      // 6432
#define B_W3D (B_W2Z+480)      // 6912
#define B_W3Z (B_W3D+480)      // 7392
#define B_WDEC (B_W3Z+320)     // 7712
#define B_G (B_WDEC+128)       // 7840
#define B_END (B_G+1)          // 7841

__global__ __launch_bounds__(256) void k_prep(
    const float* feat_d, const float* feat_z, bf16* featb_d, bf16* featb_z,
    const float* dW1, const float* dW2, const float* dW3,
    const float* zW1, const float* zW2, const float* zW3,
    bf16* w1t_d, bf16* w2t_d, bf16* w3t_d, bf16* w1t_z, bf16* w2t_z, bf16* w3t_z,
    const float* Wdec, bf16* wdect,
    const float* Wq_d, const float* Wk_d, const float* Wq_z, const float* Wk_z,
    bf16* Gtb,
    const float* bq_d, const float* bq_z, float* v2v,
    const float* wattn, float* wsm)
{
  int b = blockIdx.x, t = threadIdx.x;
  if (b < B_CVD){
    long i4 = (long)b*256 + t;
    float4 v = ((const float4*)feat_d)[i4];
    ushort4 o; o.x=f2bf(v.x); o.y=f2bf(v.y); o.z=f2bf(v.z); o.w=f2bf(v.w);
    ((ushort4*)featb_d)[i4] = o;
  } else if (b < B_CVZ){
    long i4 = (long)(b - B_CVD)*256 + t;
    float4 v = ((const float4*)feat_z)[i4];
    ushort4 o; o.x=f2bf(v.x); o.y=f2bf(v.y); o.z=f2bf(v.z); o.w=f2bf(v.w);
    ((ushort4*)featb_z)[i4] = o;
  } else if (b < B_W1D){ tpz(dW1, w1t_d, IN_DIM, MIDW, (long)(b-B_CVZ)*256 + t); }
  else if (b < B_W1Z){ tpz(zW1, w1t_z, IN_DIM, MIDW, (long)(b-B_W1D)*256 + t); }
  else if (b < B_W2D){ tpz(dW2, w2t_d, MIDW, MIDW, (long)(b-B_W1Z)*256 + t); }
  else if (b < B_W2Z){ tpz(zW2, w2t_z, MIDW, MIDW, (long)(b-B_W2D)*256 + t); }
  else if (b < B_W3D){ tpz(dW3, w3t_d, MIDW, HID, (long)(b-B_W2Z)*256 + t); }
  else if (b < B_W3Z){ tpz(zW3, w3t_z, MIDW, HID, (long)(b-B_W3D)*256 + t); }
  else if (b < B_WDEC){ tpz(Wdec, wdect, HID, HID, (long)(b-B_W3Z)*256 + t); }
  else if (b < B_G){
    // Gt[c,h'] = sum_j Wq[h',j]*Wk[c,j]
    int cc = (b - B_WDEC)*2 + (t>>7);
    int hp = t & 127;
    const float* Wq = cc < 128 ? Wq_d : Wq_z;
    const float* Wk = cc < 128 ? Wk_d : Wk_z;
    int c = cc & 127;
    float s = 0.f;
    for (int j=0;j<HID;j++) s += Wq[hp*HID+j]*Wk[c*HID+j];
    Gtb[(cc < 128 ? 0 : HID*HID) + c*HID + hp] = __float2bfloat16(s);
  } else {
    if (t < 128){
      float s = 0.f;
      for (int j=0;j<HID;j++) s += Wk_d[t*HID+j]*bq_d[j];
      v2v[t] = s;
    } else {
      int tt = t-128;
      float s = 0.f;
      for (int j=0;j<HID;j++) s += Wk_z[tt*HID+j]*bq_z[j];
      v2v[128+tt] = s;
    }
    if (t == 0){
      float mx = wattn[0];
      for (int i=1;i<NCH;i++) mx = fmaxf(mx, wattn[i]);
      float e[NCH], s=0.f;
      for (int i=0;i<NCH;i++){ e[i]=expf(wattn[i]-mx); s+=e[i]; }
      for (int i=0;i<NCH;i++) wsm[i]=e[i]/s;
    }
  }
}

// ---------------- stage 1: (A1 | A2) GEMM, z = type*5 + channel ----------------
__global__ __launch_bounds__(256) void k_stage1(
    const bf16* __restrict__ featb_d, const bf16* __restrict__ featb_z,
    const bf16* __restrict__ w1t_d, const bf16* __restrict__ w1t_z,
    const float* __restrict__ db1, const float* __restrict__ zb1,
    const float* __restrict__ att_d, const float* __restrict__ att_z,
    bf16* __restrict__ h1_d, bf16* __restrict__ h1_z,
    bf16* __restrict__ Y_d, bf16* __restrict__ Y_z)
{
  int z = blockIdx.z, typ = z/5, c = z - 5*(z/5);
  int n = typ ? NZ : ND;
  long row0 = (long)blockIdx.x*128;
  if (row0 >= n) return;
  int col0 = blockIdx.y*64;
  __shared__ short As[128*40];
  __shared__ short Bs[64*40];
  int t = threadIdx.x, lane = t&63, wv = t>>6;
  int l15 = lane&15, kof = (lane>>4)*8;
  const short* Ag = (const short*)(typ ? featb_z : featb_d);
  const short* Bg = (const short*)(typ ? w1t_z : w1t_d) + (long)c*MIDW*IN_DIM;
  f4v acc[2][4] = {};
  for (int kk=0; kk<IN_DIM; kk+=32){
    __syncthreads();
    #pragma unroll
    for (int j=0;j<2;j++){
      int c2 = t + j*256;
      int row = c2>>2, sub = c2&3;
      *(s8v*)(&As[row*40 + sub*8]) = *(const s8v*)(Ag + (row0+row)*IN_DIM + kk + sub*8);
    }
    { int row = t>>2, sub = t&3;
      *(s8v*)(&Bs[row*40 + sub*8]) = *(const s8v*)(Bg + (long)(col0+row)*IN_DIM + kk + sub*8); }
    __syncthreads();
    s8v af[2], bfr[4];
    #pragma unroll
    for (int i2=0;i2<2;i2++) af[i2] = *(const s8v*)(&As[(wv*32 + i2*16 + l15)*40 + kof]);
    #pragma unroll
    for (int j2=0;j2<4;j2++) bfr[j2] = *(const s8v*)(&Bs[(j2*16 + l15)*40 + kof]);
    #pragma unroll
    for (int i2=0;i2<2;i2++)
      #pragma unroll
      for (int j2=0;j2<4;j2++)
        acc[i2][j2] = __builtin_amdgcn_mfma_f32_16x16x32_bf16(af[i2], bfr[j2], acc[i2][j2],0,0,0);
  }
  if (c == 0){
    const float* bb = typ ? zb1 : db1;
    bf16* outp = typ ? h1_z : h1_d;
    #pragma unroll
    for (int i2=0;i2<2;i2++)
      #pragma unroll
      for (int j2=0;j2<4;j2++){
        int col = col0 + j2*16 + l15;
        float bv = bb[col];
        #pragma unroll
        for (int r=0;r<4;r++){
          long row = row0 + wv*32 + i2*16 + (lane>>4)*4 + r;
          outp[row*MIDW + col] = __float2bfloat16(fmaxf(acc[i2][j2][r] + bv, 0.f));
        }
      }
  } else {
    const float* rs = (typ ? att_z : att_d) + (long)(c-1)*n;
    bf16* outp = (typ ? Y_z : Y_d) + (long)(c-1)*n*MIDW;
    #pragma unroll
    for (int i2=0;i2<2;i2++)
      #pragma unroll
      for (int j2=0;j2<4;j2++){
        int col = col0 + j2*16 + l15;
        #pragma unroll
        for (int r=0;r<4;r++){
          long row = row0 + wv*32 + i2*16 + (lane>>4)*4 + r;
          outp[row*MIDW + col] = __float2bfloat16(acc[i2][j2][r] * rs[row]);
        }
      }
  }
}

// ---------------- aggregation (compact ushort CSR) ----------------
__global__ __launch_bounds__(256) void k_agg2(
    const ushort* __restrict__ csr_d, const int* __restrict__ off_d, const float* __restrict__ bias_d,
    const bf16* __restrict__ Y_d, bf16* __restrict__ h1_d,
    const ushort* __restrict__ csr_z, const int* __restrict__ off_z, const float* __restrict__ bias_z,
    const bf16* __restrict__ Y_z, bf16* __restrict__ h1_z)
{
  int wid = (blockIdx.x*256 + threadIdx.x) >> 6;
  int lane = threadIdx.x & 63;
  const ushort* csr; const int* off; const float* bias; const uint* Yb; bf16* h1; int n, m; long ebase;
  if (wid < NP*ND){
    m = wid >> 13; int s0 = wid & (ND-1);
    csr = csr_d; off = off_d + (long)m*(ND+1); bias = bias_d; h1 = h1_d; n = ND;
    Yb = (const uint*)Y_d + (long)m*ND*96;
    ebase = (long)m*E_D;
    wid = s0;
  } else {
    int w2 = wid - NP*ND;
    m = w2 >> 12; int s0 = w2 & (NZ-1);
    csr = csr_z; off = off_z + (long)m*(NZ+1); bias = bias_z; h1 = h1_z; n = NZ;
    Yb = (const uint*)Y_z + (long)m*NZ*96;
    ebase = (long)m*E_Z;
    wid = s0;
  }
  int s = wid;
  int o0 = off[s], o1 = off[s+1];
  int cnt = o1 - o0;
  const ushort* lp = csr + ebase + o0;
  bool hi2 = lane < 32;
  float a0=0.f,a1=0.f,a2=0.f,a3=0.f;
  for (int base=0; base<cnt; base+=64){
    int rem = cnt - base;
    int idx = (lane < rem) ? lane : (rem-1);
    int e = lp[base + idx];
    int lim = rem < 64 ? rem : 64;
    int j = 0;
    for (; j+1<lim; j+=2){
      int d0 = __shfl(e, j), d1 = __shfl(e, j+1);
      const uint* r0 = Yb + (long)d0*96;
      const uint* r1 = Yb + (long)d1*96;
      uint w0 = r0[lane], w1 = r1[lane];
      uint v0 = hi2 ? r0[64+lane] : 0u;
      uint v1 = hi2 ? r1[64+lane] : 0u;
      a0 += bfl(w0)+bfl(w1); a1 += bfh(w0)+bfh(w1);
      a2 += bfl(v0)+bfl(v1); a3 += bfh(v0)+bfh(v1);
    }
    if (j < lim){
      int d0 = __shfl(e, j);
      const uint* r0 = Yb + (long)d0*96;
      uint w0 = r0[lane];
      uint v0 = hi2 ? r0[64+lane] : 0u;
      a0 += bfl(w0); a1 += bfh(w0);
      a2 += bfl(v0); a3 += bfh(v0);
    }
  }
  float inv = 1.0f / fmaxf((float)cnt, 1.0f);
  const float* bb = bias + (m+1)*MIDW;
  float2 b0 = *(const float2*)(bb + 2*lane);
  uint* hrow = (uint*)((short*)h1 + ((long)(m+1)*n + s)*MIDW);
  hrow[lane] = packbf2(fmaxf(a0*inv + b0.x, 0.f), fmaxf(a1*inv + b0.y, 0.f));
  if (hi2){
    float2 b1v = *(const float2*)(bb + 128 + 2*lane);
    hrow[64+lane] = packbf2(fmaxf(a2*inv + b1v.x, 0.f), fmaxf(a3*inv + b1v.y, 0.f));
  }
}

// ---------------- generic batched GEMM (decoder) ----------------
struct GemmP {
  const bf16* A; const bf16* BT; const float* bias; bf16* out;
  const float* scale; const float* rowsc;
  long rs_moff, a_moff, out_rstride, out_moff;
  int K, N, nrows, relu;
};

__global__ __launch_bounds__(256) void k_gemm(GemmP P0, GemmP P1, int zsplit)
{
  const GemmP& p = ((int)blockIdx.z < zsplit) ? P0 : P1;
  int m = ((int)blockIdx.z < zsplit) ? blockIdx.z : blockIdx.z - zsplit;
  long row0 = (long)blockIdx.x*128;
  if (row0 >= p.nrows) return;
  int col0 = blockIdx.y*64;
  if (col0 >= p.N) return;
  __shared__ short As[128*40];
  __shared__ short Bs[64*40];
  int t = threadIdx.x;
  const short* Ag = (const short*)p.A + m*p.a_moff;
  const short* Bg = (const short*)p.BT + (long)m*p.N*p.K;
  int lane = t&63, wv = t>>6;
  int l15 = lane&15, kof = (lane>>4)*8;
  int K = p.K;
  f4v acc[2][4] = {};
  for (int kk=0; kk<K; kk+=32){
    __syncthreads();
    #pragma unroll
    for (int j=0;j<2;j++){
      int c = t + j*256;
      int row = c>>2, sub = c&3;
      *(s8v*)(&As[row*40 + sub*8]) = *(const s8v*)(Ag + (row0+row)*K + kk + sub*8);
    }
    { int row = t>>2, sub = t&3;
      *(s8v*)(&Bs[row*40 + sub*8]) = *(const s8v*)(Bg + (long)(col0+row)*K + kk + sub*8); }
    __syncthreads();
    s8v af[2], bfr[4];
    #pragma unroll
    for (int i2=0;i2<2;i2++) af[i2] = *(const s8v*)(&As[(wv*32 + i2*16 + l15)*40 + kof]);
    #pragma unroll
    for (int j2=0;j2<4;j2++) bfr[j2] = *(const s8v*)(&Bs[(j2*16 + l15)*40 + kof]);
    #pragma unroll
    for (int i2=0;i2<2;i2++)
      #pragma unroll
      for (int j2=0;j2<4;j2++)
        acc[i2][j2] = __builtin_amdgcn_mfma_f32_16x16x32_bf16(af[i2], bfr[j2], acc[i2][j2],0,0,0);
  }
  float sc = p.scale ? p.scale[m] : 1.0f;
  #pragma unroll
  for (int i2=0;i2<2;i2++){
    #pragma unroll
    for (int j2=0;j2<4;j2++){
      int col = col0 + j2*16 + l15;
      float bv = p.bias ? p.bias[m*p.N + col] : 0.f;
      #pragma unroll
      for (int r=0;r<4;r++){
        long row = row0 + wv*32 + i2*16 + (lane>>4)*4 + r;
        float v = acc[i2][j2][r] + bv;
        if (p.relu) v = fmaxf(v, 0.f);
        v *= sc;
        if (p.rowsc) v *= p.rowsc[m*p.rs_moff + row];
        p.out[m*p.out_moff + row*p.out_rstride + col] = __float2bfloat16(v);
      }
    }
  }
}

// ---------------- fused MLP 2+3 + pg ----------------
struct MlpP { const bf16* h1; const bf16* w2t; const float* b2;
              const bf16* w3t; const float* b3; bf16* pout; bf16* pgout;
              const bf16* gt; int n; };

__global__ __launch_bounds__(256) void k_mlp23(MlpP P0, MlpP P1, int zsplit)
{
  const MlpP& p = ((int)blockIdx.z < zsplit) ? P0 : P1;
  int m = ((int)blockIdx.z < zsplit) ? blockIdx.z : blockIdx.z - zsplit;
  int row0 = blockIdx.x*128;
  if (row0 >= p.n) return;
  __shared__ short h2s[128*200];
  __shared__ short As[128*40];
  __shared__ short Bs[192*40];
  int t = threadIdx.x, lane = t&63, wv = t>>6;
  int l15 = lane&15, hi = lane>>4, kof = hi*8;
  const short* Ag = (const short*)p.h1 + ((long)m*p.n + row0)*MIDW;
  const short* Bg = (const short*)p.w2t + (long)m*MIDW*MIDW;
  f4v accA[2][12] = {};
  for (int kk=0; kk<MIDW; kk+=32){
    __syncthreads();
    #pragma unroll
    for (int j=0;j<2;j++){
      int c = t + j*256;
      int row = c>>2, sub = c&3;
      *(s8v*)(&As[row*40 + sub*8]) = *(const s8v*)(Ag + (long)row*MIDW + kk + sub*8);
    }
    #pragma unroll
    for (int j=0;j<3;j++){
      int c = t + j*256;
      int row = c>>2, sub = c&3;
      *(s8v*)(&Bs[row*40 + sub*8]) = *(const s8v*)(Bg + (long)row*MIDW + kk + sub*8);
    }
    __syncthreads();
    s8v af[2], bfr[12];
    #pragma unroll
    for (int i2=0;i2<2;i2++) af[i2] = *(const s8v*)(&As[(wv*32 + i2*16 + l15)*40 + kof]);
    #pragma unroll
    for (int j2=0;j2<12;j2++) bfr[j2] = *(const s8v*)(&Bs[(j2*16 + l15)*40 + kof]);
    #pragma unroll
    for (int i2=0;i2<2;i2++)
      #pragma unroll
      for (int j2=0;j2<12;j2++)
        accA[i2][j2] = __builtin_amdgcn_mfma_f32_16x16x32_bf16(af[i2], bfr[j2], accA[i2][j2],0,0,0);
  }
  float b2l[12];
  #pragma unroll
  for (int j2=0;j2<12;j2++) b2l[j2] = p.b2[m*MIDW + j2*16 + l15];
  #pragma unroll
  for (int i2=0;i2<2;i2++)
    #pragma unroll
    for (int j2=0;j2<12;j2++)
      #pragma unroll
      for (int r=0;r<4;r++){
        int rl = wv*32 + i2*16 + hi*4 + r;
        h2s[rl*200 + j2*16 + l15] = (short)f2bf(fmaxf(accA[i2][j2][r] + b2l[j2], 0.f));
      }
  const short* Cg = (const short*)p.w3t + (long)m*HID*MIDW;
  f4v accB[2][8] = {};
  for (int kk=0; kk<MIDW; kk+=32){
    __syncthreads();
    #pragma unroll
    for (int j=0;j<2;j++){
      int c = t + j*256;
      int row = c>>2, sub = c&3;
      *(s8v*)(&Bs[row*40 + sub*8]) = *(const s8v*)(Cg + (long)row*MIDW + kk + sub*8);
    }
    __syncthreads();
    s8v af[2], bfr[8];
    #pragma unroll
    for (int i2=0;i2<2;i2++) af[i2] = *(const s8v*)(&h2s[(wv*32 + i2*16 + l15)*200 + kk + kof]);
    #pragma unroll
    for (int j2=0;j2<8;j2++) bfr[j2] = *(const s8v*)(&Bs[(j2*16 + l15)*40 + kof]);
    #pragma unroll
    for (int i2=0;i2<2;i2++)
      #pragma unroll
      for (int j2=0;j2<8;j2++)
        accB[i2][j2] = __builtin_amdgcn_mfma_f32_16x16x32_bf16(af[i2], bfr[j2], accB[i2][j2],0,0,0);
  }
  __syncthreads();
  #pragma unroll
  for (int j2=0;j2<8;j2++){
    float b3v = p.b3[m*HID + j2*16 + l15];
    #pragma unroll
    for (int i2=0;i2<2;i2++)
      #pragma unroll
      for (int r=0;r<4;r++){
        int rl = wv*32 + i2*16 + hi*4 + r;
        unsigned short hv = f2bf(accB[i2][j2][r] + b3v);
        p.pout[((long)(row0+rl))*(NCH*HID) + m*HID + j2*16 + l15] = *(bf16*)&hv;
        h2s[rl*200 + j2*16 + l15] = (short)hv;
      }
  }
  const short* Gg = (const short*)p.gt;
  f4v accC[2][8] = {};
  for (int kk=0; kk<HID; kk+=32){
    __syncthreads();
    #pragma unroll
    for (int j=0;j<2;j++){
      int c = t + j*256;
      int row = c>>2, sub = c&3;
      *(s8v*)(&Bs[row*40 + sub*8]) = *(const s8v*)(Gg + (long)row*HID + kk + sub*8);
    }
    __syncthreads();
    s8v af[2], bfr[8];
    #pragma unroll
    for (int i2=0;i2<2;i2++) af[i2] = *(const s8v*)(&h2s[(wv*32 + i2*16 + l15)*200 + kk + kof]);
    #pragma unroll
    for (int j2=0;j2<8;j2++) bfr[j2] = *(const s8v*)(&Bs[(j2*16 + l15)*40 + kof]);
    #pragma unroll
    for (int i2=0;i2<2;i2++)
      #pragma unroll
      for (int j2=0;j2<8;j2++)
        accC[i2][j2] = __builtin_amdgcn_mfma_f32_16x16x32_bf16(af[i2], bfr[j2], accC[i2][j2],0,0,0);
  }
  #pragma unroll
  for (int j2=0;j2<8;j2++)
    #pragma unroll
    for (int i2=0;i2<2;i2++)
      #pragma unroll
      for (int r=0;r<4;r++){
        long row = row0 + wv*32 + i2*16 + hi*4 + r;
        p.pgout[row*(NCH*HID) + m*HID + j2*16 + l15] = __float2bfloat16(accC[i2][j2][r]);
      }
}

// ---------------- per-node metapath attention (bilinear) ----------------
__global__ __launch_bounds__(64) void k_attn(
    const bf16* __restrict__ p_d, const bf16* __restrict__ pg_d, const float* __restrict__ v2v,
    const float* __restrict__ beta_d, bf16* __restrict__ o_d,
    const bf16* __restrict__ p_z, const bf16* __restrict__ pg_z,
    const float* __restrict__ beta_z, bf16* __restrict__ o_z)
{
  int node = blockIdx.x; int t = threadIdx.x;
  const bf16 *pp, *gg; bf16* outp; const float *betap, *v2p;
  if (node < ND){
    pp = p_d + (long)node*640; gg = pg_d + (long)node*640;
    outp = o_d + (long)node*640; betap = beta_d; v2p = v2v;
  } else {
    int nz = node - ND;
    pp = p_z + (long)nz*640; gg = pg_z + (long)nz*640;
    outp = o_z + (long)nz*640; betap = beta_z; v2p = v2v + 128;
  }
  __shared__ float pl[640], gl[640], v2l[128];
  __shared__ float lg[25], at[25], bv[5];
  const uint* pu = (const uint*)pp;
  const uint* gu = (const uint*)gg;
  for (int i=t; i<320; i+=64){
    uint w = pu[i];
    pl[2*i] = bfl(w); pl[2*i+1] = bfh(w);
    uint g = gu[i];
    gl[2*i] = bfl(g); gl[2*i+1] = bfh(g);
  }
  v2l[t] = v2p[t]; v2l[64+t] = v2p[64+t];
  __syncthreads();
  if (t < 60){
    int pr = t>>1, sub = t&1, h0 = sub*64;
    float s = 0.f;
    if (pr < 25){
      int mi = pr/5, ki = pr - 5*(pr/5);
      for (int h=h0; h<h0+64; h++) s += gl[mi*HID+h]*pl[ki*HID+h];
      s += __shfl_xor(s, 1);
      if (!sub) lg[pr] = s;
    } else {
      int k = pr - 25;
      for (int h=h0; h<h0+64; h++) s += pl[k*HID+h]*v2l[h];
      s += __shfl_xor(s, 1);
      if (!sub) bv[k] = s;
    }
  }
  __syncthreads();
  if (t < 5){
    float l0[5];
    for (int j=0;j<5;j++) l0[j] = lg[t*5+j] + bv[j];
    float mx = l0[0];
    for (int j=1;j<5;j++) mx = fmaxf(mx, l0[j]);
    float e[5], su=0.f;
    for (int j=0;j<5;j++){ e[j] = expf(l0[j]-mx); su += e[j]; }
    for (int j=0;j<5;j++) at[t*5+j] = e[j]/su;
  }
  __syncthreads();
  float bt = betap[0];
  for (int i=t; i<320; i+=64){
    int mm = i>>6, h = (i&63)*2;
    float s0=0.f, s1=0.f;
    #pragma unroll
    for (int k2=0;k2<5;k2++){
      s0 += at[mm*5+k2]*pl[k2*HID+h];
      s1 += at[mm*5+k2]*pl[k2*HID+h+1];
    }
    ((uint*)outp)[i] = packbf2(pl[2*i] + bt*s0, pl[2*i+1] + bt*s1);
  }
}

// ---------------- final GEMM ----------------
__global__ __launch_bounds__(256) void k_gemm_final(
    const bf16* __restrict__ Aout, const bf16* __restrict__ Bb, float* __restrict__ out)
{
  __shared__ short As[128*64];
  __shared__ short Bs[128*64];
  int t = threadIdx.x;
  int lane = t&63, wv=t>>6, wr=wv>>1, wc=wv&1;
  int row0 = blockIdx.x*128, col0 = blockIdx.y*128;
  const short* Ag = (const short*)Aout;
  const short* Bg = (const short*)Bb;
  int l15 = lane&15, hi = lane>>4;
  int srow = t>>3;
  int sseg = (t&7) ^ (srow&7);
  f4v acc[4][4] = {};
  for (int kk=0; kk<NCH*HID; kk+=64){
    int mch = kk>>7, h0 = kk&127;
    __syncthreads();
    #pragma unroll
    for (int j=0;j<4;j++){
      int row = j*32 + srow;
      gload16(Ag + ((long)mch*ND + row0+row)*HID + h0 + sseg*8,
              (char*)As + ((j*256 + t)<<4));
      gload16(Bg + (long)(col0+row)*(NCH*HID) + kk + sseg*8,
              (char*)Bs + ((j*256 + t)<<4));
    }
    asm volatile("s_waitcnt vmcnt(0)" ::: "memory");
    __syncthreads();
    #pragma unroll
    for (int sl=0; sl<2; sl++){
      s8v af[4], bg[4];
      #pragma unroll
      for (int i=0;i<4;i++){
        int ra = wr*64 + i*16 + l15;
        af[i] = *(const s8v*)(&As[ra*64 + (((sl*4+hi) ^ (ra&7))*8)]);
        int rb = wc*64 + i*16 + l15;
        bg[i] = *(const s8v*)(&Bs[rb*64 + (((sl*4+hi) ^ (rb&7))*8)]);
      }
      #pragma unroll
      for (int mi=0;mi<4;mi++)
        #pragma unroll
        for (int ni=0;ni<4;ni++)
          acc[mi][ni] = __builtin_amdgcn_mfma_f32_16x16x32_bf16(af[mi], bg[ni], acc[mi][ni],0,0,0);
    }
  }
  #pragma unroll
  for (int mi=0;mi<4;mi++){
    #pragma unroll
    for (int ni=0;ni<4;ni++){
      int col = col0 + wc*64 + ni*16 + l15;
      #pragma unroll
      for (int r=0;r<4;r++){
        int row = row0 + wr*64 + mi*16 + hi*4 + r;
        out[(long)row*NZ + col] = acc[mi][ni][r];
      }
    }
  }
}

extern "C" void kernel_launch(void* const* d_in, const int* in_sizes, int n_in,
                              void* d_out, int out_size, void* d_ws, size_t ws_size,
                              hipStream_t stream)
{
  (void)in_sizes; (void)n_in; (void)out_size;
  const float* feat_d = (const float*)d_in[0];
  const float* feat_z = (const float*)d_in[1];
  const float* att_d  = (const float*)d_in[2];
  const float* att_z  = (const float*)d_in[3];
  const int* src_d = (const int*)d_in[4];
  const int* dst_d = (const int*)d_in[5];
  const int* src_z = (const int*)d_in[6];
  const int* dst_z = (const int*)d_in[7];
  const float* dW1=(const float*)d_in[8];  const float* db1=(const float*)d_in[9];
  const float* dW2=(const float*)d_in[10]; const float* db2=(const float*)d_in[11];
  const float* dW3=(const float*)d_in[12]; const float* db3=(const float*)d_in[13];
  const float* Wq_d=(const float*)d_in[14]; const float* bq_d=(const float*)d_in[15];
  const float* Wk_d=(const float*)d_in[16]; const float* bk_d=(const float*)d_in[17];
  const float* beta_d=(const float*)d_in[18];
  const float* zW1=(const float*)d_in[19]; const float* zb1=(const float*)d_in[20];
  const float* zW2=(const float*)d_in[21]; const float* zb2=(const float*)d_in[22];
  const float* zW3=(const float*)d_in[23]; const float* zb3=(const float*)d_in[24];
  const float* Wq_z=(const float*)d_in[25]; const float* bq_z=(const float*)d_in[26];
  const float* Wk_z=(const float*)d_in[27]; const float* bk_z=(const float*)d_in[28];
  const float* beta_z=(const float*)d_in[29];
  const float* wattn=(const float*)d_in[30];
  const float* Wdec=(const float*)d_in[31]; const float* bdec=(const float*)d_in[32];
  (void)bk_d; (void)bk_z;

  char* ws = (char*)d_ws;
  size_t o = 0;
  auto alloc = [&](size_t bytes)->char*{
    size_t r = (o + 255) & ~(size_t)255;
    o = r + bytes;
    return ws + r;
  };
  // contiguity matters for aliasing below
  bf16* featb_d = (bf16*)alloc((size_t)ND*IN_DIM*2);      // 4.19 MB ┐
  bf16* featb_z = (bf16*)alloc((size_t)NZ*IN_DIM*2);      // 2.10 MB ├ pg_d (10.49) after agg2
  bf16* Y_d = (bf16*)alloc((size_t)NP*ND*MIDW*2);         // 6.29 MB ┘
  bf16* Y_z = (bf16*)alloc((size_t)NP*NZ*MIDW*2);         // 3.15 MB
  bf16* h1_d = (bf16*)alloc((size_t)NCH*ND*MIDW*2);       // out_d later
  bf16* h1_z = (bf16*)alloc((size_t)NCH*NZ*MIDW*2);       // out_z later
  bf16* pbuf_d = (bf16*)alloc((size_t)ND*NCH*HID*2);
  bf16* pbuf_z = (bf16*)alloc((size_t)NZ*NCH*HID*2);      // Bbig later
  bf16* pg_z = (bf16*)alloc((size_t)NZ*NCH*HID*2);
  ushort* csr_d = (ushort*)alloc((size_t)NP*E_D*2);       // 2.10 MB compact
  ushort* csr_z = (ushort*)alloc((size_t)NP*E_Z*2);       // 1.05 MB
  int* bh_d = (int*)alloc((size_t)NP*NB_D*ND*4);          // 4.19 MB per-chunk hist/bases
  int* bh_z = (int*)alloc((size_t)NP*NB_Z*NZ*4);          // 1.05 MB
  int* tot_d = (int*)alloc((size_t)NP*ND*4);
  int* tot_z = (int*)alloc((size_t)NP*NZ*4);
  int* off_d = (int*)alloc((size_t)NP*(ND+1)*4);
  int* off_z = (int*)alloc((size_t)NP*(NZ+1)*4);
  bf16* w1t_d = (bf16*)alloc((size_t)NCH*MIDW*IN_DIM*2);
  bf16* w2t_d = (bf16*)alloc((size_t)NCH*MIDW*MIDW*2);
  bf16* w3t_d = (bf16*)alloc((size_t)NCH*HID*MIDW*2);
  bf16* w1t_z = (bf16*)alloc((size_t)NCH*MIDW*IN_DIM*2);
  bf16* w2t_z = (bf16*)alloc((size_t)NCH*MIDW*MIDW*2);
  bf16* w3t_z = (bf16*)alloc((size_t)NCH*HID*MIDW*2);
  bf16* Gtb = (bf16*)alloc((size_t)2*HID*HID*2);
  bf16* wdect = (bf16*)alloc((size_t)NCH*HID*HID*2);
  float* v2v = (float*)alloc((size_t)256*4);
  float* wsm = (float*)alloc((size_t)NCH*4);
  bf16* out_d = h1_d;
  bf16* out_z = h1_z;
  bf16* pg_d = featb_d;           // featb+Y_d region (12.58 MB >= 10.49), dead after agg2
  bf16* Bbig = pbuf_z;            // pbuf_z dead after attn
  if (ws_size < o) return;

  // CSR build: chunked counting sort; LDS atomics only; parallel scan
  k_hist<<<NCHK, 256, 0, stream>>>(src_d, bh_d, src_z, bh_z);
  k_off_a<<<(NP*ND + NP*NZ)/256, 256, 0, stream>>>(bh_d, tot_d, bh_z, tot_z);
  k_scan<<<2*NP, 256, 0, stream>>>(tot_d, off_d, tot_z, off_z);
  k_scat2<<<256, 256, 0, stream>>>(src_d, dst_d, bh_d, off_d, csr_d,
                                   src_z, dst_z, bh_z, off_z, csr_z);
  // prep: converts + transposes + G + v2
  k_prep<<<B_END, 256, 0, stream>>>(feat_d, feat_z, featb_d, featb_z,
      dW1, dW2, dW3, zW1, zW2, zW3,
      w1t_d, w2t_d, w3t_d, w1t_z, w2t_z, w3t_z,
      Wdec, wdect, Wq_d, Wk_d, Wq_z, Wk_z, Gtb,
      bq_d, bq_z, v2v, wattn, wsm);
  // stage 1: A1 + A2 GEMM
  k_stage1<<<dim3(64, 3, 10), 256, 0, stream>>>(featb_d, featb_z, w1t_d, w1t_z,
      db1, zb1, att_d, att_z, h1_d, h1_z, Y_d, Y_z);
  // aggregation -> h1 channels 1..4
  k_agg2<<<(NP*ND + NP*NZ)/4, 256, 0, stream>>>(csr_d, off_d, db1, Y_d, h1_d,
                                                csr_z, off_z, zb1, Y_z, h1_z);
  // fused MLP 2+3 + pg
  {
    MlpP pd = {h1_d, w2t_d, db2, w3t_d, db3, pbuf_d, pg_d, Gtb, ND};
    MlpP pz = {h1_z, w2t_z, zb2, w3t_z, zb3, pbuf_z, pg_z, Gtb + HID*HID, NZ};
    k_mlp23<<<dim3(64, 1, 10), 256, 0, stream>>>(pd, pz, 5);
  }
  // metapath attention
  k_attn<<<ND + NZ, 64, 0, stream>>>(pbuf_d, pg_d, v2v, beta_d, out_d,
                                     pbuf_z, pg_z, beta_z, out_z);
  // decoder
  {
    GemmP pz = {out_z, wdect, bdec, Bbig, wsm, nullptr, 0, (long)NZ*HID, (long)NCH*HID, HID, HID, HID, NZ, 0};
    k_gemm<<<dim3(32, 2, 5), 256, 0, stream>>>(pz, pz, 5);
  }
  // final
  k_gemm_final<<<dim3(64, 32), 256, 0, stream>>>(out_d, Bbig, (float*)d_out);
}

// Round 12
// 280.509 us; speedup vs baseline: 2.4584x; 1.0486x over previous
//
#include <hip/hip_runtime.h>
#include <hip/hip_bf16.h>

#define ND 8192
#define NZ 4096
#define IN_DIM 256
#define HID 128
#define MIDW 192
#define NP 4
#define NCH 5
#define DEG 32
#define E_D (ND*DEG)
#define E_Z (NZ*DEG)
#define CHUNK 8192
#define NB_D (E_D/CHUNK)   // 32
#define NB_Z (E_Z/CHUNK)   // 16
#define NCHK (NP*NB_D + NP*NB_Z)  // 192

typedef __hip_bfloat16 bf16;
typedef __attribute__((ext_vector_type(8))) short s8v;
typedef __attribute__((ext_vector_type(4))) float f4v;

static __device__ __forceinline__ unsigned short f2bf(float x){
  bf16 b = __float2bfloat16(x);
  return *reinterpret_cast<unsigned short*>(&b);
}
static __device__ __forceinline__ uint packbf2(float a, float b){
  return (uint)f2bf(a) | ((uint)f2bf(b) << 16);
}
static __device__ __forceinline__ float bfl(uint w){ return __uint_as_float(w<<16); }
static __device__ __forceinline__ float bfh(uint w){ return __uint_as_float(w & 0xffff0000u); }
static __device__ __forceinline__ void gload16(const void* g, void* l){
  __builtin_amdgcn_global_load_lds(
      (const __attribute__((address_space(1))) unsigned int*)g,
      (__attribute__((address_space(3))) unsigned int*)l, 16, 0, 0);
}

// ---------------- mega prep: per-chunk histograms + cvts + transposes + G + v2 ----------------
static __device__ __forceinline__ void tpz(const float* __restrict__ in, bf16* __restrict__ out,
                                           int rows, int cols, long idx){
  int per = rows*cols;
  int b = (int)(idx / per);
  int rem = (int)(idx - (long)b*per);
  int r = rem / cols, c = rem - r*cols;
  out[(long)b*per + (long)c*rows + r] = __float2bfloat16(in[idx]);
}

#define P_H NCHK               // 192 histogram blocks first
#define B_CVD (P_H+2048)
#define B_CVZ (B_CVD+1024)
#define B_W1D (B_CVZ+960)
#define B_W1Z (B_W1D+960)
#define B_W2D (B_W1Z+720)
#define B_W2Z (B_W2D+720)
#define B_W3D (B_W2Z+480)
#define B_W3Z (B_W3D+480)
#define B_WDEC (B_W3Z+320)
#define B_G (B_WDEC+128)
#define B_END (B_G+1)

__global__ __launch_bounds__(256) void k_prep(
    const int* __restrict__ src_d, int* __restrict__ bh_d,
    const int* __restrict__ src_z, int* __restrict__ bh_z,
    const float* feat_d, const float* feat_z, bf16* featb_d, bf16* featb_z,
    const float* dW1, const float* dW2, const float* dW3,
    const float* zW1, const float* zW2, const float* zW3,
    bf16* w1t_d, bf16* w2t_d, bf16* w3t_d, bf16* w1t_z, bf16* w2t_z, bf16* w3t_z,
    const float* Wdec, bf16* wdect,
    const float* Wq_d, const float* Wk_d, const float* Wq_z, const float* Wk_z,
    bf16* Gtb,
    const float* bq_d, const float* bq_z, float* v2v,
    const float* wattn, float* wsm)
{
  int b = blockIdx.x, t = threadIdx.x;
  if (b < P_H){
    __shared__ int hist[ND];
    const int* src; int* bh; int n;
    if (b < NP*NB_D){
      int mp = b >> 5, ch = b & (NB_D-1);
      src = src_d + (long)mp*E_D + ch*CHUNK;
      bh = bh_d + ((long)mp*NB_D + ch)*ND;
      n = ND;
    } else {
      int b2 = b - NP*NB_D;
      int mp = b2 >> 4, ch = b2 & (NB_Z-1);
      src = src_z + (long)mp*E_Z + ch*CHUNK;
      bh = bh_z + ((long)mp*NB_Z + ch)*NZ;
      n = NZ;
    }
    for (int i=t; i<n; i+=256) hist[i] = 0;
    __syncthreads();
    for (int e=t; e<CHUNK; e+=256) atomicAdd(&hist[src[e]], 1);
    __syncthreads();
    for (int i=t; i<n; i+=256) bh[i] = hist[i];
  } else if (b < B_CVD){
    long i4 = (long)(b - P_H)*256 + t;
    float4 v = ((const float4*)feat_d)[i4];
    ushort4 o; o.x=f2bf(v.x); o.y=f2bf(v.y); o.z=f2bf(v.z); o.w=f2bf(v.w);
    ((ushort4*)featb_d)[i4] = o;
  } else if (b < B_CVZ){
    long i4 = (long)(b - B_CVD)*256 + t;
    float4 v = ((const float4*)feat_z)[i4];
    ushort4 o; o.x=f2bf(v.x); o.y=f2bf(v.y); o.z=f2bf(v.z); o.w=f2bf(v.w);
    ((ushort4*)featb_z)[i4] = o;
  } else if (b < B_W1D){ tpz(dW1, w1t_d, IN_DIM, MIDW, (long)(b-B_CVZ)*256 + t); }
  else if (b < B_W1Z){ tpz(zW1, w1t_z, IN_DIM, MIDW, (long)(b-B_W1D)*256 + t); }
  else if (b < B_W2D){ tpz(dW2, w2t_d, MIDW, MIDW, (long)(b-B_W1Z)*256 + t); }
  else if (b < B_W2Z){ tpz(zW2, w2t_z, MIDW, MIDW, (long)(b-B_W2D)*256 + t); }
  else if (b < B_W3D){ tpz(dW3, w3t_d, MIDW, HID, (long)(b-B_W2Z)*256 + t); }
  else if (b < B_W3Z){ tpz(zW3, w3t_z, MIDW, HID, (long)(b-B_W3D)*256 + t); }
  else if (b < B_WDEC){ tpz(Wdec, wdect, HID, HID, (long)(b-B_W3Z)*256 + t); }
  else if (b < B_G){
    // Gt[c,h'] = sum_j Wq[h',j]*Wk[c,j]
    int cc = (b - B_WDEC)*2 + (t>>7);
    int hp = t & 127;
    const float* Wq = cc < 128 ? Wq_d : Wq_z;
    const float* Wk = cc < 128 ? Wk_d : Wk_z;
    int c = cc & 127;
    float s = 0.f;
    for (int j=0;j<HID;j++) s += Wq[hp*HID+j]*Wk[c*HID+j];
    Gtb[(cc < 128 ? 0 : HID*HID) + c*HID + hp] = __float2bfloat16(s);
  } else {
    if (t < 128){
      float s = 0.f;
      for (int j=0;j<HID;j++) s += Wk_d[t*HID+j]*bq_d[j];
      v2v[t] = s;
    } else {
      int tt = t-128;
      float s = 0.f;
      for (int j=0;j<HID;j++) s += Wk_z[tt*HID+j]*bq_z[j];
      v2v[128+tt] = s;
    }
    if (t == 0){
      float mx = wattn[0];
      for (int i=1;i<NCH;i++) mx = fmaxf(mx, wattn[i]);
      float e[NCH], s=0.f;
      for (int i=0;i<NCH;i++){ e[i]=expf(wattn[i]-mx); s+=e[i]; }
      for (int i=0;i<NCH;i++) wsm[i]=e[i]/s;
    }
  }
}

// ---------------- CSR phase 2a: per-node cross-chunk scan (1 thread/node) ----------------
__global__ __launch_bounds__(256) void k_off_a(
    int* __restrict__ bh_d, int* __restrict__ tot_d,
    int* __restrict__ bh_z, int* __restrict__ tot_z)
{
  int i = blockIdx.x*256 + threadIdx.x;
  int* bh; int* tot; int n, NB, s;
  if (i < NP*ND){
    int m = i >> 13; s = i & (ND-1);
    bh = bh_d + (long)m*NB_D*ND; tot = tot_d + m*ND; n = ND; NB = NB_D;
  } else {
    int i2 = i - NP*ND;
    int m = i2 >> 12; s = i2 & (NZ-1);
    bh = bh_z + (long)m*NB_Z*NZ; tot = tot_z + m*NZ; n = NZ; NB = NB_Z;
  }
  int running = 0;
  for (int bb=0; bb<NB; bb++){
    int v = bh[bb*n + s];
    bh[bb*n + s] = running;
    running += v;
  }
  tot[s] = running;
}

// ---------------- CSR phase 2b: per-metapath exclusive scan tot -> off ----------------
__global__ __launch_bounds__(256) void k_scan(const int* __restrict__ tot_d, int* __restrict__ off_d,
                                              const int* __restrict__ tot_z, int* __restrict__ off_z){
  int b = blockIdx.x;
  const int* d; int* o; int n; int E;
  if (b < NP){ d = tot_d + (long)b*ND; o = off_d + (long)b*(ND+1); n = ND; E = E_D; }
  else { int m = b-NP; d = tot_z + (long)m*NZ; o = off_z + (long)m*(NZ+1); n = NZ; E = E_Z; }
  int t = threadIdx.x, lane = t&63, wv = t>>6;
  __shared__ int wsum[4];
  __shared__ int carry;
  if (t==0) carry = 0;
  __syncthreads();
  for (int base=0; base<n; base+=256){
    int v = d[base+t];
    int x = v;
    #pragma unroll
    for (int s=1; s<64; s<<=1){
      int u = __shfl_up(x, s, 64);
      if (lane >= s) x += u;
    }
    if (lane==63) wsum[wv] = x;
    __syncthreads();
    int wo = 0;
    for (int w=0; w<wv; w++) wo += wsum[w];
    int c = carry;
    o[base+t] = c + wo + x - v;
    __syncthreads();
    if (t==255) carry = c + wo + x;
    __syncthreads();
  }
  if (t==0) o[n] = E;
}

// ---------------- CSR phase 3: chunk scatter; XCD-clustered block remap ----------------
__global__ __launch_bounds__(256) void k_scat2(
    const int* __restrict__ src_d, const int* __restrict__ dst_d,
    const int* __restrict__ bh_d, const int* __restrict__ off_d, ushort* __restrict__ csr_d,
    const int* __restrict__ src_z, const int* __restrict__ dst_z,
    const int* __restrict__ bh_z, const int* __restrict__ off_z, ushort* __restrict__ csr_z)
{
  __shared__ int cur[ND];
  int b = blockIdx.x, t = threadIdx.x;
  int mp8 = b & 7, ch = b >> 3;
  const int *src, *dst, *bh, *off; ushort* csr; int n;
  if (mp8 < NP){
    if (ch >= NB_D) return;
    int mp = mp8;
    src = src_d + (long)mp*E_D + ch*CHUNK;
    dst = dst_d + (long)mp*E_D + ch*CHUNK;
    bh = bh_d + ((long)mp*NB_D + ch)*ND;
    off = off_d + (long)mp*(ND+1);
    csr = csr_d + (long)mp*E_D;
    n = ND;
  } else {
    if (ch >= NB_Z) return;
    int mp = mp8 - NP;
    src = src_z + (long)mp*E_Z + ch*CHUNK;
    dst = dst_z + (long)mp*E_Z + ch*CHUNK;
    bh = bh_z + ((long)mp*NB_Z + ch)*NZ;
    off = off_z + (long)mp*(NZ+1);
    csr = csr_z + (long)mp*E_Z;
    n = NZ;
  }
  for (int i=t; i<n; i+=256) cur[i] = bh[i] + off[i];
  __syncthreads();
  for (int e=t; e<CHUNK; e+=256){
    int s = src[e];
    int pos = atomicAdd(&cur[s], 1);
    csr[pos] = (ushort)dst[e];
  }
}

// ---------------- stage 1: (A1 | A2) GEMM, z = type*5 + channel ----------------
__global__ __launch_bounds__(256) void k_stage1(
    const bf16* __restrict__ featb_d, const bf16* __restrict__ featb_z,
    const bf16* __restrict__ w1t_d, const bf16* __restrict__ w1t_z,
    const float* __restrict__ db1, const float* __restrict__ zb1,
    const float* __restrict__ att_d, const float* __restrict__ att_z,
    bf16* __restrict__ h1_d, bf16* __restrict__ h1_z,
    bf16* __restrict__ Y_d, bf16* __restrict__ Y_z)
{
  int z = blockIdx.z, typ = z/5, c = z - 5*(z/5);
  int n = typ ? NZ : ND;
  long row0 = (long)blockIdx.x*128;
  if (row0 >= n) return;
  int col0 = blockIdx.y*64;
  __shared__ short As[128*40];
  __shared__ short Bs[64*40];
  int t = threadIdx.x, lane = t&63, wv = t>>6;
  int l15 = lane&15, kof = (lane>>4)*8;
  const short* Ag = (const short*)(typ ? featb_z : featb_d);
  const short* Bg = (const short*)(typ ? w1t_z : w1t_d) + (long)c*MIDW*IN_DIM;
  f4v acc[2][4] = {};
  for (int kk=0; kk<IN_DIM; kk+=32){
    __syncthreads();
    #pragma unroll
    for (int j=0;j<2;j++){
      int c2 = t + j*256;
      int row = c2>>2, sub = c2&3;
      *(s8v*)(&As[row*40 + sub*8]) = *(const s8v*)(Ag + (row0+row)*IN_DIM + kk + sub*8);
    }
    { int row = t>>2, sub = t&3;
      *(s8v*)(&Bs[row*40 + sub*8]) = *(const s8v*)(Bg + (long)(col0+row)*IN_DIM + kk + sub*8); }
    __syncthreads();
    s8v af[2], bfr[4];
    #pragma unroll
    for (int i2=0;i2<2;i2++) af[i2] = *(const s8v*)(&As[(wv*32 + i2*16 + l15)*40 + kof]);
    #pragma unroll
    for (int j2=0;j2<4;j2++) bfr[j2] = *(const s8v*)(&Bs[(j2*16 + l15)*40 + kof]);
    #pragma unroll
    for (int i2=0;i2<2;i2++)
      #pragma unroll
      for (int j2=0;j2<4;j2++)
        acc[i2][j2] = __builtin_amdgcn_mfma_f32_16x16x32_bf16(af[i2], bfr[j2], acc[i2][j2],0,0,0);
  }
  if (c == 0){
    const float* bb = typ ? zb1 : db1;
    bf16* outp = typ ? h1_z : h1_d;
    #pragma unroll
    for (int i2=0;i2<2;i2++)
      #pragma unroll
      for (int j2=0;j2<4;j2++){
        int col = col0 + j2*16 + l15;
        float bv = bb[col];
        #pragma unroll
        for (int r=0;r<4;r++){
          long row = row0 + wv*32 + i2*16 + (lane>>4)*4 + r;
          outp[row*MIDW + col] = __float2bfloat16(fmaxf(acc[i2][j2][r] + bv, 0.f));
        }
      }
  } else {
    const float* rs = (typ ? att_z : att_d) + (long)(c-1)*n;
    bf16* outp = (typ ? Y_z : Y_d) + (long)(c-1)*n*MIDW;
    #pragma unroll
    for (int i2=0;i2<2;i2++)
      #pragma unroll
      for (int j2=0;j2<4;j2++){
        int col = col0 + j2*16 + l15;
        #pragma unroll
        for (int r=0;r<4;r++){
          long row = row0 + wv*32 + i2*16 + (lane>>4)*4 + r;
          outp[row*MIDW + col] = __float2bfloat16(acc[i2][j2][r] * rs[row]);
        }
      }
  }
}

// ---------------- aggregation (compact ushort CSR, 4-edge unroll) ----------------
__global__ __launch_bounds__(256) void k_agg2(
    const ushort* __restrict__ csr_d, const int* __restrict__ off_d, const float* __restrict__ bias_d,
    const bf16* __restrict__ Y_d, bf16* __restrict__ h1_d,
    const ushort* __restrict__ csr_z, const int* __restrict__ off_z, const float* __restrict__ bias_z,
    const bf16* __restrict__ Y_z, bf16* __restrict__ h1_z)
{
  int wid = (blockIdx.x*256 + threadIdx.x) >> 6;
  int lane = threadIdx.x & 63;
  const ushort* csr; const int* off; const float* bias; const uint* Yb; bf16* h1; int n, m; long ebase;
  if (wid < NP*ND){
    m = wid >> 13; int s0 = wid & (ND-1);
    csr = csr_d; off = off_d + (long)m*(ND+1); bias = bias_d; h1 = h1_d; n = ND;
    Yb = (const uint*)Y_d + (long)m*ND*96;
    ebase = (long)m*E_D;
    wid = s0;
  } else {
    int w2 = wid - NP*ND;
    m = w2 >> 12; int s0 = w2 & (NZ-1);
    csr = csr_z; off = off_z + (long)m*(NZ+1); bias = bias_z; h1 = h1_z; n = NZ;
    Yb = (const uint*)Y_z + (long)m*NZ*96;
    ebase = (long)m*E_Z;
    wid = s0;
  }
  int s = wid;
  int o0 = off[s], o1 = off[s+1];
  int cnt = o1 - o0;
  const ushort* lp = csr + ebase + o0;
  bool hi2 = lane < 32;
  float a0=0.f,a1=0.f,a2=0.f,a3=0.f;
  for (int base=0; base<cnt; base+=64){
    int rem = cnt - base;
    int idx = (lane < rem) ? lane : (rem-1);
    int e = lp[base + idx];
    int lim = rem < 64 ? rem : 64;
    int j = 0;
    for (; j+3<lim; j+=4){
      int d0 = __shfl(e, j), d1 = __shfl(e, j+1), d2 = __shfl(e, j+2), d3 = __shfl(e, j+3);
      const uint* r0 = Yb + (long)d0*96;
      const uint* r1 = Yb + (long)d1*96;
      const uint* r2 = Yb + (long)d2*96;
      const uint* r3 = Yb + (long)d3*96;
      uint w0 = r0[lane], w1 = r1[lane], w2 = r2[lane], w3 = r3[lane];
      uint v0 = hi2 ? r0[64+lane] : 0u;
      uint v1 = hi2 ? r1[64+lane] : 0u;
      uint v2 = hi2 ? r2[64+lane] : 0u;
      uint v3 = hi2 ? r3[64+lane] : 0u;
      a0 += (bfl(w0)+bfl(w1)) + (bfl(w2)+bfl(w3));
      a1 += (bfh(w0)+bfh(w1)) + (bfh(w2)+bfh(w3));
      a2 += (bfl(v0)+bfl(v1)) + (bfl(v2)+bfl(v3));
      a3 += (bfh(v0)+bfh(v1)) + (bfh(v2)+bfh(v3));
    }
    for (; j<lim; j++){
      int d0 = __shfl(e, j);
      const uint* r0 = Yb + (long)d0*96;
      uint w0 = r0[lane];
      uint v0 = hi2 ? r0[64+lane] : 0u;
      a0 += bfl(w0); a1 += bfh(w0);
      a2 += bfl(v0); a3 += bfh(v0);
    }
  }
  float inv = 1.0f / fmaxf((float)cnt, 1.0f);
  const float* bb = bias + (m+1)*MIDW;
  float2 b0 = *(const float2*)(bb + 2*lane);
  uint* hrow = (uint*)((short*)h1 + ((long)(m+1)*n + s)*MIDW);
  hrow[lane] = packbf2(fmaxf(a0*inv + b0.x, 0.f), fmaxf(a1*inv + b0.y, 0.f));
  if (hi2){
    float2 b1v = *(const float2*)(bb + 128 + 2*lane);
    hrow[64+lane] = packbf2(fmaxf(a2*inv + b1v.x, 0.f), fmaxf(a3*inv + b1v.y, 0.f));
  }
}

// ---------------- generic batched GEMM (decoder) ----------------
struct GemmP {
  const bf16* A; const bf16* BT; const float* bias; bf16* out;
  const float* scale; const float* rowsc;
  long rs_moff, a_moff, out_rstride, out_moff;
  int K, N, nrows, relu;
};

__global__ __launch_bounds__(256) void k_gemm(GemmP P0, GemmP P1, int zsplit)
{
  const GemmP& p = ((int)blockIdx.z < zsplit) ? P0 : P1;
  int m = ((int)blockIdx.z < zsplit) ? blockIdx.z : blockIdx.z - zsplit;
  long row0 = (long)blockIdx.x*128;
  if (row0 >= p.nrows) return;
  int col0 = blockIdx.y*64;
  if (col0 >= p.N) return;
  __shared__ short As[128*40];
  __shared__ short Bs[64*40];
  int t = threadIdx.x;
  const short* Ag = (const short*)p.A + m*p.a_moff;
  const short* Bg = (const short*)p.BT + (long)m*p.N*p.K;
  int lane = t&63, wv = t>>6;
  int l15 = lane&15, kof = (lane>>4)*8;
  int K = p.K;
  f4v acc[2][4] = {};
  for (int kk=0; kk<K; kk+=32){
    __syncthreads();
    #pragma unroll
    for (int j=0;j<2;j++){
      int c = t + j*256;
      int row = c>>2, sub = c&3;
      *(s8v*)(&As[row*40 + sub*8]) = *(const s8v*)(Ag + (row0+row)*K + kk + sub*8);
    }
    { int row = t>>2, sub = t&3;
      *(s8v*)(&Bs[row*40 + sub*8]) = *(const s8v*)(Bg + (long)(col0+row)*K + kk + sub*8); }
    __syncthreads();
    s8v af[2], bfr[4];
    #pragma unroll
    for (int i2=0;i2<2;i2++) af[i2] = *(const s8v*)(&As[(wv*32 + i2*16 + l15)*40 + kof]);
    #pragma unroll
    for (int j2=0;j2<4;j2++) bfr[j2] = *(const s8v*)(&Bs[(j2*16 + l15)*40 + kof]);
    #pragma unroll
    for (int i2=0;i2<2;i2++)
      #pragma unroll
      for (int j2=0;j2<4;j2++)
        acc[i2][j2] = __builtin_amdgcn_mfma_f32_16x16x32_bf16(af[i2], bfr[j2], acc[i2][j2],0,0,0);
  }
  float sc = p.scale ? p.scale[m] : 1.0f;
  #pragma unroll
  for (int i2=0;i2<2;i2++){
    #pragma unroll
    for (int j2=0;j2<4;j2++){
      int col = col0 + j2*16 + l15;
      float bv = p.bias ? p.bias[m*p.N + col] : 0.f;
      #pragma unroll
      for (int r=0;r<4;r++){
        long row = row0 + wv*32 + i2*16 + (lane>>4)*4 + r;
        float v = acc[i2][j2][r] + bv;
        if (p.relu) v = fmaxf(v, 0.f);
        v *= sc;
        if (p.rowsc) v *= p.rowsc[m*p.rs_moff + row];
        p.out[m*p.out_moff + row*p.out_rstride + col] = __float2bfloat16(v);
      }
    }
  }
}

// ---------------- fused MLP 2+3 + pg ----------------
struct MlpP { const bf16* h1; const bf16* w2t; const float* b2;
              const bf16* w3t; const float* b3; bf16* pout; bf16* pgout;
              const bf16* gt; int n; };

__global__ __launch_bounds__(256) void k_mlp23(MlpP P0, MlpP P1, int zsplit)
{
  const MlpP& p = ((int)blockIdx.z < zsplit) ? P0 : P1;
  int m = ((int)blockIdx.z < zsplit) ? blockIdx.z : blockIdx.z - zsplit;
  int row0 = blockIdx.x*128;
  if (row0 >= p.n) return;
  __shared__ short h2s[128*200];
  __shared__ short As[128*40];
  __shared__ short Bs[192*40];
  int t = threadIdx.x, lane = t&63, wv = t>>6;
  int l15 = lane&15, hi = lane>>4, kof = hi*8;
  const short* Ag = (const short*)p.h1 + ((long)m*p.n + row0)*MIDW;
  const short* Bg = (const short*)p.w2t + (long)m*MIDW*MIDW;
  f4v accA[2][12] = {};
  for (int kk=0; kk<MIDW; kk+=32){
    __syncthreads();
    #pragma unroll
    for (int j=0;j<2;j++){
      int c = t + j*256;
      int row = c>>2, sub = c&3;
      *(s8v*)(&As[row*40 + sub*8]) = *(const s8v*)(Ag + (long)row*MIDW + kk + sub*8);
    }
    #pragma unroll
    for (int j=0;j<3;j++){
      int c = t + j*256;
      int row = c>>2, sub = c&3;
      *(s8v*)(&Bs[row*40 + sub*8]) = *(const s8v*)(Bg + (long)row*MIDW + kk + sub*8);
    }
    __syncthreads();
    s8v af[2], bfr[12];
    #pragma unroll
    for (int i2=0;i2<2;i2++) af[i2] = *(const s8v*)(&As[(wv*32 + i2*16 + l15)*40 + kof]);
    #pragma unroll
    for (int j2=0;j2<12;j2++) bfr[j2] = *(const s8v*)(&Bs[(j2*16 + l15)*40 + kof]);
    #pragma unroll
    for (int i2=0;i2<2;i2++)
      #pragma unroll
      for (int j2=0;j2<12;j2++)
        accA[i2][j2] = __builtin_amdgcn_mfma_f32_16x16x32_bf16(af[i2], bfr[j2], accA[i2][j2],0,0,0);
  }
  float b2l[12];
  #pragma unroll
  for (int j2=0;j2<12;j2++) b2l[j2] = p.b2[m*MIDW + j2*16 + l15];
  #pragma unroll
  for (int i2=0;i2<2;i2++)
    #pragma unroll
    for (int j2=0;j2<12;j2++)
      #pragma unroll
      for (int r=0;r<4;r++){
        int rl = wv*32 + i2*16 + hi*4 + r;
        h2s[rl*200 + j2*16 + l15] = (short)f2bf(fmaxf(accA[i2][j2][r] + b2l[j2], 0.f));
      }
  const short* Cg = (const short*)p.w3t + (long)m*HID*MIDW;
  f4v accB[2][8] = {};
  for (int kk=0; kk<MIDW; kk+=32){
    __syncthreads();
    #pragma unroll
    for (int j=0;j<2;j++){
      int c = t + j*256;
      int row = c>>2, sub = c&3;
      *(s8v*)(&Bs[row*40 + sub*8]) = *(const s8v*)(Cg + (long)row*MIDW + kk + sub*8);
    }
    __syncthreads();
    s8v af[2], bfr[8];
    #pragma unroll
    for (int i2=0;i2<2;i2++) af[i2] = *(const s8v*)(&h2s[(wv*32 + i2*16 + l15)*200 + kk + kof]);
    #pragma unroll
    for (int j2=0;j2<8;j2++) bfr[j2] = *(const s8v*)(&Bs[(j2*16 + l15)*40 + kof]);
    #pragma unroll
    for (int i2=0;i2<2;i2++)
      #pragma unroll
      for (int j2=0;j2<8;j2++)
        accB[i2][j2] = __builtin_amdgcn_mfma_f32_16x16x32_bf16(af[i2], bfr[j2], accB[i2][j2],0,0,0);
  }
  __syncthreads();
  #pragma unroll
  for (int j2=0;j2<8;j2++){
    float b3v = p.b3[m*HID + j2*16 + l15];
    #pragma unroll
    for (int i2=0;i2<2;i2++)
      #pragma unroll
      for (int r=0;r<4;r++){
        int rl = wv*32 + i2*16 + hi*4 + r;
        unsigned short hv = f2bf(accB[i2][j2][r] + b3v);
        p.pout[((long)(row0+rl))*(NCH*HID) + m*HID + j2*16 + l15] = *(bf16*)&hv;
        h2s[rl*200 + j2*16 + l15] = (short)hv;
      }
  }
  const short* Gg = (const short*)p.gt;
  f4v accC[2][8] = {};
  for (int kk=0; kk<HID; kk+=32){
    __syncthreads();
    #pragma unroll
    for (int j=0;j<2;j++){
      int c = t + j*256;
      int row = c>>2, sub = c&3;
      *(s8v*)(&Bs[row*40 + sub*8]) = *(const s8v*)(Gg + (long)row*HID + kk + sub*8);
    }
    __syncthreads();
    s8v af[2], bfr[8];
    #pragma unroll
    for (int i2=0;i2<2;i2++) af[i2] = *(const s8v*)(&h2s[(wv*32 + i2*16 + l15)*200 + kk + kof]);
    #pragma unroll
    for (int j2=0;j2<8;j2++) bfr[j2] = *(const s8v*)(&Bs[(j2*16 + l15)*40 + kof]);
    #pragma unroll
    for (int i2=0;i2<2;i2++)
      #pragma unroll
      for (int j2=0;j2<8;j2++)
        accC[i2][j2] = __builtin_amdgcn_mfma_f32_16x16x32_bf16(af[i2], bfr[j2], accC[i2][j2],0,0,0);
  }
  #pragma unroll
  for (int j2=0;j2<8;j2++)
    #pragma unroll
    for (int i2=0;i2<2;i2++)
      #pragma unroll
      for (int r=0;r<4;r++){
        long row = row0 + wv*32 + i2*16 + hi*4 + r;
        p.pgout[row*(NCH*HID) + m*HID + j2*16 + l15] = __float2bfloat16(accC[i2][j2][r]);
      }
}

// ---------------- per-node metapath attention (bilinear) ----------------
__global__ __launch_bounds__(64) void k_attn(
    const bf16* __restrict__ p_d, const bf16* __restrict__ pg_d, const float* __restrict__ v2v,
    const float* __restrict__ beta_d, bf16* __restrict__ o_d,
    const bf16* __restrict__ p_z, const bf16* __restrict__ pg_z,
    const float* __restrict__ beta_z, bf16* __restrict__ o_z)
{
  int node = blockIdx.x; int t = threadIdx.x;
  const bf16 *pp, *gg; bf16* outp; const float *betap, *v2p;
  if (node < ND){
    pp = p_d + (long)node*640; gg = pg_d + (long)node*640;
    outp = o_d + (long)node*640; betap = beta_d; v2p = v2v;
  } else {
    int nz = node - ND;
    pp = p_z + (long)nz*640; gg = pg_z + (long)nz*640;
    outp = o_z + (long)nz*640; betap = beta_z; v2p = v2v + 128;
  }
  __shared__ float pl[640], gl[640], v2l[128];
  __shared__ float lg[25], at[25], bv[5];
  const uint* pu = (const uint*)pp;
  const uint* gu = (const uint*)gg;
  for (int i=t; i<320; i+=64){
    uint w = pu[i];
    pl[2*i] = bfl(w); pl[2*i+1] = bfh(w);
    uint g = gu[i];
    gl[2*i] = bfl(g); gl[2*i+1] = bfh(g);
  }
  v2l[t] = v2p[t]; v2l[64+t] = v2p[64+t];
  __syncthreads();
  if (t < 60){
    int pr = t>>1, sub = t&1, h0 = sub*64;
    float s = 0.f;
    if (pr < 25){
      int mi = pr/5, ki = pr - 5*(pr/5);
      for (int h=h0; h<h0+64; h++) s += gl[mi*HID+h]*pl[ki*HID+h];
      s += __shfl_xor(s, 1);
      if (!sub) lg[pr] = s;
    } else {
      int k = pr - 25;
      for (int h=h0; h<h0+64; h++) s += pl[k*HID+h]*v2l[h];
      s += __shfl_xor(s, 1);
      if (!sub) bv[k] = s;
    }
  }
  __syncthreads();
  if (t < 5){
    float l0[5];
    for (int j=0;j<5;j++) l0[j] = lg[t*5+j] + bv[j];
    float mx = l0[0];
    for (int j=1;j<5;j++) mx = fmaxf(mx, l0[j]);
    float e[5], su=0.f;
    for (int j=0;j<5;j++){ e[j] = expf(l0[j]-mx); su += e[j]; }
    for (int j=0;j<5;j++) at[t*5+j] = e[j]/su;
  }
  __syncthreads();
  float bt = betap[0];
  for (int i=t; i<320; i+=64){
    int mm = i>>6, h = (i&63)*2;
    float s0=0.f, s1=0.f;
    #pragma unroll
    for (int k2=0;k2<5;k2++){
      s0 += at[mm*5+k2]*pl[k2*HID+h];
      s1 += at[mm*5+k2]*pl[k2*HID+h+1];
    }
    ((uint*)outp)[i] = packbf2(pl[2*i] + bt*s0, pl[2*i+1] + bt*s1);
  }
}

// ---------------- final GEMM ----------------
__global__ __launch_bounds__(256) void k_gemm_final(
    const bf16* __restrict__ Aout, const bf16* __restrict__ Bb, float* __restrict__ out)
{
  __shared__ short As[128*64];
  __shared__ short Bs[128*64];
  int t = threadIdx.x;
  int lane = t&63, wv=t>>6, wr=wv>>1, wc=wv&1;
  int row0 = blockIdx.x*128, col0 = blockIdx.y*128;
  const short* Ag = (const short*)Aout;
  const short* Bg = (const short*)Bb;
  int l15 = lane&15, hi = lane>>4;
  int srow = t>>3;
  int sseg = (t&7) ^ (srow&7);
  f4v acc[4][4] = {};
  for (int kk=0; kk<NCH*HID; kk+=64){
    int mch = kk>>7, h0 = kk&127;
    __syncthreads();
    #pragma unroll
    for (int j=0;j<4;j++){
      int row = j*32 + srow;
      gload16(Ag + ((long)mch*ND + row0+row)*HID + h0 + sseg*8,
              (char*)As + ((j*256 + t)<<4));
      gload16(Bg + (long)(col0+row)*(NCH*HID) + kk + sseg*8,
              (char*)Bs + ((j*256 + t)<<4));
    }
    asm volatile("s_waitcnt vmcnt(0)" ::: "memory");
    __syncthreads();
    #pragma unroll
    for (int sl=0; sl<2; sl++){
      s8v af[4], bg[4];
      #pragma unroll
      for (int i=0;i<4;i++){
        int ra = wr*64 + i*16 + l15;
        af[i] = *(const s8v*)(&As[ra*64 + (((sl*4+hi) ^ (ra&7))*8)]);
        int rb = wc*64 + i*16 + l15;
        bg[i] = *(const s8v*)(&Bs[rb*64 + (((sl*4+hi) ^ (rb&7))*8)]);
      }
      #pragma unroll
      for (int mi=0;mi<4;mi++)
        #pragma unroll
        for (int ni=0;ni<4;ni++)
          acc[mi][ni] = __builtin_amdgcn_mfma_f32_16x16x32_bf16(af[mi], bg[ni], acc[mi][ni],0,0,0);
    }
  }
  #pragma unroll
  for (int mi=0;mi<4;mi++){
    #pragma unroll
    for (int ni=0;ni<4;ni++){
      int col = col0 + wc*64 + ni*16 + l15;
      #pragma unroll
      for (int r=0;r<4;r++){
        int row = row0 + wr*64 + mi*16 + hi*4 + r;
        out[(long)row*NZ + col] = acc[mi][ni][r];
      }
    }
  }
}

extern "C" void kernel_launch(void* const* d_in, const int* in_sizes, int n_in,
                              void* d_out, int out_size, void* d_ws, size_t ws_size,
                              hipStream_t stream)
{
  (void)in_sizes; (void)n_in; (void)out_size;
  const float* feat_d = (const float*)d_in[0];
  const float* feat_z = (const float*)d_in[1];
  const float* att_d  = (const float*)d_in[2];
  const float* att_z  = (const float*)d_in[3];
  const int* src_d = (const int*)d_in[4];
  const int* dst_d = (const int*)d_in[5];
  const int* src_z = (const int*)d_in[6];
  const int* dst_z = (const int*)d_in[7];
  const float* dW1=(const float*)d_in[8];  const float* db1=(const float*)d_in[9];
  const float* dW2=(const float*)d_in[10]; const float* db2=(const float*)d_in[11];
  const float* dW3=(const float*)d_in[12]; const float* db3=(const float*)d_in[13];
  const float* Wq_d=(const float*)d_in[14]; const float* bq_d=(const float*)d_in[15];
  const float* Wk_d=(const float*)d_in[16]; const float* bk_d=(const float*)d_in[17];
  const float* beta_d=(const float*)d_in[18];
  const float* zW1=(const float*)d_in[19]; const float* zb1=(const float*)d_in[20];
  const float* zW2=(const float*)d_in[21]; const float* zb2=(const float*)d_in[22];
  const float* zW3=(const float*)d_in[23]; const float* zb3=(const float*)d_in[24];
  const float* Wq_z=(const float*)d_in[25]; const float* bq_z=(const float*)d_in[26];
  const float* Wk_z=(const float*)d_in[27]; const float* bk_z=(const float*)d_in[28];
  const float* beta_z=(const float*)d_in[29];
  const float* wattn=(const float*)d_in[30];
  const float* Wdec=(const float*)d_in[31]; const float* bdec=(const float*)d_in[32];
  (void)bk_d; (void)bk_z;

  char* ws = (char*)d_ws;
  size_t o = 0;
  auto alloc = [&](size_t bytes)->char*{
    size_t r = (o + 255) & ~(size_t)255;
    o = r + bytes;
    return ws + r;
  };
  bf16* featb_d = (bf16*)alloc((size_t)ND*IN_DIM*2);      // 4.19 MB ┐
  bf16* featb_z = (bf16*)alloc((size_t)NZ*IN_DIM*2);      // 2.10 MB ├ pg_d (10.49) after agg2
  bf16* Y_d = (bf16*)alloc((size_t)NP*ND*MIDW*2);         // 6.29 MB ┘
  bf16* Y_z = (bf16*)alloc((size_t)NP*NZ*MIDW*2);
  bf16* h1_d = (bf16*)alloc((size_t)NCH*ND*MIDW*2);       // out_d later
  bf16* h1_z = (bf16*)alloc((size_t)NCH*NZ*MIDW*2);       // out_z later
  bf16* pbuf_d = (bf16*)alloc((size_t)ND*NCH*HID*2);
  bf16* pbuf_z = (bf16*)alloc((size_t)NZ*NCH*HID*2);      // Bbig later
  bf16* pg_z = (bf16*)alloc((size_t)NZ*NCH*HID*2);
  ushort* csr_d = (ushort*)alloc((size_t)NP*E_D*2);
  ushort* csr_z = (ushort*)alloc((size_t)NP*E_Z*2);
  int* bh_d = (int*)alloc((size_t)NP*NB_D*ND*4);
  int* bh_z = (int*)alloc((size_t)NP*NB_Z*NZ*4);
  int* tot_d = (int*)alloc((size_t)NP*ND*4);
  int* tot_z = (int*)alloc((size_t)NP*NZ*4);
  int* off_d = (int*)alloc((size_t)NP*(ND+1)*4);
  int* off_z = (int*)alloc((size_t)NP*(NZ+1)*4);
  bf16* w1t_d = (bf16*)alloc((size_t)NCH*MIDW*IN_DIM*2);
  bf16* w2t_d = (bf16*)alloc((size_t)NCH*MIDW*MIDW*2);
  bf16* w3t_d = (bf16*)alloc((size_t)NCH*HID*MIDW*2);
  bf16* w1t_z = (bf16*)alloc((size_t)NCH*MIDW*IN_DIM*2);
  bf16* w2t_z = (bf16*)alloc((size_t)NCH*MIDW*MIDW*2);
  bf16* w3t_z = (bf16*)alloc((size_t)NCH*HID*MIDW*2);
  bf16* Gtb = (bf16*)alloc((size_t)2*HID*HID*2);
  bf16* wdect = (bf16*)alloc((size_t)NCH*HID*HID*2);
  float* v2v = (float*)alloc((size_t)256*4);
  float* wsm = (float*)alloc((size_t)NCH*4);
  bf16* out_d = h1_d;
  bf16* out_z = h1_z;
  bf16* pg_d = featb_d;           // featb+Y_d region dead after agg2
  bf16* Bbig = pbuf_z;            // pbuf_z dead after attn
  if (ws_size < o) return;

  // prep: per-chunk histograms + converts + transposes + G + v2 (one launch)
  k_prep<<<B_END, 256, 0, stream>>>(src_d, bh_d, src_z, bh_z,
      feat_d, feat_z, featb_d, featb_z,
      dW1, dW2, dW3, zW1, zW2, zW3,
      w1t_d, w2t_d, w3t_d, w1t_z, w2t_z, w3t_z,
      Wdec, wdect, Wq_d, Wk_d, Wq_z, Wk_z, Gtb,
      bq_d, bq_z, v2v, wattn, wsm);
  // CSR: per-node cross-chunk scan -> per-metapath scan -> chunk scatter
  k_off_a<<<(NP*ND + NP*NZ)/256, 256, 0, stream>>>(bh_d, tot_d, bh_z, tot_z);
  k_scan<<<2*NP, 256, 0, stream>>>(tot_d, off_d, tot_z, off_z);
  k_scat2<<<256, 256, 0, stream>>>(src_d, dst_d, bh_d, off_d, csr_d,
                                   src_z, dst_z, bh_z, off_z, csr_z);
  // stage 1: A1 + A2 GEMM
  k_stage1<<<dim3(64, 3, 10), 256, 0, stream>>>(featb_d, featb_z, w1t_d, w1t_z,
      db1, zb1, att_d, att_z, h1_d, h1_z, Y_d, Y_z);
  // aggregation -> h1 channels 1..4
  k_agg2<<<(NP*ND + NP*NZ)/4, 256, 0, stream>>>(csr_d, off_d, db1, Y_d, h1_d,
                                                csr_z, off_z, zb1, Y_z, h1_z);
  // fused MLP 2+3 + pg
  {
    MlpP pd = {h1_d, w2t_d, db2, w3t_d, db3, pbuf_d, pg_d, Gtb, ND};
    MlpP pz = {h1_z, w2t_z, zb2, w3t_z, zb3, pbuf_z, pg_z, Gtb + HID*HID, NZ};
    k_mlp23<<<dim3(64, 1, 10), 256, 0, stream>>>(pd, pz, 5);
  }
  // metapath attention
  k_attn<<<ND + NZ, 64, 0, stream>>>(pbuf_d, pg_d, v2v, beta_d, out_d,
                                     pbuf_z, pg_z, beta_z, out_z);
  // decoder
  {
    GemmP pz = {out_z, wdect, bdec, Bbig, wsm, nullptr, 0, (long)NZ*HID, (long)NCH*HID, HID, HID, HID, NZ, 0};
    k_gemm<<<dim3(32, 2, 5), 256, 0, stream>>>(pz, pz, 5);
  }
  // final
  k_gemm_final<<<dim3(64, 32), 256, 0, stream>>>(out_d, Bbig, (float*)d_out);
}

// Round 13
// 269.306 us; speedup vs baseline: 2.5607x; 1.0416x over previous
//
#include <hip/hip_runtime.h>
#include <hip/hip_bf16.h>

#define ND 8192
#define NZ 4096
#define IN_DIM 256
#define HID 128
#define MIDW 192
#define NP 4
#define NCH 5
#define DEG 32
#define E_D (ND*DEG)
#define E_Z (NZ*DEG)
#define CHUNK 8192
#define NB_D (E_D/CHUNK)   // 32
#define NB_Z (E_Z/CHUNK)   // 16
#define NCHK (NP*NB_D + NP*NB_Z)  // 192

typedef __hip_bfloat16 bf16;
typedef __attribute__((ext_vector_type(8))) short s8v;
typedef __attribute__((ext_vector_type(4))) float f4v;

static __device__ __forceinline__ unsigned short f2bf(float x){
  bf16 b = __float2bfloat16(x);
  return *reinterpret_cast<unsigned short*>(&b);
}
static __device__ __forceinline__ uint packbf2(float a, float b){
  return (uint)f2bf(a) | ((uint)f2bf(b) << 16);
}
static __device__ __forceinline__ float bfl(uint w){ return __uint_as_float(w<<16); }
static __device__ __forceinline__ float bfh(uint w){ return __uint_as_float(w & 0xffff0000u); }
static __device__ __forceinline__ void gload16(const void* g, void* l){
  __builtin_amdgcn_global_load_lds(
      (const __attribute__((address_space(1))) unsigned int*)g,
      (__attribute__((address_space(3))) unsigned int*)l, 16, 0, 0);
}

// ---------------- mega prep: per-chunk histograms + cvts + transposes + G + v2 ----------------
static __device__ __forceinline__ void tpz(const float* __restrict__ in, bf16* __restrict__ out,
                                           int rows, int cols, long idx){
  int per = rows*cols;
  int b = (int)(idx / per);
  int rem = (int)(idx - (long)b*per);
  int r = rem / cols, c = rem - r*cols;
  out[(long)b*per + (long)c*rows + r] = __float2bfloat16(in[idx]);
}

#define P_H NCHK               // 192 histogram blocks first
#define B_CVD (P_H+2048)
#define B_CVZ (B_CVD+1024)
#define B_W1D (B_CVZ+960)
#define B_W1Z (B_W1D+960)
#define B_W2D (B_W1Z+720)
#define B_W2Z (B_W2D+720)
#define B_W3D (B_W2Z+480)
#define B_W3Z (B_W3D+480)
#define B_WDEC (B_W3Z+320)
#define B_G (B_WDEC+128)
#define B_END (B_G+1)

__global__ __launch_bounds__(256) void k_prep(
    const int* __restrict__ src_d, int* __restrict__ bh_d,
    const int* __restrict__ src_z, int* __restrict__ bh_z,
    const float* feat_d, const float* feat_z, bf16* featb_d, bf16* featb_z,
    const float* dW1, const float* dW2, const float* dW3,
    const float* zW1, const float* zW2, const float* zW3,
    bf16* w1t_d, bf16* w2t_d, bf16* w3t_d, bf16* w1t_z, bf16* w2t_z, bf16* w3t_z,
    const float* Wdec, bf16* wdect,
    const float* Wq_d, const float* Wk_d, const float* Wq_z, const float* Wk_z,
    bf16* Gtb,
    const float* bq_d, const float* bq_z, float* v2v,
    const float* wattn, float* wsm)
{
  int b = blockIdx.x, t = threadIdx.x;
  if (b < P_H){
    __shared__ int hist[ND];
    const int* src; int* bh; int n;
    if (b < NP*NB_D){
      int mp = b >> 5, ch = b & (NB_D-1);
      src = src_d + (long)mp*E_D + ch*CHUNK;
      bh = bh_d + ((long)mp*NB_D + ch)*ND;
      n = ND;
    } else {
      int b2 = b - NP*NB_D;
      int mp = b2 >> 4, ch = b2 & (NB_Z-1);
      src = src_z + (long)mp*E_Z + ch*CHUNK;
      bh = bh_z + ((long)mp*NB_Z + ch)*NZ;
      n = NZ;
    }
    for (int i=t; i<n; i+=256) hist[i] = 0;
    __syncthreads();
    for (int e=t; e<CHUNK; e+=256) atomicAdd(&hist[src[e]], 1);
    __syncthreads();
    for (int i=t; i<n; i+=256) bh[i] = hist[i];
  } else if (b < B_CVD){
    long i4 = (long)(b - P_H)*256 + t;
    float4 v = ((const float4*)feat_d)[i4];
    ushort4 o; o.x=f2bf(v.x); o.y=f2bf(v.y); o.z=f2bf(v.z); o.w=f2bf(v.w);
    ((ushort4*)featb_d)[i4] = o;
  } else if (b < B_CVZ){
    long i4 = (long)(b - B_CVD)*256 + t;
    float4 v = ((const float4*)feat_z)[i4];
    ushort4 o; o.x=f2bf(v.x); o.y=f2bf(v.y); o.z=f2bf(v.z); o.w=f2bf(v.w);
    ((ushort4*)featb_z)[i4] = o;
  } else if (b < B_W1D){ tpz(dW1, w1t_d, IN_DIM, MIDW, (long)(b-B_CVZ)*256 + t); }
  else if (b < B_W1Z){ tpz(zW1, w1t_z, IN_DIM, MIDW, (long)(b-B_W1D)*256 + t); }
  else if (b < B_W2D){ tpz(dW2, w2t_d, MIDW, MIDW, (long)(b-B_W1Z)*256 + t); }
  else if (b < B_W2Z){ tpz(zW2, w2t_z, MIDW, MIDW, (long)(b-B_W2D)*256 + t); }
  else if (b < B_W3D){ tpz(dW3, w3t_d, MIDW, HID, (long)(b-B_W2Z)*256 + t); }
  else if (b < B_W3Z){ tpz(zW3, w3t_z, MIDW, HID, (long)(b-B_W3D)*256 + t); }
  else if (b < B_WDEC){ tpz(Wdec, wdect, HID, HID, (long)(b-B_W3Z)*256 + t); }
  else if (b < B_G){
    // Gt[c,h'] = sum_j Wq[h',j]*Wk[c,j]
    int cc = (b - B_WDEC)*2 + (t>>7);
    int hp = t & 127;
    const float* Wq = cc < 128 ? Wq_d : Wq_z;
    const float* Wk = cc < 128 ? Wk_d : Wk_z;
    int c = cc & 127;
    float s = 0.f;
    for (int j=0;j<HID;j++) s += Wq[hp*HID+j]*Wk[c*HID+j];
    Gtb[(cc < 128 ? 0 : HID*HID) + c*HID + hp] = __float2bfloat16(s);
  } else {
    if (t < 128){
      float s = 0.f;
      for (int j=0;j<HID;j++) s += Wk_d[t*HID+j]*bq_d[j];
      v2v[t] = s;
    } else {
      int tt = t-128;
      float s = 0.f;
      for (int j=0;j<HID;j++) s += Wk_z[tt*HID+j]*bq_z[j];
      v2v[128+tt] = s;
    }
    if (t == 0){
      float mx = wattn[0];
      for (int i=1;i<NCH;i++) mx = fmaxf(mx, wattn[i]);
      float e[NCH], s=0.f;
      for (int i=0;i<NCH;i++){ e[i]=expf(wattn[i]-mx); s+=e[i]; }
      for (int i=0;i<NCH;i++) wsm[i]=e[i]/s;
    }
  }
}

// ---------------- CSR phase 2a: per-node cross-chunk scan (1 thread/node) ----------------
__global__ __launch_bounds__(256) void k_off_a(
    int* __restrict__ bh_d, int* __restrict__ tot_d,
    int* __restrict__ bh_z, int* __restrict__ tot_z)
{
  int i = blockIdx.x*256 + threadIdx.x;
  int* bh; int* tot; int n, NB, s;
  if (i < NP*ND){
    int m = i >> 13; s = i & (ND-1);
    bh = bh_d + (long)m*NB_D*ND; tot = tot_d + m*ND; n = ND; NB = NB_D;
  } else {
    int i2 = i - NP*ND;
    int m = i2 >> 12; s = i2 & (NZ-1);
    bh = bh_z + (long)m*NB_Z*NZ; tot = tot_z + m*NZ; n = NZ; NB = NB_Z;
  }
  int running = 0;
  for (int bb=0; bb<NB; bb++){
    int v = bh[bb*n + s];
    bh[bb*n + s] = running;
    running += v;
  }
  tot[s] = running;
}

// ---------------- CSR phase 2b: per-metapath exclusive scan tot -> off ----------------
__global__ __launch_bounds__(256) void k_scan(const int* __restrict__ tot_d, int* __restrict__ off_d,
                                              const int* __restrict__ tot_z, int* __restrict__ off_z){
  int b = blockIdx.x;
  const int* d; int* o; int n; int E;
  if (b < NP){ d = tot_d + (long)b*ND; o = off_d + (long)b*(ND+1); n = ND; E = E_D; }
  else { int m = b-NP; d = tot_z + (long)m*NZ; o = off_z + (long)m*(NZ+1); n = NZ; E = E_Z; }
  int t = threadIdx.x, lane = t&63, wv = t>>6;
  __shared__ int wsum[4];
  __shared__ int carry;
  if (t==0) carry = 0;
  __syncthreads();
  for (int base=0; base<n; base+=256){
    int v = d[base+t];
    int x = v;
    #pragma unroll
    for (int s=1; s<64; s<<=1){
      int u = __shfl_up(x, s, 64);
      if (lane >= s) x += u;
    }
    if (lane==63) wsum[wv] = x;
    __syncthreads();
    int wo = 0;
    for (int w=0; w<wv; w++) wo += wsum[w];
    int c = carry;
    o[base+t] = c + wo + x - v;
    __syncthreads();
    if (t==255) carry = c + wo + x;
    __syncthreads();
  }
  if (t==0) o[n] = E;
}

// ---------------- CSR phase 3: chunk scatter; XCD-clustered block remap ----------------
__global__ __launch_bounds__(512) void k_scat2(
    const int* __restrict__ src_d, const int* __restrict__ dst_d,
    const int* __restrict__ bh_d, const int* __restrict__ off_d, ushort* __restrict__ csr_d,
    const int* __restrict__ src_z, const int* __restrict__ dst_z,
    const int* __restrict__ bh_z, const int* __restrict__ off_z, ushort* __restrict__ csr_z)
{
  __shared__ int cur[ND];
  int b = blockIdx.x, t = threadIdx.x;
  int mp8 = b & 7, ch = b >> 3;
  const int *src, *dst, *bh, *off; ushort* csr; int n;
  if (mp8 < NP){
    if (ch >= NB_D) return;
    int mp = mp8;
    src = src_d + (long)mp*E_D + ch*CHUNK;
    dst = dst_d + (long)mp*E_D + ch*CHUNK;
    bh = bh_d + ((long)mp*NB_D + ch)*ND;
    off = off_d + (long)mp*(ND+1);
    csr = csr_d + (long)mp*E_D;
    n = ND;
  } else {
    if (ch >= NB_Z) return;
    int mp = mp8 - NP;
    src = src_z + (long)mp*E_Z + ch*CHUNK;
    dst = dst_z + (long)mp*E_Z + ch*CHUNK;
    bh = bh_z + ((long)mp*NB_Z + ch)*NZ;
    off = off_z + (long)mp*(NZ+1);
    csr = csr_z + (long)mp*E_Z;
    n = NZ;
  }
  for (int i=t; i<n; i+=512) cur[i] = bh[i] + off[i];
  __syncthreads();
  for (int e=t; e<CHUNK; e+=512){
    int s = src[e];
    int pos = atomicAdd(&cur[s], 1);
    csr[pos] = (ushort)dst[e];
  }
}

// ---------------- stage 1: (A1 | A2) full-width 128x192 GEMM, z = type*5 + channel ----------------
__global__ __launch_bounds__(256) void k_stage1(
    const bf16* __restrict__ featb_d, const bf16* __restrict__ featb_z,
    const bf16* __restrict__ w1t_d, const bf16* __restrict__ w1t_z,
    const float* __restrict__ db1, const float* __restrict__ zb1,
    const float* __restrict__ att_d, const float* __restrict__ att_z,
    bf16* __restrict__ h1_d, bf16* __restrict__ h1_z,
    bf16* __restrict__ Y_d, bf16* __restrict__ Y_z)
{
  int z = blockIdx.z, typ = z/5, c = z - 5*(z/5);
  int n = typ ? NZ : ND;
  long row0 = (long)blockIdx.x*128;
  if (row0 >= n) return;
  __shared__ short As[128*40];
  __shared__ short Bs[192*40];
  int t = threadIdx.x, lane = t&63, wv = t>>6;
  int l15 = lane&15, hi = lane>>4, kof = hi*8;
  const short* Ag = (const short*)(typ ? featb_z : featb_d);
  const short* Bg = (const short*)(typ ? w1t_z : w1t_d) + (long)c*MIDW*IN_DIM;
  f4v acc[2][12] = {};
  for (int kk=0; kk<IN_DIM; kk+=32){
    __syncthreads();
    #pragma unroll
    for (int j=0;j<2;j++){
      int c2 = t + j*256;
      int row = c2>>2, sub = c2&3;
      *(s8v*)(&As[row*40 + sub*8]) = *(const s8v*)(Ag + (row0+row)*IN_DIM + kk + sub*8);
    }
    #pragma unroll
    for (int j=0;j<3;j++){
      int c2 = t + j*256;
      int row = c2>>2, sub = c2&3;
      *(s8v*)(&Bs[row*40 + sub*8]) = *(const s8v*)(Bg + (long)row*IN_DIM + kk + sub*8);
    }
    __syncthreads();
    s8v af[2], bfr[12];
    #pragma unroll
    for (int i2=0;i2<2;i2++) af[i2] = *(const s8v*)(&As[(wv*32 + i2*16 + l15)*40 + kof]);
    #pragma unroll
    for (int j2=0;j2<12;j2++) bfr[j2] = *(const s8v*)(&Bs[(j2*16 + l15)*40 + kof]);
    #pragma unroll
    for (int i2=0;i2<2;i2++)
      #pragma unroll
      for (int j2=0;j2<12;j2++)
        acc[i2][j2] = __builtin_amdgcn_mfma_f32_16x16x32_bf16(af[i2], bfr[j2], acc[i2][j2],0,0,0);
  }
  if (c == 0){
    const float* bb = typ ? zb1 : db1;
    bf16* outp = typ ? h1_z : h1_d;
    #pragma unroll
    for (int i2=0;i2<2;i2++)
      #pragma unroll
      for (int j2=0;j2<12;j2++){
        int col = j2*16 + l15;
        float bv = bb[col];
        #pragma unroll
        for (int r=0;r<4;r++){
          long row = row0 + wv*32 + i2*16 + hi*4 + r;
          outp[row*MIDW + col] = __float2bfloat16(fmaxf(acc[i2][j2][r] + bv, 0.f));
        }
      }
  } else {
    const float* rs = (typ ? att_z : att_d) + (long)(c-1)*n;
    bf16* outp = (typ ? Y_z : Y_d) + (long)(c-1)*n*MIDW;
    #pragma unroll
    for (int i2=0;i2<2;i2++)
      #pragma unroll
      for (int j2=0;j2<12;j2++){
        int col = j2*16 + l15;
        #pragma unroll
        for (int r=0;r<4;r++){
          long row = row0 + wv*32 + i2*16 + hi*4 + r;
          outp[row*MIDW + col] = __float2bfloat16(acc[i2][j2][r] * rs[row]);
        }
      }
  }
}

// ---------------- aggregation (compact ushort CSR, 4-edge unroll) ----------------
__global__ __launch_bounds__(256) void k_agg2(
    const ushort* __restrict__ csr_d, const int* __restrict__ off_d, const float* __restrict__ bias_d,
    const bf16* __restrict__ Y_d, bf16* __restrict__ h1_d,
    const ushort* __restrict__ csr_z, const int* __restrict__ off_z, const float* __restrict__ bias_z,
    const bf16* __restrict__ Y_z, bf16* __restrict__ h1_z)
{
  int wid = (blockIdx.x*256 + threadIdx.x) >> 6;
  int lane = threadIdx.x & 63;
  const ushort* csr; const int* off; const float* bias; const uint* Yb; bf16* h1; int n, m; long ebase;
  if (wid < NP*ND){
    m = wid >> 13; int s0 = wid & (ND-1);
    csr = csr_d; off = off_d + (long)m*(ND+1); bias = bias_d; h1 = h1_d; n = ND;
    Yb = (const uint*)Y_d + (long)m*ND*96;
    ebase = (long)m*E_D;
    wid = s0;
  } else {
    int w2 = wid - NP*ND;
    m = w2 >> 12; int s0 = w2 & (NZ-1);
    csr = csr_z; off = off_z + (long)m*(NZ+1); bias = bias_z; h1 = h1_z; n = NZ;
    Yb = (const uint*)Y_z + (long)m*NZ*96;
    ebase = (long)m*E_Z;
    wid = s0;
  }
  int s = wid;
  int o0 = off[s], o1 = off[s+1];
  int cnt = o1 - o0;
  const ushort* lp = csr + ebase + o0;
  bool hi2 = lane < 32;
  float a0=0.f,a1=0.f,a2=0.f,a3=0.f;
  for (int base=0; base<cnt; base+=64){
    int rem = cnt - base;
    int idx = (lane < rem) ? lane : (rem-1);
    int e = lp[base + idx];
    int lim = rem < 64 ? rem : 64;
    int j = 0;
    for (; j+3<lim; j+=4){
      int d0 = __shfl(e, j), d1 = __shfl(e, j+1), d2 = __shfl(e, j+2), d3 = __shfl(e, j+3);
      const uint* r0 = Yb + (long)d0*96;
      const uint* r1 = Yb + (long)d1*96;
      const uint* r2 = Yb + (long)d2*96;
      const uint* r3 = Yb + (long)d3*96;
      uint w0 = r0[lane], w1 = r1[lane], w2 = r2[lane], w3 = r3[lane];
      uint v0 = hi2 ? r0[64+lane] : 0u;
      uint v1 = hi2 ? r1[64+lane] : 0u;
      uint v2 = hi2 ? r2[64+lane] : 0u;
      uint v3 = hi2 ? r3[64+lane] : 0u;
      a0 += (bfl(w0)+bfl(w1)) + (bfl(w2)+bfl(w3));
      a1 += (bfh(w0)+bfh(w1)) + (bfh(w2)+bfh(w3));
      a2 += (bfl(v0)+bfl(v1)) + (bfl(v2)+bfl(v3));
      a3 += (bfh(v0)+bfh(v1)) + (bfh(v2)+bfh(v3));
    }
    for (; j<lim; j++){
      int d0 = __shfl(e, j);
      const uint* r0 = Yb + (long)d0*96;
      uint w0 = r0[lane];
      uint v0 = hi2 ? r0[64+lane] : 0u;
      a0 += bfl(w0); a1 += bfh(w0);
      a2 += bfl(v0); a3 += bfh(v0);
    }
  }
  float inv = 1.0f / fmaxf((float)cnt, 1.0f);
  const float* bb = bias + (m+1)*MIDW;
  float2 b0 = *(const float2*)(bb + 2*lane);
  uint* hrow = (uint*)((short*)h1 + ((long)(m+1)*n + s)*MIDW);
  hrow[lane] = packbf2(fmaxf(a0*inv + b0.x, 0.f), fmaxf(a1*inv + b0.y, 0.f));
  if (hi2){
    float2 b1v = *(const float2*)(bb + 128 + 2*lane);
    hrow[64+lane] = packbf2(fmaxf(a2*inv + b1v.x, 0.f), fmaxf(a3*inv + b1v.y, 0.f));
  }
}

// ---------------- generic batched GEMM (decoder) ----------------
struct GemmP {
  const bf16* A; const bf16* BT; const float* bias; bf16* out;
  const float* scale; const float* rowsc;
  long rs_moff, a_moff, out_rstride, out_moff;
  int K, N, nrows, relu;
};

__global__ __launch_bounds__(256) void k_gemm(GemmP P0, GemmP P1, int zsplit)
{
  const GemmP& p = ((int)blockIdx.z < zsplit) ? P0 : P1;
  int m = ((int)blockIdx.z < zsplit) ? blockIdx.z : blockIdx.z - zsplit;
  long row0 = (long)blockIdx.x*128;
  if (row0 >= p.nrows) return;
  int col0 = blockIdx.y*64;
  if (col0 >= p.N) return;
  __shared__ short As[128*40];
  __shared__ short Bs[64*40];
  int t = threadIdx.x;
  const short* Ag = (const short*)p.A + m*p.a_moff;
  const short* Bg = (const short*)p.BT + (long)m*p.N*p.K;
  int lane = t&63, wv = t>>6;
  int l15 = lane&15, kof = (lane>>4)*8;
  int K = p.K;
  f4v acc[2][4] = {};
  for (int kk=0; kk<K; kk+=32){
    __syncthreads();
    #pragma unroll
    for (int j=0;j<2;j++){
      int c = t + j*256;
      int row = c>>2, sub = c&3;
      *(s8v*)(&As[row*40 + sub*8]) = *(const s8v*)(Ag + (row0+row)*K + kk + sub*8);
    }
    { int row = t>>2, sub = t&3;
      *(s8v*)(&Bs[row*40 + sub*8]) = *(const s8v*)(Bg + (long)(col0+row)*K + kk + sub*8); }
    __syncthreads();
    s8v af[2], bfr[4];
    #pragma unroll
    for (int i2=0;i2<2;i2++) af[i2] = *(const s8v*)(&As[(wv*32 + i2*16 + l15)*40 + kof]);
    #pragma unroll
    for (int j2=0;j2<4;j2++) bfr[j2] = *(const s8v*)(&Bs[(j2*16 + l15)*40 + kof]);
    #pragma unroll
    for (int i2=0;i2<2;i2++)
      #pragma unroll
      for (int j2=0;j2<4;j2++)
        acc[i2][j2] = __builtin_amdgcn_mfma_f32_16x16x32_bf16(af[i2], bfr[j2], acc[i2][j2],0,0,0);
  }
  float sc = p.scale ? p.scale[m] : 1.0f;
  #pragma unroll
  for (int i2=0;i2<2;i2++){
    #pragma unroll
    for (int j2=0;j2<4;j2++){
      int col = col0 + j2*16 + l15;
      float bv = p.bias ? p.bias[m*p.N + col] : 0.f;
      #pragma unroll
      for (int r=0;r<4;r++){
        long row = row0 + wv*32 + i2*16 + (lane>>4)*4 + r;
        float v = acc[i2][j2][r] + bv;
        if (p.relu) v = fmaxf(v, 0.f);
        v *= sc;
        if (p.rowsc) v *= p.rowsc[m*p.rs_moff + row];
        p.out[m*p.out_moff + row*p.out_rstride + col] = __float2bfloat16(v);
      }
    }
  }
}

// ---------------- fused MLP 2+3 + pg (64-row tiles, 3 blocks/CU) ----------------
struct MlpP { const bf16* h1; const bf16* w2t; const float* b2;
              const bf16* w3t; const float* b3; bf16* pout; bf16* pgout;
              const bf16* gt; int n; };

__global__ __launch_bounds__(256) void k_mlp23(MlpP P0, MlpP P1, int zsplit)
{
  const MlpP& p = ((int)blockIdx.z < zsplit) ? P0 : P1;
  int m = ((int)blockIdx.z < zsplit) ? blockIdx.z : blockIdx.z - zsplit;
  int row0 = blockIdx.x*64;
  if (row0 >= p.n) return;
  __shared__ short h2s[64*200];
  __shared__ short As[64*40];
  __shared__ short Bs[192*40];
  int t = threadIdx.x, lane = t&63, wv = t>>6;
  int l15 = lane&15, hi = lane>>4, kof = hi*8;
  const short* Ag = (const short*)p.h1 + ((long)m*p.n + row0)*MIDW;
  const short* Bg = (const short*)p.w2t + (long)m*MIDW*MIDW;
  f4v accA[12] = {};
  for (int kk=0; kk<MIDW; kk+=32){
    __syncthreads();
    { int row = t>>2, sub = t&3;
      *(s8v*)(&As[row*40 + sub*8]) = *(const s8v*)(Ag + (long)row*MIDW + kk + sub*8); }
    #pragma unroll
    for (int j=0;j<3;j++){
      int c = t + j*256;
      int row = c>>2, sub = c&3;
      *(s8v*)(&Bs[row*40 + sub*8]) = *(const s8v*)(Bg + (long)row*MIDW + kk + sub*8);
    }
    __syncthreads();
    s8v af = *(const s8v*)(&As[(wv*16 + l15)*40 + kof]);
    #pragma unroll
    for (int j2=0;j2<12;j2++){
      s8v bfr = *(const s8v*)(&Bs[(j2*16 + l15)*40 + kof]);
      accA[j2] = __builtin_amdgcn_mfma_f32_16x16x32_bf16(af, bfr, accA[j2],0,0,0);
    }
  }
  #pragma unroll
  for (int j2=0;j2<12;j2++){
    float b2l = p.b2[m*MIDW + j2*16 + l15];
    #pragma unroll
    for (int r=0;r<4;r++){
      int rl = wv*16 + hi*4 + r;
      h2s[rl*200 + j2*16 + l15] = (short)f2bf(fmaxf(accA[j2][r] + b2l, 0.f));
    }
  }
  const short* Cg = (const short*)p.w3t + (long)m*HID*MIDW;
  f4v accB[8] = {};
  for (int kk=0; kk<MIDW; kk+=32){
    __syncthreads();
    #pragma unroll
    for (int j=0;j<2;j++){
      int c = t + j*256;
      int row = c>>2, sub = c&3;
      *(s8v*)(&Bs[row*40 + sub*8]) = *(const s8v*)(Cg + (long)row*MIDW + kk + sub*8);
    }
    __syncthreads();
    s8v af = *(const s8v*)(&h2s[(wv*16 + l15)*200 + kk + kof]);
    #pragma unroll
    for (int j2=0;j2<8;j2++){
      s8v bfr = *(const s8v*)(&Bs[(j2*16 + l15)*40 + kof]);
      accB[j2] = __builtin_amdgcn_mfma_f32_16x16x32_bf16(af, bfr, accB[j2],0,0,0);
    }
  }
  __syncthreads();              // all phase-B h2s reads done before overwrite with p
  #pragma unroll
  for (int j2=0;j2<8;j2++){
    float b3v = p.b3[m*HID + j2*16 + l15];
    #pragma unroll
    for (int r=0;r<4;r++){
      int rl = wv*16 + hi*4 + r;
      unsigned short hv = f2bf(accB[j2][r] + b3v);
      p.pout[((long)(row0+rl))*(NCH*HID) + m*HID + j2*16 + l15] = *(bf16*)&hv;
      h2s[rl*200 + j2*16 + l15] = (short)hv;
    }
  }
  const short* Gg = (const short*)p.gt;
  f4v accC[8] = {};
  for (int kk=0; kk<HID; kk+=32){
    __syncthreads();
    #pragma unroll
    for (int j=0;j<2;j++){
      int c = t + j*256;
      int row = c>>2, sub = c&3;
      *(s8v*)(&Bs[row*40 + sub*8]) = *(const s8v*)(Gg + (long)row*HID + kk + sub*8);
    }
    __syncthreads();
    s8v af = *(const s8v*)(&h2s[(wv*16 + l15)*200 + kk + kof]);
    #pragma unroll
    for (int j2=0;j2<8;j2++){
      s8v bfr = *(const s8v*)(&Bs[(j2*16 + l15)*40 + kof]);
      accC[j2] = __builtin_amdgcn_mfma_f32_16x16x32_bf16(af, bfr, accC[j2],0,0,0);
    }
  }
  #pragma unroll
  for (int j2=0;j2<8;j2++)
    #pragma unroll
    for (int r=0;r<4;r++){
      long row = row0 + wv*16 + hi*4 + r;
      p.pgout[row*(NCH*HID) + m*HID + j2*16 + l15] = __float2bfloat16(accC[j2][r]);
    }
}

// ---------------- per-node metapath attention (bilinear) ----------------
__global__ __launch_bounds__(64) void k_attn(
    const bf16* __restrict__ p_d, const bf16* __restrict__ pg_d, const float* __restrict__ v2v,
    const float* __restrict__ beta_d, bf16* __restrict__ o_d,
    const bf16* __restrict__ p_z, const bf16* __restrict__ pg_z,
    const float* __restrict__ beta_z, bf16* __restrict__ o_z)
{
  int node = blockIdx.x; int t = threadIdx.x;
  const bf16 *pp, *gg; bf16* outp; const float *betap, *v2p;
  if (node < ND){
    pp = p_d + (long)node*640; gg = pg_d + (long)node*640;
    outp = o_d + (long)node*640; betap = beta_d; v2p = v2v;
  } else {
    int nz = node - ND;
    pp = p_z + (long)nz*640; gg = pg_z + (long)nz*640;
    outp = o_z + (long)nz*640; betap = beta_z; v2p = v2v + 128;
  }
  __shared__ float pl[640], gl[640], v2l[128];
  __shared__ float lg[25], at[25], bv[5];
  const uint* pu = (const uint*)pp;
  const uint* gu = (const uint*)gg;
  for (int i=t; i<320; i+=64){
    uint w = pu[i];
    pl[2*i] = bfl(w); pl[2*i+1] = bfh(w);
    uint g = gu[i];
    gl[2*i] = bfl(g); gl[2*i+1] = bfh(g);
  }
  v2l[t] = v2p[t]; v2l[64+t] = v2p[64+t];
  __syncthreads();
  if (t < 60){
    int pr = t>>1, sub = t&1, h0 = sub*64;
    float s = 0.f;
    if (pr < 25){
      int mi = pr/5, ki = pr - 5*(pr/5);
      for (int h=h0; h<h0+64; h++) s += gl[mi*HID+h]*pl[ki*HID+h];
      s += __shfl_xor(s, 1);
      if (!sub) lg[pr] = s;
    } else {
      int k = pr - 25;
      for (int h=h0; h<h0+64; h++) s += pl[k*HID+h]*v2l[h];
      s += __shfl_xor(s, 1);
      if (!sub) bv[k] = s;
    }
  }
  __syncthreads();
  if (t < 5){
    float l0[5];
    for (int j=0;j<5;j++) l0[j] = lg[t*5+j] + bv[j];
    float mx = l0[0];
    for (int j=1;j<5;j++) mx = fmaxf(mx, l0[j]);
    float e[5], su=0.f;
    for (int j=0;j<5;j++){ e[j] = expf(l0[j]-mx); su += e[j]; }
    for (int j=0;j<5;j++) at[t*5+j] = e[j]/su;
  }
  __syncthreads();
  float bt = betap[0];
  for (int i=t; i<320; i+=64){
    int mm = i>>6, h = (i&63)*2;
    float s0=0.f, s1=0.f;
    #pragma unroll
    for (int k2=0;k2<5;k2++){
      s0 += at[mm*5+k2]*pl[k2*HID+h];
      s1 += at[mm*5+k2]*pl[k2*HID+h+1];
    }
    ((uint*)outp)[i] = packbf2(pl[2*i] + bt*s0, pl[2*i+1] + bt*s1);
  }
}

// ---------------- final GEMM ----------------
__global__ __launch_bounds__(256) void k_gemm_final(
    const bf16* __restrict__ Aout, const bf16* __restrict__ Bb, float* __restrict__ out)
{
  __shared__ short As[128*64];
  __shared__ short Bs[128*64];
  int t = threadIdx.x;
  int lane = t&63, wv=t>>6, wr=wv>>1, wc=wv&1;
  int row0 = blockIdx.x*128, col0 = blockIdx.y*128;
  const short* Ag = (const short*)Aout;
  const short* Bg = (const short*)Bb;
  int l15 = lane&15, hi = lane>>4;
  int srow = t>>3;
  int sseg = (t&7) ^ (srow&7);
  f4v acc[4][4] = {};
  for (int kk=0; kk<NCH*HID; kk+=64){
    int mch = kk>>7, h0 = kk&127;
    __syncthreads();
    #pragma unroll
    for (int j=0;j<4;j++){
      int row = j*32 + srow;
      gload16(Ag + ((long)mch*ND + row0+row)*HID + h0 + sseg*8,
              (char*)As + ((j*256 + t)<<4));
      gload16(Bg + (long)(col0+row)*(NCH*HID) + kk + sseg*8,
              (char*)Bs + ((j*256 + t)<<4));
    }
    asm volatile("s_waitcnt vmcnt(0)" ::: "memory");
    __syncthreads();
    #pragma unroll
    for (int sl=0; sl<2; sl++){
      s8v af[4], bg[4];
      #pragma unroll
      for (int i=0;i<4;i++){
        int ra = wr*64 + i*16 + l15;
        af[i] = *(const s8v*)(&As[ra*64 + (((sl*4+hi) ^ (ra&7))*8)]);
        int rb = wc*64 + i*16 + l15;
        bg[i] = *(const s8v*)(&Bs[rb*64 + (((sl*4+hi) ^ (rb&7))*8)]);
      }
      #pragma unroll
      for (int mi=0;mi<4;mi++)
        #pragma unroll
        for (int ni=0;ni<4;ni++)
          acc[mi][ni] = __builtin_amdgcn_mfma_f32_16x16x32_bf16(af[mi], bg[ni], acc[mi][ni],0,0,0);
    }
  }
  #pragma unroll
  for (int mi=0;mi<4;mi++){
    #pragma unroll
    for (int ni=0;ni<4;ni++){
      int col = col0 + wc*64 + ni*16 + l15;
      #pragma unroll
      for (int r=0;r<4;r++){
        int row = row0 + wr*64 + mi*16 + hi*4 + r;
        out[(long)row*NZ + col] = acc[mi][ni][r];
      }
    }
  }
}

extern "C" void kernel_launch(void* const* d_in, const int* in_sizes, int n_in,
                              void* d_out, int out_size, void* d_ws, size_t ws_size,
                              hipStream_t stream)
{
  (void)in_sizes; (void)n_in; (void)out_size;
  const float* feat_d = (const float*)d_in[0];
  const float* feat_z = (const float*)d_in[1];
  const float* att_d  = (const float*)d_in[2];
  const float* att_z  = (const float*)d_in[3];
  const int* src_d = (const int*)d_in[4];
  const int* dst_d = (const int*)d_in[5];
  const int* src_z = (const int*)d_in[6];
  const int* dst_z = (const int*)d_in[7];
  const float* dW1=(const float*)d_in[8];  const float* db1=(const float*)d_in[9];
  const float* dW2=(const float*)d_in[10]; const float* db2=(const float*)d_in[11];
  const float* dW3=(const float*)d_in[12]; const float* db3=(const float*)d_in[13];
  const float* Wq_d=(const float*)d_in[14]; const float* bq_d=(const float*)d_in[15];
  const float* Wk_d=(const float*)d_in[16]; const float* bk_d=(const float*)d_in[17];
  const float* beta_d=(const float*)d_in[18];
  const float* zW1=(const float*)d_in[19]; const float* zb1=(const float*)d_in[20];
  const float* zW2=(const float*)d_in[21]; const float* zb2=(const float*)d_in[22];
  const float* zW3=(const float*)d_in[23]; const float* zb3=(const float*)d_in[24];
  const float* Wq_z=(const float*)d_in[25]; const float* bq_z=(const float*)d_in[26];
  const float* Wk_z=(const float*)d_in[27]; const float* bk_z=(const float*)d_in[28];
  const float* beta_z=(const float*)d_in[29];
  const float* wattn=(const float*)d_in[30];
  const float* Wdec=(const float*)d_in[31]; const float* bdec=(const float*)d_in[32];
  (void)bk_d; (void)bk_z;

  char* ws = (char*)d_ws;
  size_t o = 0;
  auto alloc = [&](size_t bytes)->char*{
    size_t r = (o + 255) & ~(size_t)255;
    o = r + bytes;
    return ws + r;
  };
  bf16* featb_d = (bf16*)alloc((size_t)ND*IN_DIM*2);      // 4.19 MB ┐
  bf16* featb_z = (bf16*)alloc((size_t)NZ*IN_DIM*2);      // 2.10 MB ├ pg_d (10.49) after agg2
  bf16* Y_d = (bf16*)alloc((size_t)NP*ND*MIDW*2);         // 6.29 MB ┘
  bf16* Y_z = (bf16*)alloc((size_t)NP*NZ*MIDW*2);
  bf16* h1_d = (bf16*)alloc((size_t)NCH*ND*MIDW*2);       // out_d later
  bf16* h1_z = (bf16*)alloc((size_t)NCH*NZ*MIDW*2);       // out_z later
  bf16* pbuf_d = (bf16*)alloc((size_t)ND*NCH*HID*2);
  bf16* pbuf_z = (bf16*)alloc((size_t)NZ*NCH*HID*2);      // Bbig later
  bf16* pg_z = (bf16*)alloc((size_t)NZ*NCH*HID*2);
  ushort* csr_d = (ushort*)alloc((size_t)NP*E_D*2);
  ushort* csr_z = (ushort*)alloc((size_t)NP*E_Z*2);
  int* bh_d = (int*)alloc((size_t)NP*NB_D*ND*4);
  int* bh_z = (int*)alloc((size_t)NP*NB_Z*NZ*4);
  int* tot_d = (int*)alloc((size_t)NP*ND*4);
  int* tot_z = (int*)alloc((size_t)NP*NZ*4);
  int* off_d = (int*)alloc((size_t)NP*(ND+1)*4);
  int* off_z = (int*)alloc((size_t)NP*(NZ+1)*4);
  bf16* w1t_d = (bf16*)alloc((size_t)NCH*MIDW*IN_DIM*2);
  bf16* w2t_d = (bf16*)alloc((size_t)NCH*MIDW*MIDW*2);
  bf16* w3t_d = (bf16*)alloc((size_t)NCH*HID*MIDW*2);
  bf16* w1t_z = (bf16*)alloc((size_t)NCH*MIDW*IN_DIM*2);
  bf16* w2t_z = (bf16*)alloc((size_t)NCH*MIDW*MIDW*2);
  bf16* w3t_z = (bf16*)alloc((size_t)NCH*HID*MIDW*2);
  bf16* Gtb = (bf16*)alloc((size_t)2*HID*HID*2);
  bf16* wdect = (bf16*)alloc((size_t)NCH*HID*HID*2);
  float* v2v = (float*)alloc((size_t)256*4);
  float* wsm = (float*)alloc((size_t)NCH*4);
  bf16* out_d = h1_d;
  bf16* out_z = h1_z;
  bf16* pg_d = featb_d;           // featb+Y_d region dead after agg2
  bf16* Bbig = pbuf_z;            // pbuf_z dead after attn
  if (ws_size < o) return;

  // prep: per-chunk histograms + converts + transposes + G + v2 (one launch)
  k_prep<<<B_END, 256, 0, stream>>>(src_d, bh_d, src_z, bh_z,
      feat_d, feat_z, featb_d, featb_z,
      dW1, dW2, dW3, zW1, zW2, zW3,
      w1t_d, w2t_d, w3t_d, w1t_z, w2t_z, w3t_z,
      Wdec, wdect, Wq_d, Wk_d, Wq_z, Wk_z, Gtb,
      bq_d, bq_z, v2v, wattn, wsm);
  // CSR: per-node cross-chunk scan -> per-metapath scan -> chunk scatter
  k_off_a<<<(NP*ND + NP*NZ)/256, 256, 0, stream>>>(bh_d, tot_d, bh_z, tot_z);
  k_scan<<<2*NP, 256, 0, stream>>>(tot_d, off_d, tot_z, off_z);
  k_scat2<<<256, 512, 0, stream>>>(src_d, dst_d, bh_d, off_d, csr_d,
                                   src_z, dst_z, bh_z, off_z, csr_z);
  // stage 1: A1 + A2 GEMM (full-width 128x192 tiles)
  k_stage1<<<dim3(64, 1, 10), 256, 0, stream>>>(featb_d, featb_z, w1t_d, w1t_z,
      db1, zb1, att_d, att_z, h1_d, h1_z, Y_d, Y_z);
  // aggregation -> h1 channels 1..4
  k_agg2<<<(NP*ND + NP*NZ)/4, 256, 0, stream>>>(csr_d, off_d, db1, Y_d, h1_d,
                                                csr_z, off_z, zb1, Y_z, h1_z);
  // fused MLP 2+3 + pg (64-row tiles)
  {
    MlpP pd = {h1_d, w2t_d, db2, w3t_d, db3, pbuf_d, pg_d, Gtb, ND};
    MlpP pz = {h1_z, w2t_z, zb2, w3t_z, zb3, pbuf_z, pg_z, Gtb + HID*HID, NZ};
    k_mlp23<<<dim3(128, 1, 10), 256, 0, stream>>>(pd, pz, 5);
  }
  // metapath attention
  k_attn<<<ND + NZ, 64, 0, stream>>>(pbuf_d, pg_d, v2v, beta_d, out_d,
                                     pbuf_z, pg_z, beta_z, out_z);
  // decoder
  {
    GemmP pz = {out_z, wdect, bdec, Bbig, wsm, nullptr, 0, (long)NZ*HID, (long)NCH*HID, HID, HID, HID, NZ, 0};
    k_gemm<<<dim3(32, 2, 5), 256, 0, stream>>>(pz, pz, 5);
  }
  // final
  k_gemm_final<<<dim3(64, 32), 256, 0, stream>>>(out_d, Bbig, (float*)d_out);
}